// Round 9
// baseline (480.585 us; speedup 1.0000x reference)
//
#include <hip/hip_runtime.h>
#include <hip/hip_bf16.h>

// Problem constants
constexpr int B = 4, L = 2048, E = 300, D = 128, NH = 4, HD = 128, NL = 3, D2 = 512;
constexpr int L1 = L + 1; // 2049
constexpr float EPS = 1e-5f;
constexpr float SCALE = 0.08838834764831843f; // 1/sqrt(128)
constexpr int NCH = 32;              // relay-attention L-chunks
constexpr int CHUNK = 65;            // ceil(2049/32)

typedef unsigned int uint_t;
typedef unsigned short u16;
typedef short bf16x8 __attribute__((ext_vector_type(8)));
typedef float f32x4 __attribute__((ext_vector_type(4)));

__device__ __forceinline__ u16 f2bf(float f) {
  union { float f; uint_t i; } x; x.f = f;
  uint_t r = x.i + 0x7fffu + ((x.i >> 16) & 1u);
  return (u16)(r >> 16);
}
__device__ __forceinline__ uint_t packbf(float a, float b) {
  return (uint_t)f2bf(a) | ((uint_t)f2bf(b) << 16);
}
__device__ __forceinline__ float bf2f(u16 u) {
  union { uint_t i; float f; } x; x.i = ((uint_t)u) << 16; return x.f;
}
__device__ __forceinline__ float2 bf2x2(uint_t u) {
  union { uint_t i; float f; } a, b;
  a.i = (u & 0xffffu) << 16; b.i = u & 0xffff0000u;
  return make_float2(a.f, b.f);
}

// ---------------- weight pre-conversion: 4 tensors (rq,rk,rv,ro), NL*D*D2 fp32 -> bf16
struct WCArgs { const float* s[4]; u16* d[4]; };
__global__ __launch_bounds__(256) void wconv(WCArgs wa) {
  int ti = blockIdx.y;
  const float* s = wa.s[ti]; u16* dd = wa.d[ti];
  int i = (blockIdx.x * 256 + threadIdx.x) * 4;
  float4 f = *(const float4*)(s + i);
  *(uint2*)(dd + i) = make_uint2(packbf(f.x, f.y), packbf(f.z, f.w));
}

// ================= all-bf16 MFMA GEMM, BK=128: out[M,N] = A[M,K] @ W[N,K]^T + bias
// 64x64 tile, 256 threads = 4 waves 2x2 (each 32x32).
// If Af32 set (requires K==128): A is fp32 with fused LayerNorm (lng/lnb) on the fly.
struct GDesc {
  const u16* A; const u16* W; const float* bias;
  u16* outb;                // bf16 output (when !residleaky)
  float* outf;              // fp32 output (residleaky path)
  const float* resid; u16* out2b; const int* mask;
  const float* Af32; const float* lng; const float* lnb;
  int residleaky;
};
struct GArgs { GDesc d[5]; };

__global__ __launch_bounds__(256) void gemm_bf(GArgs ga, int nby, int N, int K) {
  __shared__ u16 As[64][136];
  __shared__ u16 Ws[64][136];
  __shared__ float gbs[2][D];
  int t = threadIdx.x;
  int bm = blockIdx.x;
  int di = blockIdx.y / nby, bn = blockIdx.y - di * nby;
  GDesc d = ga.d[di];
  const int rowA = bm * 64, rowW = bn * 64;

  f32x4 acc[2][2];
#pragma unroll
  for (int i = 0; i < 2; i++)
#pragma unroll
    for (int j = 0; j < 2; j++)
      acc[i][j] = (f32x4){0.f, 0.f, 0.f, 0.f};

  const int r = t >> 2;             // 0..63
  const int jj = t & 3;
  const int c0 = jj * 32;           // 0,32,64,96 (shorts)
  const int wid = t >> 6;
  const int wm = (wid & 1) * 32, wn = (wid >> 1) * 32;
  const int lr = t & 15, quad = (t >> 4) & 3;

  if (d.Af32 && t < 64) {           // stage gamma/beta (t<64: 2 floats each)
    gbs[0][t * 2] = d.lng[t * 2]; gbs[0][t * 2 + 1] = d.lng[t * 2 + 1];
    gbs[1][t * 2] = d.lnb[t * 2]; gbs[1][t * 2 + 1] = d.lnb[t * 2 + 1];
  }

  const u16* Wrow = d.W + (size_t)(rowW + r) * K;
  const u16* Arow = d.A ? d.A + (size_t)(rowA + r) * K : nullptr;

  for (int kt = 0; kt < K; kt += 128) {
    uint4 w0 = *(const uint4*)(Wrow + kt + c0);
    uint4 w1 = *(const uint4*)(Wrow + kt + c0 + 8);
    uint4 w2 = *(const uint4*)(Wrow + kt + c0 + 16);
    uint4 w3 = *(const uint4*)(Wrow + kt + c0 + 24);
    uint4 au[4];
    if (d.Af32) {
      // fused LN: 4 threads per row, 32 fp32 values each
      const float4* Ap = (const float4*)(d.Af32 + (size_t)(rowA + r) * 128 + c0);
      float4 f[8];
#pragma unroll
      for (int i = 0; i < 8; i++) f[i] = Ap[i];
      float sum = 0.f, sq = 0.f;
#pragma unroll
      for (int i = 0; i < 8; i++) {
        sum += f[i].x + f[i].y + f[i].z + f[i].w;
        sq += f[i].x * f[i].x + f[i].y * f[i].y + f[i].z * f[i].z + f[i].w * f[i].w;
      }
      sum += __shfl_xor(sum, 1, 64); sum += __shfl_xor(sum, 2, 64);
      sq  += __shfl_xor(sq, 1, 64);  sq  += __shfl_xor(sq, 2, 64);
      float mu = sum * (1.0f / D);
      float var = sq * (1.0f / D) - mu * mu;
      float rs = rsqrtf(var + EPS);
      __syncthreads();   // gbs ready (also guards As reuse)
#pragma unroll
      for (int i = 0; i < 8; i++) {
        float g0 = gbs[0][c0 + i * 4], g1 = gbs[0][c0 + i * 4 + 1];
        float g2 = gbs[0][c0 + i * 4 + 2], g3 = gbs[0][c0 + i * 4 + 3];
        float b0 = gbs[1][c0 + i * 4], b1 = gbs[1][c0 + i * 4 + 1];
        float b2 = gbs[1][c0 + i * 4 + 2], b3 = gbs[1][c0 + i * 4 + 3];
        float v0 = (f[i].x - mu) * rs * g0 + b0;
        float v1 = (f[i].y - mu) * rs * g1 + b1;
        float v2 = (f[i].z - mu) * rs * g2 + b2;
        float v3 = (f[i].w - mu) * rs * g3 + b3;
        ((uint2*)au)[i] = make_uint2(packbf(v0, v1), packbf(v2, v3));
      }
    } else {
      au[0] = *(const uint4*)(Arow + kt + c0);
      au[1] = *(const uint4*)(Arow + kt + c0 + 8);
      au[2] = *(const uint4*)(Arow + kt + c0 + 16);
      au[3] = *(const uint4*)(Arow + kt + c0 + 24);
      __syncthreads();
    }
    *(uint4*)&As[r][c0] = au[0]; *(uint4*)&As[r][c0 + 8] = au[1];
    *(uint4*)&As[r][c0 + 16] = au[2]; *(uint4*)&As[r][c0 + 24] = au[3];
    *(uint4*)&Ws[r][c0] = w0; *(uint4*)&Ws[r][c0 + 8] = w1;
    *(uint4*)&Ws[r][c0 + 16] = w2; *(uint4*)&Ws[r][c0 + 24] = w3;
    __syncthreads();
#pragma unroll
    for (int ks = 0; ks < 4; ks++) {
      bf16x8 af[2], bfr[2];
#pragma unroll
      for (int mt = 0; mt < 2; mt++)
        af[mt] = *(const bf16x8*)&As[wm + mt * 16 + lr][ks * 32 + quad * 8];
#pragma unroll
      for (int nt = 0; nt < 2; nt++)
        bfr[nt] = *(const bf16x8*)&Ws[wn + nt * 16 + lr][ks * 32 + quad * 8];
#pragma unroll
      for (int mt = 0; mt < 2; mt++)
#pragma unroll
        for (int nt = 0; nt < 2; nt++)
          acc[mt][nt] = __builtin_amdgcn_mfma_f32_16x16x32_bf16(af[mt], bfr[nt], acc[mt][nt], 0, 0, 0);
    }
  }

  // epilogue: C/D layout col=lane&15, row=quad*4+reg
#pragma unroll
  for (int nt = 0; nt < 2; nt++) {
    int col = rowW + wn + nt * 16 + lr;
    float bv = d.bias[col];
#pragma unroll
    for (int mt = 0; mt < 2; mt++) {
#pragma unroll
      for (int rr = 0; rr < 4; rr++) {
        int row = rowA + wm + mt * 16 + quad * 4 + rr;
        float v = acc[mt][nt][rr] + bv;
        if (d.residleaky) {
          v = (v > 0.f) ? v : 0.01f * v;
          v += d.resid[(size_t)row * N + col];
          if (d.mask[row] == 0) v = 0.f;
          d.outf[(size_t)row * N + col] = v;
          d.out2b[(size_t)row * N + col] = f2bf(v);
        } else {
          d.outb[(size_t)row * N + col] = f2bf(v);
        }
      }
    }
  }
}

// ================= fp32-input MFMA GEMM for the embedding projection (gathered A, K=300)
__global__ __launch_bounds__(256) void gemm_embed(
    const float* __restrict__ A, const float* __restrict__ W, const float* __restrict__ bias,
    float* __restrict__ outf, u16* __restrict__ outb,
    const int* __restrict__ gather, int N, int K) {
  __shared__ u16 As[64][72];
  __shared__ u16 Ws[64][72];
  int t = threadIdx.x;
  int bm = blockIdx.x, bn = blockIdx.y;
  const int rowA = bm * 64, rowW = bn * 64;

  f32x4 acc[2][2];
#pragma unroll
  for (int i = 0; i < 2; i++)
#pragma unroll
    for (int j = 0; j < 2; j++)
      acc[i][j] = (f32x4){0.f, 0.f, 0.f, 0.f};

  const int srow = t >> 2, sc0 = (t & 3) * 16;
  const int wid = t >> 6, wm = (wid & 1) * 32, wn = (wid >> 1) * 32;
  const int lr = t & 15, quad = (t >> 4) & 3;

  const float* Arow = A + (size_t)gather[rowA + srow] * K;
  const float* Wrow = W + (size_t)(rowW + srow) * K;

  for (int kt = 0; kt < K; kt += 64) {
    __syncthreads();
    bool full = (kt + 64 <= K);
#pragma unroll
    for (int ch = 0; ch < 4; ch++) {
      int c = kt + sc0 + ch * 4;
      float4 fa, fw;
      if (full) {
        fa = *(const float4*)(Arow + c);
        fw = *(const float4*)(Wrow + c);
      } else {
        fa.x = (c + 0 < K) ? Arow[c + 0] : 0.f;
        fa.y = (c + 1 < K) ? Arow[c + 1] : 0.f;
        fa.z = (c + 2 < K) ? Arow[c + 2] : 0.f;
        fa.w = (c + 3 < K) ? Arow[c + 3] : 0.f;
        fw.x = (c + 0 < K) ? Wrow[c + 0] : 0.f;
        fw.y = (c + 1 < K) ? Wrow[c + 1] : 0.f;
        fw.z = (c + 2 < K) ? Wrow[c + 2] : 0.f;
        fw.w = (c + 3 < K) ? Wrow[c + 3] : 0.f;
      }
      *(uint2*)&As[srow][sc0 + ch * 4] = make_uint2(packbf(fa.x, fa.y), packbf(fa.z, fa.w));
      *(uint2*)&Ws[srow][sc0 + ch * 4] = make_uint2(packbf(fw.x, fw.y), packbf(fw.z, fw.w));
    }
    __syncthreads();
#pragma unroll
    for (int ks = 0; ks < 2; ks++) {
      bf16x8 af[2], bfr[2];
#pragma unroll
      for (int mt = 0; mt < 2; mt++)
        af[mt] = *(const bf16x8*)&As[wm + mt * 16 + lr][ks * 32 + quad * 8];
#pragma unroll
      for (int nt = 0; nt < 2; nt++)
        bfr[nt] = *(const bf16x8*)&Ws[wn + nt * 16 + lr][ks * 32 + quad * 8];
#pragma unroll
      for (int mt = 0; mt < 2; mt++)
#pragma unroll
        for (int nt = 0; nt < 2; nt++)
          acc[mt][nt] = __builtin_amdgcn_mfma_f32_16x16x32_bf16(af[mt], bfr[nt], acc[mt][nt], 0, 0, 0);
    }
  }
#pragma unroll
  for (int nt = 0; nt < 2; nt++) {
    int col = rowW + wn + nt * 16 + lr;
    float bv = bias[col];
#pragma unroll
    for (int mt = 0; mt < 2; mt++) {
#pragma unroll
      for (int rr = 0; rr < 4; rr++) {
        int row = rowA + wm + mt * 16 + quad * 4 + rr;
        float v = acc[mt][nt][rr] + bv;
        outf[(size_t)row * N + col] = v;       // nodes (fp32)
        outb[(size_t)row * N + col] = f2bf(v); // xb (bf16)
      }
    }
  }
}

// ---------------- relay = mean over L of nodes  (relay zeroed first)
__global__ __launch_bounds__(128) void relay_init_kernel(const float* __restrict__ x, float* __restrict__ relay) {
  int b = blockIdx.x >> 6, c = blockIdx.x & 63, t = threadIdx.x;
  float sum = 0.f;
  for (int i = 0; i < 32; i++) {
    int l = c * 32 + i;
    sum += x[((size_t)b * L + l) * D + t];
  }
  atomicAdd(&relay[b * D + t], sum * (1.0f / L));
}

// ---------------- shared device helper: relay projections from rel[] in LDS
__device__ __forceinline__ void do_relay_proj(
    int b, int di, int t, const float* rel,
    const float* rkw, const float* rkb, const float* rvw, const float* rvb,
    const float* sqw, const float* sqb, const float* skw, const float* skb_,
    float* relay_k, float* relay_v, float* u, float* cvec,
    float* sql, float* cred) {
  const float4* r4 = (const float4*)rel;
  if (di < 8) {
    int which = di >> 2;           // 0 = rk, 1 = rv
    int n = (di & 3) * 128 + t;
    const float* W = which ? rvw : rkw;
    float acc = (which ? rvb : rkb)[n];
    const float4* w4 = (const float4*)(W + (size_t)n * D);
#pragma unroll 8
    for (int i = 0; i < D / 4; i++) {
      float4 w = w4[i], r = r4[i];
      acc += w.x * r.x + w.y * r.y + w.z * r.z + w.w * r.w;
    }
    (which ? relay_v : relay_k)[(size_t)b * D2 + n] = acc;
  } else {
    int n = di - 8;
    {
      int nh = n * HD + t;
      float acc = sqb[nh];
      const float4* w4 = (const float4*)(sqw + (size_t)nh * D);
#pragma unroll 8
      for (int i = 0; i < D / 4; i++) {
        float4 w = w4[i], r = r4[i];
        acc += w.x * r.x + w.y * r.y + w.z * r.z + w.w * r.w;
      }
      sql[t] = acc;
    }
    __syncthreads();
    {
      float cp = sql[t] * skb_[n * HD + t];
#pragma unroll
      for (int o = 1; o < 64; o <<= 1) cp += __shfl_xor(cp, o, 64);
      if ((t & 63) == 0) cred[t >> 6] = cp;
    }
    float a0 = 0.f, a1 = 0.f, a2 = 0.f, a3 = 0.f;
    const float* wp = skw + (size_t)(n * HD) * D + t;
    for (int h = 0; h < HD; h += 4) {
      a0 += sql[h] * wp[(size_t)h * D];
      a1 += sql[h + 1] * wp[(size_t)(h + 1) * D];
      a2 += sql[h + 2] * wp[(size_t)(h + 2) * D];
      a3 += sql[h + 3] * wp[(size_t)(h + 3) * D];
    }
    u[((size_t)b * NH + n) * D + t] = (a0 + a1 + a2 + a3) * SCALE;
    __syncthreads();
    if (t == 0) cvec[b * NH + n] = (cred[0] + cred[1]) * SCALE;
  }
}

// ---------------- standalone relay projections (layer 0), grid (B,12) x 128
__global__ __launch_bounds__(128) void relay_proj(
    const float* __restrict__ relay,
    const float* __restrict__ rkw, const float* __restrict__ rkb,
    const float* __restrict__ rvw, const float* __restrict__ rvb,
    const float* __restrict__ sqw, const float* __restrict__ sqb,
    const float* __restrict__ skw, const float* __restrict__ skb_,
    float* __restrict__ relay_k, float* __restrict__ relay_v,
    float* __restrict__ u, float* __restrict__ cvec) {
  __shared__ float rel[D];
  __shared__ float sql[HD];
  __shared__ float cred[2];
  int b = blockIdx.x, di = blockIdx.y, t = threadIdx.x;
  rel[t] = relay[(size_t)b * D + t];
  __syncthreads();
  do_relay_proj(b, di, t, rel, rkw, rkb, rvw, rvb, sqw, sqb, skw, skb_,
                relay_k, relay_v, u, cvec, sql, cred);
}

// ---------------- ring (windowed) attention; bf16 q/k/v/ak/av + att, fp32 rk/rv
__global__ __launch_bounds__(256) void ring_attn_kernel(
    const u16* __restrict__ q, const u16* __restrict__ k, const u16* __restrict__ v,
    const u16* __restrict__ akr, const u16* __restrict__ avr,
    const float* __restrict__ rk, const float* __restrict__ rv,
    u16* __restrict__ att) {
  int bl = blockIdx.x;
  int b = bl >> 11, l = bl & (L - 1);
  int n = threadIdx.x >> 6, lane = threadIdx.x & 63;
  int h = lane << 1;
  size_t base = (size_t)bl * D2 + n * HD + h;
  float2 qv = bf2x2(*(const uint_t*)(q + base));
  float s[5], v0[5], v1[5];
#pragma unroll
  for (int u = 0; u < 5; u++) {
    float k0 = 0.f, k1 = 0.f, vv0 = 0.f, vv1 = 0.f;
    if (u < 3) {
      int ll = l + u - 1;
      if (ll >= 0 && ll < L) {
        size_t off = ((size_t)b * L + ll) * D2 + n * HD + h;
        float2 kf = bf2x2(*(const uint_t*)(k + off));
        float2 vf = bf2x2(*(const uint_t*)(v + off));
        k0 = kf.x; k1 = kf.y; vv0 = vf.x; vv1 = vf.y;
      }
    } else if (u == 3) {
      float2 kf = bf2x2(*(const uint_t*)(akr + base));
      float2 vf = bf2x2(*(const uint_t*)(avr + base));
      k0 = kf.x; k1 = kf.y; vv0 = vf.x; vv1 = vf.y;
    } else {
      size_t rb = (size_t)b * D2 + n * HD + h;
      k0 = rk[rb]; k1 = rk[rb + 1]; vv0 = rv[rb]; vv1 = rv[rb + 1];
    }
    float p = qv.x * k0 + qv.y * k1;
#pragma unroll
    for (int o = 1; o < 64; o <<= 1) p += __shfl_xor(p, o, 64);
    s[u] = p * SCALE;
    v0[u] = vv0; v1[u] = vv1;
  }
  float m = s[0];
#pragma unroll
  for (int u = 1; u < 5; u++) m = fmaxf(m, s[u]);
  float sum = 0.f, o0 = 0.f, o1 = 0.f;
#pragma unroll
  for (int u = 0; u < 5; u++) {
    float e = expf(s[u] - m);
    sum += e; o0 += e * v0[u]; o1 += e * v1[u];
  }
  *(uint_t*)(att + base) = packbf(o0 / sum, o1 / sum);
}

// ---------------- relay attention phase 1: scores from nodesb/relay vs u; partial wsum of rows
__global__ __launch_bounds__(256) void relay_attn_partial(
    const float* __restrict__ relay, const u16* __restrict__ nodesb,
    const float* __restrict__ u, const float* __restrict__ cvec,
    const int* __restrict__ mask,
    float* __restrict__ pm, float* __restrict__ ps, float* __restrict__ pw) {
  int bn = blockIdx.x;           // b*NH + n
  int b = bn >> 2;
  int c = blockIdx.y;
  int l0 = c * CHUNK;
  int nloc = min(CHUNK, L1 - l0);
  __shared__ float us[D];
  __shared__ float sc[CHUNK];
  __shared__ float red[4];
  __shared__ float accs[2][D];
  int t = threadIdx.x;
  if (t < D) us[t] = u[(size_t)bn * D + t];
  __syncthreads();
  float cb = cvec[bn];
  int wv = t >> 6, lane = t & 63;
  float2 qv = ((const float2*)us)[lane];
  for (int i = wv; i < nloc; i += 4) {
    int p = l0 + i;
    float2 kk;
    if (p == 0) kk = ((const float2*)(relay + (size_t)b * D))[lane];
    else kk = bf2x2(*(const uint_t*)(nodesb + ((size_t)b * L + p - 1) * D + 2 * lane));
    float s = qv.x * kk.x + qv.y * kk.y;
#pragma unroll
    for (int o = 1; o < 64; o <<= 1) s += __shfl_xor(s, o, 64);
    if (lane == 0) {
      s += cb;
      if (p > 0 && mask[b * L + p - 1] == 0) s = -1e30f;
      sc[i] = s;
    }
  }
  __syncthreads();
  float m = -1e30f;
  for (int i = t; i < nloc; i += 256) m = fmaxf(m, sc[i]);
#pragma unroll
  for (int o = 1; o < 64; o <<= 1) m = fmaxf(m, __shfl_xor(m, o, 64));
  if (lane == 0) red[wv] = m;
  __syncthreads();
  m = fmaxf(fmaxf(red[0], red[1]), fmaxf(red[2], red[3]));
  __syncthreads();
  float sum = 0.f;
  for (int i = t; i < nloc; i += 256) { float e = expf(sc[i] - m); sc[i] = e; sum += e; }
#pragma unroll
  for (int o = 1; o < 64; o <<= 1) sum += __shfl_xor(sum, o, 64);
  if (lane == 0) red[wv] = sum;
  __syncthreads();
  sum = red[0] + red[1] + red[2] + red[3];
  int h = t & 127, par = t >> 7;
  float o = 0.f;
  for (int i = par; i < nloc; i += 2) {
    int p = l0 + i;
    float val = (p == 0) ? relay[(size_t)b * D + h]
                         : bf2f(nodesb[((size_t)b * L + p - 1) * D + h]);
    o += sc[i] * val;
  }
  accs[par][h] = o;
  __syncthreads();
  if (t < D) pw[((size_t)bn * NCH + c) * D + t] = accs[0][t] + accs[1][t];
  if (t == 0) { pm[bn * NCH + c] = m; ps[bn * NCH + c] = sum; }
}

// ---------------- combine chunks -> satt -> relay; then (optional) next-layer projections
// grid (B, 12) when do_proj, else (B, 1); 128 threads
__global__ __launch_bounds__(128) void relay_final(
    const float* __restrict__ pm, const float* __restrict__ ps, const float* __restrict__ pw,
    const float* __restrict__ svw, const float* __restrict__ svb,
    const float* __restrict__ sow, const float* __restrict__ sob,
    const float* __restrict__ nrkw, const float* __restrict__ nrkb,
    const float* __restrict__ nrvw, const float* __restrict__ nrvb,
    const float* __restrict__ nsqw, const float* __restrict__ nsqb,
    const float* __restrict__ nskw, const float* __restrict__ nskb,
    float* __restrict__ relay_out,
    float* __restrict__ relay_k, float* __restrict__ relay_v,
    float* __restrict__ u, float* __restrict__ cvec, int do_proj) {
  int b = blockIdx.x, di = blockIdx.y, t = threadIdx.x;
  __shared__ float wsum[NH][D];
  __shared__ float satts[D2];
  __shared__ float rel[D];
  __shared__ float sql[HD];
  __shared__ float cred[2];
  // stage A: combine chunks; 4 groups of 32 threads, one head each; 4 h per thread
  {
    int n = t >> 5, lt = t & 31;
    int bn = b * NH + n;
    float M = -1e30f;
#pragma unroll
    for (int c = 0; c < NCH; c++) M = fmaxf(M, pm[bn * NCH + c]);
    float S = 0.f;
    float ec[NCH];
#pragma unroll
    for (int c = 0; c < NCH; c++) { ec[c] = expf(pm[bn * NCH + c] - M); S += ps[bn * NCH + c] * ec[c]; }
    float invS = 1.0f / S;
#pragma unroll
    for (int hh = 0; hh < 4; hh++) {
      int h = lt * 4 + hh;
      float o = 0.f;
#pragma unroll
      for (int c = 0; c < NCH; c++) o += ec[c] * pw[((size_t)bn * NCH + c) * D + h];
      wsum[n][h] = o * invS;
    }
  }
  __syncthreads();
  // stage B: satts[nh] = wsum·svw + svb (4 per thread)
#pragma unroll
  for (int rep = 0; rep < 4; rep++) {
    int nh = rep * 128 + t;
    int hn = nh >> 7;
    float acc = svb[nh];
    const float4* wp = (const float4*)(svw + (size_t)nh * D);
    const float4* wl = (const float4*)wsum[hn];
#pragma unroll 8
    for (int d = 0; d < D / 4; d++) {
      float4 a = wl[d], wv4 = wp[d];
      acc += a.x * wv4.x + a.y * wv4.y + a.z * wv4.z + a.w * wv4.w;
    }
    satts[nh] = acc;
  }
  __syncthreads();
  // stage C: rel[t] = leaky(satts·sow[t,:] + sob[t])
  {
    float acc = sob[t];
    const float4* wp = (const float4*)(sow + (size_t)t * D2);
    const float4* a4 = (const float4*)satts;
#pragma unroll 8
    for (int j = 0; j < D2 / 4; j++) {
      float4 a = a4[j], wv4 = wp[j];
      acc += a.x * wv4.x + a.y * wv4.y + a.z * wv4.z + a.w * wv4.w;
    }
    acc = (acc > 0.f) ? acc : 0.01f * acc;
    rel[t] = acc;
    relay_out[(size_t)b * D + t] = acc;
  }
  __syncthreads();
  if (do_proj)
    do_relay_proj(b, di, t, rel, nrkw, nrkb, nrvw, nrvb, nsqw, nsqb, nskw, nskb,
                  relay_k, relay_v, u, cvec, sql, cred);
}

extern "C" void kernel_launch(void* const* d_in, const int* in_sizes, int n_in,
                              void* d_out, int out_size, void* d_ws, size_t ws_size,
                              hipStream_t stream) {
  const int* tokens = (const int*)d_in[0];
  const int* mask = (const int*)d_in[1];
  const float* emb = (const float*)d_in[2];
  const float* proj_w = (const float*)d_in[3];
  const float* proj_b = (const float*)d_in[4];
  const float* ng = (const float*)d_in[5];
  const float* nb = (const float*)d_in[6];
  const float* rq_w = (const float*)d_in[7], * rq_b = (const float*)d_in[8];
  const float* rk_w = (const float*)d_in[9], * rk_b = (const float*)d_in[10];
  const float* rv_w = (const float*)d_in[11], * rv_b = (const float*)d_in[12];
  const float* ro_w = (const float*)d_in[13], * ro_b = (const float*)d_in[14];
  const float* sq_w = (const float*)d_in[15], * sq_b = (const float*)d_in[16];
  const float* sk_w = (const float*)d_in[17], * sk_b = (const float*)d_in[18];
  const float* sv_w = (const float*)d_in[19], * sv_b = (const float*)d_in[20];
  const float* so_w = (const float*)d_in[21], * so_b = (const float*)d_in[22];

  const size_t BLD = (size_t)B * L * D;        // 1,048,576
  const size_t BLD4 = (size_t)B * L * D2;      // 4,194,304
  const size_t WTEN = (size_t)NL * D * D2;     // 196,608 per tensor

  float* fp = (float*)d_ws;
  float* nodes = fp;                    fp += BLD;
  float* relay = fp;                    fp += B * D;
  float* relay_k = fp;                  fp += B * D2;
  float* relay_v = fp;                  fp += B * D2;
  float* uvec = fp;                     fp += B * NH * D;
  float* cvec = fp;                     fp += B * NH;
  float* pm = fp;                       fp += B * NH * NCH;
  float* ps = fp;                       fp += B * NH * NCH;
  float* pw = fp;                       fp += (size_t)B * NH * NCH * D;
  u16* up = (u16*)fp;
  u16* xb = up;                         up += BLD;
  u16* nodesb = up;                     up += BLD;
  u16* qb = up;                         up += BLD4;
  u16* kb = up;                         up += BLD4;
  u16* vb = up;                         up += BLD4;
  u16* akb = up;                        up += BLD4;
  u16* avb = up;                        up += BLD4;
  u16* attb = up;                       up += BLD4;
  u16* wb = up;                         // 4 * WTEN
  u16* wrq = wb, * wrk = wb + WTEN, * wrv = wb + 2 * WTEN, * wro = wb + 3 * WTEN;

  hipMemsetAsync(relay, 0, B * D * sizeof(float), stream);

  // convert ring-side weights to bf16 (one-time per launch)
  {
    WCArgs wa;
    wa.s[0] = rq_w; wa.s[1] = rk_w; wa.s[2] = rv_w; wa.s[3] = ro_w;
    wa.d[0] = wrq; wa.d[1] = wrk; wa.d[2] = wrv; wa.d[3] = wro;
    wconv<<<dim3(WTEN / 1024, 4), 256, 0, stream>>>(wa);
  }
  // embedding projection: nodes (fp32) + xb (bf16)
  gemm_embed<<<dim3(128, 2), 256, 0, stream>>>(emb, proj_w, proj_b, nodes, xb, tokens, D, E);
  relay_init_kernel<<<B * 64, 128, 0, stream>>>(nodes, relay);
  // layer-0 relay-side projections
  relay_proj<<<dim3(B, 12), 128, 0, stream>>>(relay, rk_w, rk_b, rv_w, rv_b, sq_w, sq_b,
                                              sk_w, sk_b, relay_k, relay_v, uvec, cvec);

  for (int i = 0; i < NL; i++) {
    const size_t wo = (size_t)i * D * D2;
    const float* rqbi = rq_b + (size_t)i * D2;
    const float* rkbi = rk_b + (size_t)i * D2;
    const float* rvbi = rv_b + (size_t)i * D2;
    const float* robi = ro_b + (size_t)i * D;
    const float* svwi = sv_w + wo, * svbi = sv_b + (size_t)i * D2;
    const float* sowi = so_w + wo, * sobi = so_b + (size_t)i * D;

    // fused LN + q,k,v (from nodes) + ak,av (from xb): one dispatch
    {
      GArgs ga = {};
      ga.d[0].Af32 = nodes; ga.d[0].lng = ng + i * D; ga.d[0].lnb = nb + i * D;
      ga.d[0].W = wrq + wo; ga.d[0].bias = rqbi; ga.d[0].outb = qb;
      ga.d[1].Af32 = nodes; ga.d[1].lng = ng + i * D; ga.d[1].lnb = nb + i * D;
      ga.d[1].W = wrk + wo; ga.d[1].bias = rkbi; ga.d[1].outb = kb;
      ga.d[2].Af32 = nodes; ga.d[2].lng = ng + i * D; ga.d[2].lnb = nb + i * D;
      ga.d[2].W = wrv + wo; ga.d[2].bias = rvbi; ga.d[2].outb = vb;
      ga.d[3].A = xb;  ga.d[3].W = wrk + wo; ga.d[3].bias = rkbi; ga.d[3].outb = akb;
      ga.d[4].A = xb;  ga.d[4].W = wrv + wo; ga.d[4].bias = rvbi; ga.d[4].outb = avb;
      gemm_bf<<<dim3(128, 40), 256, 0, stream>>>(ga, 8, D2, D);
    }
    ring_attn_kernel<<<B * L, 256, 0, stream>>>(qb, kb, vb, akb, avb, relay_k, relay_v, attb);
    // nodes = where(pad, 0, nodes + leaky(att @ ro^T + ro_b)); also nodesb (bf16)
    {
      GArgs ga = {};
      ga.d[0].A = attb; ga.d[0].W = wro + wo; ga.d[0].bias = robi;
      ga.d[0].outf = nodes; ga.d[0].resid = nodes; ga.d[0].out2b = nodesb;
      ga.d[0].mask = mask; ga.d[0].residleaky = 1;
      gemm_bf<<<dim3(128, 2), 256, 0, stream>>>(ga, 2, D, D2);
    }
    relay_attn_partial<<<dim3(B * NH, NCH), 256, 0, stream>>>(relay, nodesb, uvec, cvec, mask, pm, ps, pw);
    // combine + project relay; fuse next layer's relay-side projections
    int last = (i == NL - 1);
    const size_t wn_ = (size_t)(i + 1) * D * D2;
    float* relay_dst = last ? (float*)d_out : relay;
    relay_final<<<dim3(B, last ? 1 : 12), 128, 0, stream>>>(
        pm, ps, pw, svwi, svbi, sowi, sobi,
        last ? nullptr : rk_w + wn_, last ? nullptr : rk_b + (size_t)(i + 1) * D2,
        last ? nullptr : rv_w + wn_, last ? nullptr : rv_b + (size_t)(i + 1) * D2,
        last ? nullptr : sq_w + wn_, last ? nullptr : sq_b + (size_t)(i + 1) * D2,
        last ? nullptr : sk_w + wn_, last ? nullptr : sk_b + (size_t)(i + 1) * D2,
        relay_dst, relay_k, relay_v, uvec, cvec, last ? 0 : 1);
  }
}

// Round 10
// 441.064 us; speedup vs baseline: 1.0896x; 1.0896x over previous
//
#include <hip/hip_runtime.h>
#include <hip/hip_bf16.h>

// Problem constants
constexpr int B = 4, L = 2048, E = 300, D = 128, NH = 4, HD = 128, NL = 3, D2 = 512;
constexpr int L1 = L + 1; // 2049
constexpr float EPS = 1e-5f;
constexpr float SCALE = 0.08838834764831843f; // 1/sqrt(128)
constexpr int NCH = 32;              // relay-attention L-chunks
constexpr int CHUNK = 65;            // ceil(2049/32)

typedef unsigned int uint_t;
typedef unsigned short u16;
typedef short bf16x8 __attribute__((ext_vector_type(8)));
typedef float f32x4 __attribute__((ext_vector_type(4)));

__device__ __forceinline__ u16 f2bf(float f) {
  union { float f; uint_t i; } x; x.f = f;
  uint_t r = x.i + 0x7fffu + ((x.i >> 16) & 1u);
  return (u16)(r >> 16);
}
__device__ __forceinline__ uint_t packbf(float a, float b) {
  return (uint_t)f2bf(a) | ((uint_t)f2bf(b) << 16);
}
__device__ __forceinline__ float bf2f(u16 u) {
  union { uint_t i; float f; } x; x.i = ((uint_t)u) << 16; return x.f;
}
__device__ __forceinline__ float2 bf2x2(uint_t u) {
  union { uint_t i; float f; } a, b;
  a.i = (u & 0xffffu) << 16; b.i = u & 0xffff0000u;
  return make_float2(a.f, b.f);
}

// ---------------- weight pre-conversion: 4 tensors (rq,rk,rv,ro), NL*D*D2 fp32 -> bf16
struct WCArgs { const float* s[4]; u16* d[4]; };
__global__ __launch_bounds__(256) void wconv(WCArgs wa) {
  int ti = blockIdx.y;
  const float* s = wa.s[ti]; u16* dd = wa.d[ti];
  int i = (blockIdx.x * 256 + threadIdx.x) * 4;
  float4 f = *(const float4*)(s + i);
  *(uint2*)(dd + i) = make_uint2(packbf(f.x, f.y), packbf(f.z, f.w));
}

// ================= all-bf16 MFMA GEMM, BK=128: out[M,N] = A[M,K] @ W[N,K]^T + bias (bf16 out)
// 64x64 tile, 256 threads = 4 waves 2x2 (each 32x32).
struct GDesc {
  const u16* A; const u16* W; const float* bias; u16* outb;
};
struct GArgs { GDesc d[5]; };

__global__ __launch_bounds__(256) void gemm_bf(GArgs ga, int nby, int N, int K) {
  __shared__ u16 As[64][136];
  __shared__ u16 Ws[64][136];
  int t = threadIdx.x;
  int bm = blockIdx.x;
  int di = blockIdx.y / nby, bn = blockIdx.y - di * nby;
  GDesc d = ga.d[di];
  const int rowA = bm * 64, rowW = bn * 64;

  f32x4 acc[2][2];
#pragma unroll
  for (int i = 0; i < 2; i++)
#pragma unroll
    for (int j = 0; j < 2; j++)
      acc[i][j] = (f32x4){0.f, 0.f, 0.f, 0.f};

  const int r = t >> 2;             // 0..63
  const int c0 = (t & 3) * 32;      // 0,32,64,96 (shorts)
  const int wid = t >> 6;
  const int wm = (wid & 1) * 32, wn = (wid >> 1) * 32;
  const int lr = t & 15, quad = (t >> 4) & 3;

  const u16* Arow = d.A + (size_t)(rowA + r) * K;
  const u16* Wrow = d.W + (size_t)(rowW + r) * K;

  for (int kt = 0; kt < K; kt += 128) {
    uint4 a0 = *(const uint4*)(Arow + kt + c0);
    uint4 a1 = *(const uint4*)(Arow + kt + c0 + 8);
    uint4 a2 = *(const uint4*)(Arow + kt + c0 + 16);
    uint4 a3 = *(const uint4*)(Arow + kt + c0 + 24);
    uint4 w0 = *(const uint4*)(Wrow + kt + c0);
    uint4 w1 = *(const uint4*)(Wrow + kt + c0 + 8);
    uint4 w2 = *(const uint4*)(Wrow + kt + c0 + 16);
    uint4 w3 = *(const uint4*)(Wrow + kt + c0 + 24);
    __syncthreads();
    *(uint4*)&As[r][c0] = a0; *(uint4*)&As[r][c0 + 8] = a1;
    *(uint4*)&As[r][c0 + 16] = a2; *(uint4*)&As[r][c0 + 24] = a3;
    *(uint4*)&Ws[r][c0] = w0; *(uint4*)&Ws[r][c0 + 8] = w1;
    *(uint4*)&Ws[r][c0 + 16] = w2; *(uint4*)&Ws[r][c0 + 24] = w3;
    __syncthreads();
#pragma unroll
    for (int ks = 0; ks < 4; ks++) {
      bf16x8 af[2], bfr[2];
#pragma unroll
      for (int mt = 0; mt < 2; mt++)
        af[mt] = *(const bf16x8*)&As[wm + mt * 16 + lr][ks * 32 + quad * 8];
#pragma unroll
      for (int nt = 0; nt < 2; nt++)
        bfr[nt] = *(const bf16x8*)&Ws[wn + nt * 16 + lr][ks * 32 + quad * 8];
#pragma unroll
      for (int mt = 0; mt < 2; mt++)
#pragma unroll
        for (int nt = 0; nt < 2; nt++)
          acc[mt][nt] = __builtin_amdgcn_mfma_f32_16x16x32_bf16(af[mt], bfr[nt], acc[mt][nt], 0, 0, 0);
    }
  }

  // epilogue: C/D layout col=lane&15, row=quad*4+reg
#pragma unroll
  for (int nt = 0; nt < 2; nt++) {
    int col = rowW + wn + nt * 16 + lr;
    float bv = d.bias[col];
#pragma unroll
    for (int mt = 0; mt < 2; mt++) {
#pragma unroll
      for (int rr = 0; rr < 4; rr++) {
        int row = rowA + wm + mt * 16 + quad * 4 + rr;
        d.outb[(size_t)row * N + col] = f2bf(acc[mt][nt][rr] + bv);
      }
    }
  }
}

// ================= ro GEMM (64x128 tile, K=512) + residual + mask + fused next-layer LN
// out: nodes (fp32), nodesb (bf16), nxb (bf16 LN'd, if do_ln)
__global__ __launch_bounds__(256) void gemm_ro_ln(
    const u16* __restrict__ A,      // attb [B*L, 512]
    const u16* __restrict__ W,      // ro_w bf16 [128, 512]
    const float* __restrict__ bias, // ro_b [128]
    const int* __restrict__ mask,
    const float* __restrict__ lng, const float* __restrict__ lnb,
    float* __restrict__ nodes, u16* __restrict__ nodesb, u16* __restrict__ nxb,
    int do_ln) {
  __shared__ u16 As[64][136];       // 17408 B
  __shared__ u16 Ws[128][136];      // 34816 B
  __shared__ float C[64][132];      // 33792 B (528B row stride, 16B-aligned)
  __shared__ float gb[2][D];
  __shared__ float lmu[64], lrs[64];
  int t = threadIdx.x;
  int bm = blockIdx.x;
  const int rowA0 = bm * 64;

  f32x4 acc[2][4];
#pragma unroll
  for (int i = 0; i < 2; i++)
#pragma unroll
    for (int j = 0; j < 4; j++)
      acc[i][j] = (f32x4){0.f, 0.f, 0.f, 0.f};

  const int wid = t >> 6;
  const int wm = (wid & 1) * 32, wn = (wid >> 1) * 64;
  const int lr = t & 15, quad = (t >> 4) & 3;
  const int ra = t >> 2, ca = (t & 3) * 32;   // A staging: 64 rows x 128 k
  const int rw = t >> 1, cw = (t & 1) * 64;   // W staging: 128 rows x 128 k (64 shorts/thread)

  if (do_ln && t < D) { gb[0][t] = lng[t]; gb[1][t] = lnb[t]; }

  const u16* Arow = A + (size_t)(rowA0 + ra) * 512;
  const u16* Wrow = W + (size_t)rw * 512;

  for (int kt = 0; kt < 512; kt += 128) {
    uint4 a0 = *(const uint4*)(Arow + kt + ca);
    uint4 a1 = *(const uint4*)(Arow + kt + ca + 8);
    uint4 a2 = *(const uint4*)(Arow + kt + ca + 16);
    uint4 a3 = *(const uint4*)(Arow + kt + ca + 24);
    uint4 w0 = *(const uint4*)(Wrow + kt + cw);
    uint4 w1 = *(const uint4*)(Wrow + kt + cw + 8);
    uint4 w2 = *(const uint4*)(Wrow + kt + cw + 16);
    uint4 w3 = *(const uint4*)(Wrow + kt + cw + 24);
    uint4 w4 = *(const uint4*)(Wrow + kt + cw + 32);
    uint4 w5 = *(const uint4*)(Wrow + kt + cw + 40);
    uint4 w6 = *(const uint4*)(Wrow + kt + cw + 48);
    uint4 w7 = *(const uint4*)(Wrow + kt + cw + 56);
    __syncthreads();
    *(uint4*)&As[ra][ca] = a0; *(uint4*)&As[ra][ca + 8] = a1;
    *(uint4*)&As[ra][ca + 16] = a2; *(uint4*)&As[ra][ca + 24] = a3;
    *(uint4*)&Ws[rw][cw] = w0; *(uint4*)&Ws[rw][cw + 8] = w1;
    *(uint4*)&Ws[rw][cw + 16] = w2; *(uint4*)&Ws[rw][cw + 24] = w3;
    *(uint4*)&Ws[rw][cw + 32] = w4; *(uint4*)&Ws[rw][cw + 40] = w5;
    *(uint4*)&Ws[rw][cw + 48] = w6; *(uint4*)&Ws[rw][cw + 56] = w7;
    __syncthreads();
#pragma unroll
    for (int ks = 0; ks < 4; ks++) {
      bf16x8 af[2], bfr[4];
#pragma unroll
      for (int mt = 0; mt < 2; mt++)
        af[mt] = *(const bf16x8*)&As[wm + mt * 16 + lr][ks * 32 + quad * 8];
#pragma unroll
      for (int nt = 0; nt < 4; nt++)
        bfr[nt] = *(const bf16x8*)&Ws[wn + nt * 16 + lr][ks * 32 + quad * 8];
#pragma unroll
      for (int mt = 0; mt < 2; mt++)
#pragma unroll
        for (int nt = 0; nt < 4; nt++)
          acc[mt][nt] = __builtin_amdgcn_mfma_f32_16x16x32_bf16(af[mt], bfr[nt], acc[mt][nt], 0, 0, 0);
    }
  }
  __syncthreads();
  // epilogue into LDS C: v = mask ? 0 : resid + leaky(acc + bias)
#pragma unroll
  for (int nt = 0; nt < 4; nt++) {
    int col = wn + nt * 16 + lr;
    float bv = bias[col];
#pragma unroll
    for (int mt = 0; mt < 2; mt++) {
#pragma unroll
      for (int rr = 0; rr < 4; rr++) {
        int row = wm + mt * 16 + quad * 4 + rr;
        float v = acc[mt][nt][rr] + bv;
        v = (v > 0.f) ? v : 0.01f * v;
        v += nodes[(size_t)(rowA0 + row) * D + col];
        if (mask[rowA0 + row] == 0) v = 0.f;
        C[row][col] = v;
      }
    }
  }
  __syncthreads();
  // LN stats per row (threads 0..63)
  if (t < 64) {
    float s = 0.f, s2 = 0.f;
#pragma unroll 16
    for (int j = 0; j < D; j++) { float v = C[t][j]; s += v; s2 += v * v; }
    float mu = s * (1.0f / D);
    float var = s2 * (1.0f / D) - mu * mu;
    lmu[t] = mu; lrs[t] = rsqrtf(var + EPS);
  }
  __syncthreads();
  // coalesced writes: 8 float4 per thread
#pragma unroll
  for (int rep = 0; rep < 8; rep++) {
    int lin = rep * 1024 + t * 4;
    int row = lin >> 7, col = lin & 127;
    float4 v = *(const float4*)&C[row][col];
    size_t g = (size_t)(rowA0 + row) * D + col;
    *(float4*)&nodes[g] = v;
    *(uint2*)&nodesb[g] = make_uint2(packbf(v.x, v.y), packbf(v.z, v.w));
    if (do_ln) {
      float mu = lmu[row], rs = lrs[row];
      float o0 = (v.x - mu) * rs * gb[0][col] + gb[1][col];
      float o1 = (v.y - mu) * rs * gb[0][col + 1] + gb[1][col + 1];
      float o2 = (v.z - mu) * rs * gb[0][col + 2] + gb[1][col + 2];
      float o3 = (v.w - mu) * rs * gb[0][col + 3] + gb[1][col + 3];
      *(uint2*)&nxb[g] = make_uint2(packbf(o0, o1), packbf(o2, o3));
    }
  }
}

// ================= fp32-input MFMA GEMM for the embedding projection (gathered A, K=300)
__global__ __launch_bounds__(256) void gemm_embed(
    const float* __restrict__ A, const float* __restrict__ W, const float* __restrict__ bias,
    float* __restrict__ outf, u16* __restrict__ outb,
    const int* __restrict__ gather, int N, int K) {
  __shared__ u16 As[64][72];
  __shared__ u16 Ws[64][72];
  int t = threadIdx.x;
  int bm = blockIdx.x, bn = blockIdx.y;
  const int rowA = bm * 64, rowW = bn * 64;

  f32x4 acc[2][2];
#pragma unroll
  for (int i = 0; i < 2; i++)
#pragma unroll
    for (int j = 0; j < 2; j++)
      acc[i][j] = (f32x4){0.f, 0.f, 0.f, 0.f};

  const int srow = t >> 2, sc0 = (t & 3) * 16;
  const int wid = t >> 6, wm = (wid & 1) * 32, wn = (wid >> 1) * 32;
  const int lr = t & 15, quad = (t >> 4) & 3;

  const float* Arow = A + (size_t)gather[rowA + srow] * K;
  const float* Wrow = W + (size_t)(rowW + srow) * K;

  for (int kt = 0; kt < K; kt += 64) {
    __syncthreads();
    bool full = (kt + 64 <= K);
#pragma unroll
    for (int ch = 0; ch < 4; ch++) {
      int c = kt + sc0 + ch * 4;
      float4 fa, fw;
      if (full) {
        fa = *(const float4*)(Arow + c);
        fw = *(const float4*)(Wrow + c);
      } else {
        fa.x = (c + 0 < K) ? Arow[c + 0] : 0.f;
        fa.y = (c + 1 < K) ? Arow[c + 1] : 0.f;
        fa.z = (c + 2 < K) ? Arow[c + 2] : 0.f;
        fa.w = (c + 3 < K) ? Arow[c + 3] : 0.f;
        fw.x = (c + 0 < K) ? Wrow[c + 0] : 0.f;
        fw.y = (c + 1 < K) ? Wrow[c + 1] : 0.f;
        fw.z = (c + 2 < K) ? Wrow[c + 2] : 0.f;
        fw.w = (c + 3 < K) ? Wrow[c + 3] : 0.f;
      }
      *(uint2*)&As[srow][sc0 + ch * 4] = make_uint2(packbf(fa.x, fa.y), packbf(fa.z, fa.w));
      *(uint2*)&Ws[srow][sc0 + ch * 4] = make_uint2(packbf(fw.x, fw.y), packbf(fw.z, fw.w));
    }
    __syncthreads();
#pragma unroll
    for (int ks = 0; ks < 2; ks++) {
      bf16x8 af[2], bfr[2];
#pragma unroll
      for (int mt = 0; mt < 2; mt++)
        af[mt] = *(const bf16x8*)&As[wm + mt * 16 + lr][ks * 32 + quad * 8];
#pragma unroll
      for (int nt = 0; nt < 2; nt++)
        bfr[nt] = *(const bf16x8*)&Ws[wn + nt * 16 + lr][ks * 32 + quad * 8];
#pragma unroll
      for (int mt = 0; mt < 2; mt++)
#pragma unroll
        for (int nt = 0; nt < 2; nt++)
          acc[mt][nt] = __builtin_amdgcn_mfma_f32_16x16x32_bf16(af[mt], bfr[nt], acc[mt][nt], 0, 0, 0);
    }
  }
#pragma unroll
  for (int nt = 0; nt < 2; nt++) {
    int col = rowW + wn + nt * 16 + lr;
    float bv = bias[col];
#pragma unroll
    for (int mt = 0; mt < 2; mt++) {
#pragma unroll
      for (int rr = 0; rr < 4; rr++) {
        int row = rowA + wm + mt * 16 + quad * 4 + rr;
        float v = acc[mt][nt][rr] + bv;
        outf[(size_t)row * N + col] = v;       // nodes (fp32)
        outb[(size_t)row * N + col] = f2bf(v); // xb (bf16)
      }
    }
  }
}

// ---------------- relay = mean over L of nodes  (relay zeroed first)
__global__ __launch_bounds__(128) void relay_init_kernel(const float* __restrict__ x, float* __restrict__ relay) {
  int b = blockIdx.x >> 6, c = blockIdx.x & 63, t = threadIdx.x;
  float sum = 0.f;
  for (int i = 0; i < 32; i++) {
    int l = c * 32 + i;
    sum += x[((size_t)b * L + l) * D + t];
  }
  atomicAdd(&relay[b * D + t], sum * (1.0f / L));
}

// ---------------- layernorm (fp32 in, bf16 out) — layer 0 only
__global__ __launch_bounds__(128) void ln_kernel(
    const float* __restrict__ in, u16* __restrict__ out,
    const float* __restrict__ g, const float* __restrict__ bb) {
  int row = blockIdx.x, t = threadIdx.x;
  float v = in[(size_t)row * D + t];
  float s = v, s2 = v * v;
#pragma unroll
  for (int o = 1; o < 64; o <<= 1) { s += __shfl_xor(s, o, 64); s2 += __shfl_xor(s2, o, 64); }
  __shared__ float rs[2], rs2[2];
  int w = t >> 6;
  if ((t & 63) == 0) { rs[w] = s; rs2[w] = s2; }
  __syncthreads();
  float S = rs[0] + rs[1], S2 = rs2[0] + rs2[1];
  float mu = S * (1.0f / D);
  float var = S2 * (1.0f / D) - mu * mu;
  float r = rsqrtf(var + EPS);
  out[(size_t)row * D + t] = f2bf((v - mu) * r * g[t] + bb[t]);
}

// ---------------- shared device helper: relay projections from rel[] in LDS
__device__ __forceinline__ void do_relay_proj(
    int b, int di, int t, const float* rel,
    const float* rkw, const float* rkb, const float* rvw, const float* rvb,
    const float* sqw, const float* sqb, const float* skw, const float* skb_,
    float* relay_k, float* relay_v, float* u, float* cvec,
    float* sql, float* cred) {
  const float4* r4 = (const float4*)rel;
  if (di < 8) {
    int which = di >> 2;           // 0 = rk, 1 = rv
    int n = (di & 3) * 128 + t;
    const float* W = which ? rvw : rkw;
    float acc = (which ? rvb : rkb)[n];
    const float4* w4 = (const float4*)(W + (size_t)n * D);
#pragma unroll 8
    for (int i = 0; i < D / 4; i++) {
      float4 w = w4[i], r = r4[i];
      acc += w.x * r.x + w.y * r.y + w.z * r.z + w.w * r.w;
    }
    (which ? relay_v : relay_k)[(size_t)b * D2 + n] = acc;
  } else {
    int n = di - 8;
    {
      int nh = n * HD + t;
      float acc = sqb[nh];
      const float4* w4 = (const float4*)(sqw + (size_t)nh * D);
#pragma unroll 8
      for (int i = 0; i < D / 4; i++) {
        float4 w = w4[i], r = r4[i];
        acc += w.x * r.x + w.y * r.y + w.z * r.z + w.w * r.w;
      }
      sql[t] = acc;
    }
    __syncthreads();
    {
      float cp = sql[t] * skb_[n * HD + t];
#pragma unroll
      for (int o = 1; o < 64; o <<= 1) cp += __shfl_xor(cp, o, 64);
      if ((t & 63) == 0) cred[t >> 6] = cp;
    }
    float a0 = 0.f, a1 = 0.f, a2 = 0.f, a3 = 0.f;
    const float* wp = skw + (size_t)(n * HD) * D + t;
    for (int h = 0; h < HD; h += 4) {
      a0 += sql[h] * wp[(size_t)h * D];
      a1 += sql[h + 1] * wp[(size_t)(h + 1) * D];
      a2 += sql[h + 2] * wp[(size_t)(h + 2) * D];
      a3 += sql[h + 3] * wp[(size_t)(h + 3) * D];
    }
    u[((size_t)b * NH + n) * D + t] = (a0 + a1 + a2 + a3) * SCALE;
    __syncthreads();
    if (t == 0) cvec[b * NH + n] = (cred[0] + cred[1]) * SCALE;
  }
}

// ---------------- standalone relay projections (layer 0), grid (B,12) x 128
__global__ __launch_bounds__(128) void relay_proj(
    const float* __restrict__ relay,
    const float* __restrict__ rkw, const float* __restrict__ rkb,
    const float* __restrict__ rvw, const float* __restrict__ rvb,
    const float* __restrict__ sqw, const float* __restrict__ sqb,
    const float* __restrict__ skw, const float* __restrict__ skb_,
    float* __restrict__ relay_k, float* __restrict__ relay_v,
    float* __restrict__ u, float* __restrict__ cvec) {
  __shared__ float rel[D];
  __shared__ float sql[HD];
  __shared__ float cred[2];
  int b = blockIdx.x, di = blockIdx.y, t = threadIdx.x;
  rel[t] = relay[(size_t)b * D + t];
  __syncthreads();
  do_relay_proj(b, di, t, rel, rkw, rkb, rvw, rvb, sqw, sqb, skw, skb_,
                relay_k, relay_v, u, cvec, sql, cred);
}

// ---------------- ring (windowed) attention; bf16 q/k/v/ak/av + att, fp32 rk/rv
__global__ __launch_bounds__(256) void ring_attn_kernel(
    const u16* __restrict__ q, const u16* __restrict__ k, const u16* __restrict__ v,
    const u16* __restrict__ akr, const u16* __restrict__ avr,
    const float* __restrict__ rk, const float* __restrict__ rv,
    u16* __restrict__ att) {
  int bl = blockIdx.x;
  int b = bl >> 11, l = bl & (L - 1);
  int n = threadIdx.x >> 6, lane = threadIdx.x & 63;
  int h = lane << 1;
  size_t base = (size_t)bl * D2 + n * HD + h;
  float2 qv = bf2x2(*(const uint_t*)(q + base));
  float s[5], v0[5], v1[5];
#pragma unroll
  for (int u = 0; u < 5; u++) {
    float k0 = 0.f, k1 = 0.f, vv0 = 0.f, vv1 = 0.f;
    if (u < 3) {
      int ll = l + u - 1;
      if (ll >= 0 && ll < L) {
        size_t off = ((size_t)b * L + ll) * D2 + n * HD + h;
        float2 kf = bf2x2(*(const uint_t*)(k + off));
        float2 vf = bf2x2(*(const uint_t*)(v + off));
        k0 = kf.x; k1 = kf.y; vv0 = vf.x; vv1 = vf.y;
      }
    } else if (u == 3) {
      float2 kf = bf2x2(*(const uint_t*)(akr + base));
      float2 vf = bf2x2(*(const uint_t*)(avr + base));
      k0 = kf.x; k1 = kf.y; vv0 = vf.x; vv1 = vf.y;
    } else {
      size_t rb = (size_t)b * D2 + n * HD + h;
      k0 = rk[rb]; k1 = rk[rb + 1]; vv0 = rv[rb]; vv1 = rv[rb + 1];
    }
    float p = qv.x * k0 + qv.y * k1;
#pragma unroll
    for (int o = 1; o < 64; o <<= 1) p += __shfl_xor(p, o, 64);
    s[u] = p * SCALE;
    v0[u] = vv0; v1[u] = vv1;
  }
  float m = s[0];
#pragma unroll
  for (int u = 1; u < 5; u++) m = fmaxf(m, s[u]);
  float sum = 0.f, o0 = 0.f, o1 = 0.f;
#pragma unroll
  for (int u = 0; u < 5; u++) {
    float e = expf(s[u] - m);
    sum += e; o0 += e * v0[u]; o1 += e * v1[u];
  }
  *(uint_t*)(att + base) = packbf(o0 / sum, o1 / sum);
}

// ---------------- relay attention phase 1: scores from nodesb/relay vs u; partial wsum of rows
__global__ __launch_bounds__(256) void relay_attn_partial(
    const float* __restrict__ relay, const u16* __restrict__ nodesb,
    const float* __restrict__ u, const float* __restrict__ cvec,
    const int* __restrict__ mask,
    float* __restrict__ pm, float* __restrict__ ps, float* __restrict__ pw) {
  int bn = blockIdx.x;           // b*NH + n
  int b = bn >> 2;
  int c = blockIdx.y;
  int l0 = c * CHUNK;
  int nloc = min(CHUNK, L1 - l0);
  __shared__ float us[D];
  __shared__ float sc[CHUNK];
  __shared__ float red[4];
  __shared__ float accs[2][D];
  int t = threadIdx.x;
  if (t < D) us[t] = u[(size_t)bn * D + t];
  __syncthreads();
  float cb = cvec[bn];
  int wv = t >> 6, lane = t & 63;
  float2 qv = ((const float2*)us)[lane];
  for (int i = wv; i < nloc; i += 4) {
    int p = l0 + i;
    float2 kk;
    if (p == 0) kk = ((const float2*)(relay + (size_t)b * D))[lane];
    else kk = bf2x2(*(const uint_t*)(nodesb + ((size_t)b * L + p - 1) * D + 2 * lane));
    float s = qv.x * kk.x + qv.y * kk.y;
#pragma unroll
    for (int o = 1; o < 64; o <<= 1) s += __shfl_xor(s, o, 64);
    if (lane == 0) {
      s += cb;
      if (p > 0 && mask[b * L + p - 1] == 0) s = -1e30f;
      sc[i] = s;
    }
  }
  __syncthreads();
  float m = -1e30f;
  for (int i = t; i < nloc; i += 256) m = fmaxf(m, sc[i]);
#pragma unroll
  for (int o = 1; o < 64; o <<= 1) m = fmaxf(m, __shfl_xor(m, o, 64));
  if (lane == 0) red[wv] = m;
  __syncthreads();
  m = fmaxf(fmaxf(red[0], red[1]), fmaxf(red[2], red[3]));
  __syncthreads();
  float sum = 0.f;
  for (int i = t; i < nloc; i += 256) { float e = expf(sc[i] - m); sc[i] = e; sum += e; }
#pragma unroll
  for (int o = 1; o < 64; o <<= 1) sum += __shfl_xor(sum, o, 64);
  if (lane == 0) red[wv] = sum;
  __syncthreads();
  sum = red[0] + red[1] + red[2] + red[3];
  int h = t & 127, par = t >> 7;
  float o = 0.f;
  for (int i = par; i < nloc; i += 2) {
    int p = l0 + i;
    float val = (p == 0) ? relay[(size_t)b * D + h]
                         : bf2f(nodesb[((size_t)b * L + p - 1) * D + h]);
    o += sc[i] * val;
  }
  accs[par][h] = o;
  __syncthreads();
  if (t < D) pw[((size_t)bn * NCH + c) * D + t] = accs[0][t] + accs[1][t];
  if (t == 0) { pm[bn * NCH + c] = m; ps[bn * NCH + c] = sum; }
}

// ---------------- combine chunks -> satt -> relay; then (optional) next-layer projections
__global__ __launch_bounds__(128) void relay_final(
    const float* __restrict__ pm, const float* __restrict__ ps, const float* __restrict__ pw,
    const float* __restrict__ svw, const float* __restrict__ svb,
    const float* __restrict__ sow, const float* __restrict__ sob,
    const float* __restrict__ nrkw, const float* __restrict__ nrkb,
    const float* __restrict__ nrvw, const float* __restrict__ nrvb,
    const float* __restrict__ nsqw, const float* __restrict__ nsqb,
    const float* __restrict__ nskw, const float* __restrict__ nskb,
    float* __restrict__ relay_out,
    float* __restrict__ relay_k, float* __restrict__ relay_v,
    float* __restrict__ u, float* __restrict__ cvec, int do_proj) {
  int b = blockIdx.x, di = blockIdx.y, t = threadIdx.x;
  __shared__ float wsum[NH][D];
  __shared__ float satts[D2];
  __shared__ float rel[D];
  __shared__ float sql[HD];
  __shared__ float cred[2];
  {
    int n = t >> 5, lt = t & 31;
    int bn = b * NH + n;
    float M = -1e30f;
#pragma unroll
    for (int c = 0; c < NCH; c++) M = fmaxf(M, pm[bn * NCH + c]);
    float S = 0.f;
    float ec[NCH];
#pragma unroll
    for (int c = 0; c < NCH; c++) { ec[c] = expf(pm[bn * NCH + c] - M); S += ps[bn * NCH + c] * ec[c]; }
    float invS = 1.0f / S;
#pragma unroll
    for (int hh = 0; hh < 4; hh++) {
      int h = lt * 4 + hh;
      float o = 0.f;
#pragma unroll
      for (int c = 0; c < NCH; c++) o += ec[c] * pw[((size_t)bn * NCH + c) * D + h];
      wsum[n][h] = o * invS;
    }
  }
  __syncthreads();
#pragma unroll
  for (int rep = 0; rep < 4; rep++) {
    int nh = rep * 128 + t;
    int hn = nh >> 7;
    float acc = svb[nh];
    const float4* wp = (const float4*)(svw + (size_t)nh * D);
    const float4* wl = (const float4*)wsum[hn];
#pragma unroll 8
    for (int d = 0; d < D / 4; d++) {
      float4 a = wl[d], wv4 = wp[d];
      acc += a.x * wv4.x + a.y * wv4.y + a.z * wv4.z + a.w * wv4.w;
    }
    satts[nh] = acc;
  }
  __syncthreads();
  {
    float acc = sob[t];
    const float4* wp = (const float4*)(sow + (size_t)t * D2);
    const float4* a4 = (const float4*)satts;
#pragma unroll 8
    for (int j = 0; j < D2 / 4; j++) {
      float4 a = a4[j], wv4 = wp[j];
      acc += a.x * wv4.x + a.y * wv4.y + a.z * wv4.z + a.w * wv4.w;
    }
    acc = (acc > 0.f) ? acc : 0.01f * acc;
    rel[t] = acc;
    relay_out[(size_t)b * D + t] = acc;
  }
  __syncthreads();
  if (do_proj)
    do_relay_proj(b, di, t, rel, nrkw, nrkb, nrvw, nrvb, nsqw, nsqb, nskw, nskb,
                  relay_k, relay_v, u, cvec, sql, cred);
}

extern "C" void kernel_launch(void* const* d_in, const int* in_sizes, int n_in,
                              void* d_out, int out_size, void* d_ws, size_t ws_size,
                              hipStream_t stream) {
  const int* tokens = (const int*)d_in[0];
  const int* mask = (const int*)d_in[1];
  const float* emb = (const float*)d_in[2];
  const float* proj_w = (const float*)d_in[3];
  const float* proj_b = (const float*)d_in[4];
  const float* ng = (const float*)d_in[5];
  const float* nb = (const float*)d_in[6];
  const float* rq_w = (const float*)d_in[7], * rq_b = (const float*)d_in[8];
  const float* rk_w = (const float*)d_in[9], * rk_b = (const float*)d_in[10];
  const float* rv_w = (const float*)d_in[11], * rv_b = (const float*)d_in[12];
  const float* ro_w = (const float*)d_in[13], * ro_b = (const float*)d_in[14];
  const float* sq_w = (const float*)d_in[15], * sq_b = (const float*)d_in[16];
  const float* sk_w = (const float*)d_in[17], * sk_b = (const float*)d_in[18];
  const float* sv_w = (const float*)d_in[19], * sv_b = (const float*)d_in[20];
  const float* so_w = (const float*)d_in[21], * so_b = (const float*)d_in[22];

  const size_t BLD = (size_t)B * L * D;        // 1,048,576
  const size_t BLD4 = (size_t)B * L * D2;      // 4,194,304
  const size_t WTEN = (size_t)NL * D * D2;     // 196,608 per tensor

  float* fp = (float*)d_ws;
  float* nodes = fp;                    fp += BLD;
  float* relay = fp;                    fp += B * D;
  float* relay_k = fp;                  fp += B * D2;
  float* relay_v = fp;                  fp += B * D2;
  float* uvec = fp;                     fp += B * NH * D;
  float* cvec = fp;                     fp += B * NH;
  float* pm = fp;                       fp += B * NH * NCH;
  float* ps = fp;                       fp += B * NH * NCH;
  float* pw = fp;                       fp += (size_t)B * NH * NCH * D;
  u16* up = (u16*)fp;
  u16* xb = up;                         up += BLD;
  u16* nxb = up;                        up += BLD;
  u16* nodesb = up;                     up += BLD;
  u16* qb = up;                         up += BLD4;
  u16* kb = up;                         up += BLD4;
  u16* vb = up;                         up += BLD4;
  u16* akb = up;                        up += BLD4;
  u16* avb = up;                        up += BLD4;
  u16* attb = up;                       up += BLD4;
  u16* wb = up;                         // 4 * WTEN
  u16* wrq = wb, * wrk = wb + WTEN, * wrv = wb + 2 * WTEN, * wro = wb + 3 * WTEN;

  hipMemsetAsync(relay, 0, B * D * sizeof(float), stream);

  // convert ring-side weights to bf16 (one-time per launch)
  {
    WCArgs wa;
    wa.s[0] = rq_w; wa.s[1] = rk_w; wa.s[2] = rv_w; wa.s[3] = ro_w;
    wa.d[0] = wrq; wa.d[1] = wrk; wa.d[2] = wrv; wa.d[3] = wro;
    wconv<<<dim3(WTEN / 1024, 4), 256, 0, stream>>>(wa);
  }
  // embedding projection: nodes (fp32) + xb (bf16)
  gemm_embed<<<dim3(128, 2), 256, 0, stream>>>(emb, proj_w, proj_b, nodes, xb, tokens, D, E);
  relay_init_kernel<<<B * 64, 128, 0, stream>>>(nodes, relay);
  // layer-0 relay-side projections + layer-0 LN
  relay_proj<<<dim3(B, 12), 128, 0, stream>>>(relay, rk_w, rk_b, rv_w, rv_b, sq_w, sq_b,
                                              sk_w, sk_b, relay_k, relay_v, uvec, cvec);
  ln_kernel<<<B * L, 128, 0, stream>>>(nodes, nxb, ng, nb);

  for (int i = 0; i < NL; i++) {
    const size_t wo = (size_t)i * D * D2;
    const float* rqbi = rq_b + (size_t)i * D2;
    const float* rkbi = rk_b + (size_t)i * D2;
    const float* rvbi = rv_b + (size_t)i * D2;
    const float* robi = ro_b + (size_t)i * D;
    const float* svwi = sv_w + wo, * svbi = sv_b + (size_t)i * D2;
    const float* sowi = so_w + wo, * sobi = so_b + (size_t)i * D;

    // q,k,v (from nxb) + ak,av (from xb): one dispatch
    {
      GArgs ga = {};
      ga.d[0] = {nxb, wrq + wo, rqbi, qb};
      ga.d[1] = {nxb, wrk + wo, rkbi, kb};
      ga.d[2] = {nxb, wrv + wo, rvbi, vb};
      ga.d[3] = {xb,  wrk + wo, rkbi, akb};
      ga.d[4] = {xb,  wrv + wo, rvbi, avb};
      gemm_bf<<<dim3(128, 40), 256, 0, stream>>>(ga, 8, D2, D);
    }
    ring_attn_kernel<<<B * L, 256, 0, stream>>>(qb, kb, vb, akb, avb, relay_k, relay_v, attb);
    // ro GEMM + residual + mask + fused next-layer LN (writes nodes, nodesb, nxb)
    int last = (i == NL - 1);
    gemm_ro_ln<<<128, 256, 0, stream>>>(
        attb, wro + wo, robi, mask,
        last ? nullptr : ng + (i + 1) * D, last ? nullptr : nb + (i + 1) * D,
        nodes, nodesb, nxb, last ? 0 : 1);
    relay_attn_partial<<<dim3(B * NH, NCH), 256, 0, stream>>>(relay, nodesb, uvec, cvec, mask, pm, ps, pw);
    // combine + project relay; fuse next layer's relay-side projections
    const size_t wn_ = (size_t)(i + 1) * D * D2;
    float* relay_dst = last ? (float*)d_out : relay;
    relay_final<<<dim3(B, last ? 1 : 12), 128, 0, stream>>>(
        pm, ps, pw, svwi, svbi, sowi, sobi,
        last ? nullptr : rk_w + wn_, last ? nullptr : rk_b + (size_t)(i + 1) * D2,
        last ? nullptr : rv_w + wn_, last ? nullptr : rv_b + (size_t)(i + 1) * D2,
        last ? nullptr : sq_w + wn_, last ? nullptr : sq_b + (size_t)(i + 1) * D2,
        last ? nullptr : sk_w + wn_, last ? nullptr : sk_b + (size_t)(i + 1) * D2,
        relay_dst, relay_k, relay_v, uvec, cvec, last ? 0 : 1);
  }
}

// Round 11
// 433.028 us; speedup vs baseline: 1.1098x; 1.0186x over previous
//
#include <hip/hip_runtime.h>
#include <hip/hip_bf16.h>

// Problem constants
constexpr int B = 4, L = 2048, E = 300, D = 128, NH = 4, HD = 128, NL = 3, D2 = 512;
constexpr int L1 = L + 1; // 2049
constexpr float EPS = 1e-5f;
constexpr float SCALE = 0.08838834764831843f; // 1/sqrt(128)
constexpr int NCH = 32;              // relay-attention L-chunks
constexpr int CHUNK = 65;            // ceil(2049/32)

typedef unsigned int uint_t;
typedef unsigned short u16;
typedef short bf16x8 __attribute__((ext_vector_type(8)));
typedef float f32x4 __attribute__((ext_vector_type(4)));

__device__ __forceinline__ u16 f2bf(float f) {
  union { float f; uint_t i; } x; x.f = f;
  uint_t r = x.i + 0x7fffu + ((x.i >> 16) & 1u);
  return (u16)(r >> 16);
}
__device__ __forceinline__ uint_t packbf(float a, float b) {
  return (uint_t)f2bf(a) | ((uint_t)f2bf(b) << 16);
}
__device__ __forceinline__ float bf2f(u16 u) {
  union { uint_t i; float f; } x; x.i = ((uint_t)u) << 16; return x.f;
}
__device__ __forceinline__ float2 bf2x2(uint_t u) {
  union { uint_t i; float f; } a, b;
  a.i = (u & 0xffffu) << 16; b.i = u & 0xffff0000u;
  return make_float2(a.f, b.f);
}

// ---------------- weight pre-conversion: 4 tensors (rq,rk,rv,ro), NL*D*D2 fp32 -> bf16
struct WCArgs { const float* s[4]; u16* d[4]; };
__global__ __launch_bounds__(256) void wconv(WCArgs wa) {
  int ti = blockIdx.y;
  const float* s = wa.s[ti]; u16* dd = wa.d[ti];
  int i = (blockIdx.x * 256 + threadIdx.x) * 4;
  float4 f = *(const float4*)(s + i);
  *(uint2*)(dd + i) = make_uint2(packbf(f.x, f.y), packbf(f.z, f.w));
}

// ================= qkv GEMM: 128x128 tile, K=128 (single stage, one barrier)
// out[M,512] = A[M,128] @ W[512,128]^T + bias (bf16 out); 4 waves as 2x2, each 64x64
struct GDesc { const u16* A; const u16* W; const float* bias; u16* outb; };
struct GArgs { GDesc d[5]; };

__global__ __launch_bounds__(256) void gemm_qkv(GArgs ga, int nby, int N) {
  __shared__ u16 As[128][136];
  __shared__ u16 Ws[128][136];
  int t = threadIdx.x;
  int bm = blockIdx.x;
  int di = blockIdx.y / nby, bn = blockIdx.y - di * nby;
  GDesc d = ga.d[di];
  const int rowA = bm * 128, rowW = bn * 128;

  f32x4 acc[4][4];
#pragma unroll
  for (int i = 0; i < 4; i++)
#pragma unroll
    for (int j = 0; j < 4; j++)
      acc[i][j] = (f32x4){0.f, 0.f, 0.f, 0.f};

  const int r = t >> 1, c0 = (t & 1) * 64;   // 128 rows x 128 shorts; 64 shorts/thread
  const int wid = t >> 6;
  const int wm = (wid & 1) * 64, wn = (wid >> 1) * 64;
  const int lr = t & 15, quad = (t >> 4) & 3;

  const u16* Arow = d.A + (size_t)(rowA + r) * 128;
  const u16* Wrow = d.W + (size_t)(rowW + r) * 128;
  uint4 av_[8], wv_[8];
#pragma unroll
  for (int i = 0; i < 8; i++) {
    av_[i] = *(const uint4*)(Arow + c0 + i * 8);
    wv_[i] = *(const uint4*)(Wrow + c0 + i * 8);
  }
#pragma unroll
  for (int i = 0; i < 8; i++) {
    *(uint4*)&As[r][c0 + i * 8] = av_[i];
    *(uint4*)&Ws[r][c0 + i * 8] = wv_[i];
  }
  __syncthreads();
#pragma unroll
  for (int ks = 0; ks < 4; ks++) {
    bf16x8 af[4], bfr[4];
#pragma unroll
    for (int mt = 0; mt < 4; mt++)
      af[mt] = *(const bf16x8*)&As[wm + mt * 16 + lr][ks * 32 + quad * 8];
#pragma unroll
    for (int nt = 0; nt < 4; nt++)
      bfr[nt] = *(const bf16x8*)&Ws[wn + nt * 16 + lr][ks * 32 + quad * 8];
#pragma unroll
    for (int mt = 0; mt < 4; mt++)
#pragma unroll
      for (int nt = 0; nt < 4; nt++)
        acc[mt][nt] = __builtin_amdgcn_mfma_f32_16x16x32_bf16(af[mt], bfr[nt], acc[mt][nt], 0, 0, 0);
  }
  // epilogue: C/D layout col=lane&15, row=quad*4+reg
#pragma unroll
  for (int nt = 0; nt < 4; nt++) {
    int col = rowW + wn + nt * 16 + lr;
    float bv = d.bias[col];
#pragma unroll
    for (int mt = 0; mt < 4; mt++) {
#pragma unroll
      for (int rr = 0; rr < 4; rr++) {
        int row = rowA + wm + mt * 16 + quad * 4 + rr;
        d.outb[(size_t)row * N + col] = f2bf(acc[mt][nt][rr] + bv);
      }
    }
  }
}

// ================= embedding projection (gathered A, K=300, 64x128 tile) +
// fused layer-0 LN (-> nxb) + relay mean (atomics) + nodes/xb writes
__global__ __launch_bounds__(256) void gemm_embed_ln(
    const float* __restrict__ emb, const float* __restrict__ W,
    const float* __restrict__ bias, const int* __restrict__ gather,
    const float* __restrict__ lng, const float* __restrict__ lnb,
    float* __restrict__ nodes, u16* __restrict__ xb, u16* __restrict__ nxb,
    float* __restrict__ relay) {
  __shared__ u16 As[64][72];
  __shared__ u16 Ws[128][72];
  __shared__ float C[64][132];
  __shared__ float gb[2][D];
  __shared__ float lmu[64], lrs[64];
  int t = threadIdx.x;
  int bm = blockIdx.x;               // 128 blocks
  const int rowA0 = bm * 64;

  f32x4 acc[2][4];
#pragma unroll
  for (int i = 0; i < 2; i++)
#pragma unroll
    for (int j = 0; j < 4; j++)
      acc[i][j] = (f32x4){0.f, 0.f, 0.f, 0.f};

  const int wid = t >> 6;
  const int wm = (wid & 1) * 32, wn = (wid >> 1) * 64;
  const int lr = t & 15, quad = (t >> 4) & 3;
  const int ra = t >> 2, ca = (t & 3) * 16;  // A: 64 rows, 16 floats/thread
  const int rw = t >> 1, cw = (t & 1) * 32;  // W: 128 rows, 32 floats/thread

  if (t < D) { gb[0][t] = lng[t]; gb[1][t] = lnb[t]; }

  const float* Arow = emb + (size_t)gather[rowA0 + ra] * E;
  const float* Wrow = W + (size_t)rw * E;

  for (int kt = 0; kt < E; kt += 64) {
    __syncthreads();
    bool full = (kt + 64 <= E);
#pragma unroll
    for (int ch = 0; ch < 4; ch++) {
      int c = kt + ca + ch * 4;
      float4 fa;
      if (full) fa = *(const float4*)(Arow + c);
      else {
        fa.x = (c + 0 < E) ? Arow[c + 0] : 0.f;
        fa.y = (c + 1 < E) ? Arow[c + 1] : 0.f;
        fa.z = (c + 2 < E) ? Arow[c + 2] : 0.f;
        fa.w = (c + 3 < E) ? Arow[c + 3] : 0.f;
      }
      *(uint2*)&As[ra][ca + ch * 4] = make_uint2(packbf(fa.x, fa.y), packbf(fa.z, fa.w));
    }
#pragma unroll
    for (int ch = 0; ch < 8; ch++) {
      int c = kt + cw + ch * 4;
      float4 fw;
      if (full) fw = *(const float4*)(Wrow + c);
      else {
        fw.x = (c + 0 < E) ? Wrow[c + 0] : 0.f;
        fw.y = (c + 1 < E) ? Wrow[c + 1] : 0.f;
        fw.z = (c + 2 < E) ? Wrow[c + 2] : 0.f;
        fw.w = (c + 3 < E) ? Wrow[c + 3] : 0.f;
      }
      *(uint2*)&Ws[rw][cw + ch * 4] = make_uint2(packbf(fw.x, fw.y), packbf(fw.z, fw.w));
    }
    __syncthreads();
#pragma unroll
    for (int ks = 0; ks < 2; ks++) {
      bf16x8 af[2], bfr[4];
#pragma unroll
      for (int mt = 0; mt < 2; mt++)
        af[mt] = *(const bf16x8*)&As[wm + mt * 16 + lr][ks * 32 + quad * 8];
#pragma unroll
      for (int nt = 0; nt < 4; nt++)
        bfr[nt] = *(const bf16x8*)&Ws[wn + nt * 16 + lr][ks * 32 + quad * 8];
#pragma unroll
      for (int mt = 0; mt < 2; mt++)
#pragma unroll
        for (int nt = 0; nt < 4; nt++)
          acc[mt][nt] = __builtin_amdgcn_mfma_f32_16x16x32_bf16(af[mt], bfr[nt], acc[mt][nt], 0, 0, 0);
    }
  }
  // epilogue into LDS C
#pragma unroll
  for (int nt = 0; nt < 4; nt++) {
    int col = wn + nt * 16 + lr;
    float bv = bias[col];
#pragma unroll
    for (int mt = 0; mt < 2; mt++) {
#pragma unroll
      for (int rr = 0; rr < 4; rr++) {
        int row = wm + mt * 16 + quad * 4 + rr;
        C[row][col] = acc[mt][nt][rr] + bv;
      }
    }
  }
  __syncthreads();
  if (t < 64) {
    float s = 0.f, s2 = 0.f;
#pragma unroll 16
    for (int j = 0; j < D; j++) { float v = C[t][j]; s += v; s2 += v * v; }
    float mu = s * (1.0f / D);
    float var = s2 * (1.0f / D) - mu * mu;
    lmu[t] = mu; lrs[t] = rsqrtf(var + EPS);
  }
  __syncthreads();
#pragma unroll
  for (int rep = 0; rep < 8; rep++) {
    int lin = rep * 1024 + t * 4;
    int row = lin >> 7, col = lin & 127;
    float4 v = *(const float4*)&C[row][col];
    size_t g = (size_t)(rowA0 + row) * D + col;
    *(float4*)&nodes[g] = v;
    *(uint2*)&xb[g] = make_uint2(packbf(v.x, v.y), packbf(v.z, v.w));
    float mu = lmu[row], rs = lrs[row];
    float o0 = (v.x - mu) * rs * gb[0][col] + gb[1][col];
    float o1 = (v.y - mu) * rs * gb[0][col + 1] + gb[1][col + 1];
    float o2 = (v.z - mu) * rs * gb[0][col + 2] + gb[1][col + 2];
    float o3 = (v.w - mu) * rs * gb[0][col + 3] + gb[1][col + 3];
    *(uint2*)&nxb[g] = make_uint2(packbf(o0, o1), packbf(o2, o3));
  }
  // relay mean partial (rows of this tile share one b since 64 | 2048)
  if (t < D) {
    int b = rowA0 >> 11;
    float s = 0.f;
#pragma unroll 16
    for (int r2 = 0; r2 < 64; r2++) s += C[r2][t];
    atomicAdd(&relay[b * D + t], s * (1.0f / L));
  }
}

// ================= ro GEMM (32x128 tile, K=512, 256 blocks) + residual + mask + fused next-layer LN
__global__ __launch_bounds__(256) void gemm_ro_ln(
    const u16* __restrict__ A,      // attb [B*L, 512]
    const u16* __restrict__ W,      // ro_w bf16 [128, 512]
    const float* __restrict__ bias, // ro_b [128]
    const int* __restrict__ mask,
    const float* __restrict__ lng, const float* __restrict__ lnb,
    float* __restrict__ nodes, u16* __restrict__ nodesb, u16* __restrict__ nxb,
    int do_ln) {
  __shared__ u16 As[32][136];
  __shared__ u16 Ws[128][136];
  __shared__ float C[32][132];
  __shared__ float gb[2][D];
  __shared__ float lmu[32], lrs[32];
  int t = threadIdx.x;
  int bm = blockIdx.x;               // 256 blocks
  const int rowA0 = bm * 32;

  f32x4 acc[4];
#pragma unroll
  for (int j = 0; j < 4; j++) acc[j] = (f32x4){0.f, 0.f, 0.f, 0.f};

  const int wid = t >> 6;
  const int wm = (wid & 1) * 16, wn = (wid >> 1) * 64;
  const int lr = t & 15, quad = (t >> 4) & 3;
  const int ra = t >> 3, ca = (t & 7) * 16;   // A: 32 rows x 128 shorts, 16/thread
  const int rw = t >> 1, cw = (t & 1) * 64;   // W: 128 rows x 128 shorts, 64/thread

  if (do_ln && t < D) { gb[0][t] = lng[t]; gb[1][t] = lnb[t]; }

  const u16* Arow = A + (size_t)(rowA0 + ra) * 512;
  const u16* Wrow = W + (size_t)rw * 512;

  for (int kt = 0; kt < 512; kt += 128) {
    uint4 a0 = *(const uint4*)(Arow + kt + ca);
    uint4 a1 = *(const uint4*)(Arow + kt + ca + 8);
    uint4 w0 = *(const uint4*)(Wrow + kt + cw);
    uint4 w1 = *(const uint4*)(Wrow + kt + cw + 8);
    uint4 w2 = *(const uint4*)(Wrow + kt + cw + 16);
    uint4 w3 = *(const uint4*)(Wrow + kt + cw + 24);
    uint4 w4 = *(const uint4*)(Wrow + kt + cw + 32);
    uint4 w5 = *(const uint4*)(Wrow + kt + cw + 40);
    uint4 w6 = *(const uint4*)(Wrow + kt + cw + 48);
    uint4 w7 = *(const uint4*)(Wrow + kt + cw + 56);
    __syncthreads();
    *(uint4*)&As[ra][ca] = a0; *(uint4*)&As[ra][ca + 8] = a1;
    *(uint4*)&Ws[rw][cw] = w0; *(uint4*)&Ws[rw][cw + 8] = w1;
    *(uint4*)&Ws[rw][cw + 16] = w2; *(uint4*)&Ws[rw][cw + 24] = w3;
    *(uint4*)&Ws[rw][cw + 32] = w4; *(uint4*)&Ws[rw][cw + 40] = w5;
    *(uint4*)&Ws[rw][cw + 48] = w6; *(uint4*)&Ws[rw][cw + 56] = w7;
    __syncthreads();
#pragma unroll
    for (int ks = 0; ks < 4; ks++) {
      bf16x8 af = *(const bf16x8*)&As[wm + lr][ks * 32 + quad * 8];
      bf16x8 bfr[4];
#pragma unroll
      for (int nt = 0; nt < 4; nt++)
        bfr[nt] = *(const bf16x8*)&Ws[wn + nt * 16 + lr][ks * 32 + quad * 8];
#pragma unroll
      for (int nt = 0; nt < 4; nt++)
        acc[nt] = __builtin_amdgcn_mfma_f32_16x16x32_bf16(af, bfr[nt], acc[nt], 0, 0, 0);
    }
  }
  __syncthreads();
#pragma unroll
  for (int nt = 0; nt < 4; nt++) {
    int col = wn + nt * 16 + lr;
    float bv = bias[col];
#pragma unroll
    for (int rr = 0; rr < 4; rr++) {
      int row = wm + quad * 4 + rr;
      float v = acc[nt][rr] + bv;
      v = (v > 0.f) ? v : 0.01f * v;
      v += nodes[(size_t)(rowA0 + row) * D + col];
      if (mask[rowA0 + row] == 0) v = 0.f;
      C[row][col] = v;
    }
  }
  __syncthreads();
  if (t < 32) {
    float s = 0.f, s2 = 0.f;
#pragma unroll 16
    for (int j = 0; j < D; j++) { float v = C[t][j]; s += v; s2 += v * v; }
    float mu = s * (1.0f / D);
    float var = s2 * (1.0f / D) - mu * mu;
    lmu[t] = mu; lrs[t] = rsqrtf(var + EPS);
  }
  __syncthreads();
#pragma unroll
  for (int rep = 0; rep < 4; rep++) {
    int lin = rep * 1024 + t * 4;
    int row = lin >> 7, col = lin & 127;
    float4 v = *(const float4*)&C[row][col];
    size_t g = (size_t)(rowA0 + row) * D + col;
    *(float4*)&nodes[g] = v;
    *(uint2*)&nodesb[g] = make_uint2(packbf(v.x, v.y), packbf(v.z, v.w));
    if (do_ln) {
      float mu = lmu[row], rs = lrs[row];
      float o0 = (v.x - mu) * rs * gb[0][col] + gb[1][col];
      float o1 = (v.y - mu) * rs * gb[0][col + 1] + gb[1][col + 1];
      float o2 = (v.z - mu) * rs * gb[0][col + 2] + gb[1][col + 2];
      float o3 = (v.w - mu) * rs * gb[0][col + 3] + gb[1][col + 3];
      *(uint2*)&nxb[g] = make_uint2(packbf(o0, o1), packbf(o2, o3));
    }
  }
}

// ---------------- shared device helper: relay projections from rel[] in LDS
__device__ __forceinline__ void do_relay_proj(
    int b, int di, int t, const float* rel,
    const float* rkw, const float* rkb, const float* rvw, const float* rvb,
    const float* sqw, const float* sqb, const float* skw, const float* skb_,
    float* relay_k, float* relay_v, float* u, float* cvec,
    float* sql, float* cred) {
  const float4* r4 = (const float4*)rel;
  if (di < 8) {
    int which = di >> 2;           // 0 = rk, 1 = rv
    int n = (di & 3) * 128 + t;
    const float* W = which ? rvw : rkw;
    float acc = (which ? rvb : rkb)[n];
    const float4* w4 = (const float4*)(W + (size_t)n * D);
#pragma unroll 8
    for (int i = 0; i < D / 4; i++) {
      float4 w = w4[i], r = r4[i];
      acc += w.x * r.x + w.y * r.y + w.z * r.z + w.w * r.w;
    }
    (which ? relay_v : relay_k)[(size_t)b * D2 + n] = acc;
  } else {
    int n = di - 8;
    {
      int nh = n * HD + t;
      float acc = sqb[nh];
      const float4* w4 = (const float4*)(sqw + (size_t)nh * D);
#pragma unroll 8
      for (int i = 0; i < D / 4; i++) {
        float4 w = w4[i], r = r4[i];
        acc += w.x * r.x + w.y * r.y + w.z * r.z + w.w * r.w;
      }
      sql[t] = acc;
    }
    __syncthreads();
    {
      float cp = sql[t] * skb_[n * HD + t];
#pragma unroll
      for (int o = 1; o < 64; o <<= 1) cp += __shfl_xor(cp, o, 64);
      if ((t & 63) == 0) cred[t >> 6] = cp;
    }
    float a0 = 0.f, a1 = 0.f, a2 = 0.f, a3 = 0.f;
    const float* wp = skw + (size_t)(n * HD) * D + t;
    for (int h = 0; h < HD; h += 4) {
      a0 += sql[h] * wp[(size_t)h * D];
      a1 += sql[h + 1] * wp[(size_t)(h + 1) * D];
      a2 += sql[h + 2] * wp[(size_t)(h + 2) * D];
      a3 += sql[h + 3] * wp[(size_t)(h + 3) * D];
    }
    u[((size_t)b * NH + n) * D + t] = (a0 + a1 + a2 + a3) * SCALE;
    __syncthreads();
    if (t == 0) cvec[b * NH + n] = (cred[0] + cred[1]) * SCALE;
  }
}

// ---------------- standalone relay projections (layer 0), grid (B,12) x 128
__global__ __launch_bounds__(128) void relay_proj(
    const float* __restrict__ relay,
    const float* __restrict__ rkw, const float* __restrict__ rkb,
    const float* __restrict__ rvw, const float* __restrict__ rvb,
    const float* __restrict__ sqw, const float* __restrict__ sqb,
    const float* __restrict__ skw, const float* __restrict__ skb_,
    float* __restrict__ relay_k, float* __restrict__ relay_v,
    float* __restrict__ u, float* __restrict__ cvec) {
  __shared__ float rel[D];
  __shared__ float sql[HD];
  __shared__ float cred[2];
  int b = blockIdx.x, di = blockIdx.y, t = threadIdx.x;
  rel[t] = relay[(size_t)b * D + t];
  __syncthreads();
  do_relay_proj(b, di, t, rel, rkw, rkb, rvw, rvb, sqw, sqb, skw, skb_,
                relay_k, relay_v, u, cvec, sql, cred);
}

// ---------------- ring (windowed) attention; bf16 q/k/v/ak/av + att, fp32 rk/rv
__global__ __launch_bounds__(256) void ring_attn_kernel(
    const u16* __restrict__ q, const u16* __restrict__ k, const u16* __restrict__ v,
    const u16* __restrict__ akr, const u16* __restrict__ avr,
    const float* __restrict__ rk, const float* __restrict__ rv,
    u16* __restrict__ att) {
  int bl = blockIdx.x;
  int b = bl >> 11, l = bl & (L - 1);
  int n = threadIdx.x >> 6, lane = threadIdx.x & 63;
  int h = lane << 1;
  size_t base = (size_t)bl * D2 + n * HD + h;
  float2 qv = bf2x2(*(const uint_t*)(q + base));
  float s[5], v0[5], v1[5];
#pragma unroll
  for (int u = 0; u < 5; u++) {
    float k0 = 0.f, k1 = 0.f, vv0 = 0.f, vv1 = 0.f;
    if (u < 3) {
      int ll = l + u - 1;
      if (ll >= 0 && ll < L) {
        size_t off = ((size_t)b * L + ll) * D2 + n * HD + h;
        float2 kf = bf2x2(*(const uint_t*)(k + off));
        float2 vf = bf2x2(*(const uint_t*)(v + off));
        k0 = kf.x; k1 = kf.y; vv0 = vf.x; vv1 = vf.y;
      }
    } else if (u == 3) {
      float2 kf = bf2x2(*(const uint_t*)(akr + base));
      float2 vf = bf2x2(*(const uint_t*)(avr + base));
      k0 = kf.x; k1 = kf.y; vv0 = vf.x; vv1 = vf.y;
    } else {
      size_t rb = (size_t)b * D2 + n * HD + h;
      k0 = rk[rb]; k1 = rk[rb + 1]; vv0 = rv[rb]; vv1 = rv[rb + 1];
    }
    float p = qv.x * k0 + qv.y * k1;
#pragma unroll
    for (int o = 1; o < 64; o <<= 1) p += __shfl_xor(p, o, 64);
    s[u] = p * SCALE;
    v0[u] = vv0; v1[u] = vv1;
  }
  float m = s[0];
#pragma unroll
  for (int u = 1; u < 5; u++) m = fmaxf(m, s[u]);
  float sum = 0.f, o0 = 0.f, o1 = 0.f;
#pragma unroll
  for (int u = 0; u < 5; u++) {
    float e = expf(s[u] - m);
    sum += e; o0 += e * v0[u]; o1 += e * v1[u];
  }
  *(uint_t*)(att + base) = packbf(o0 / sum, o1 / sum);
}

// ---------------- relay attention phase 1: scores from nodesb/relay vs u; partial wsum of rows
__global__ __launch_bounds__(256) void relay_attn_partial(
    const float* __restrict__ relay, const u16* __restrict__ nodesb,
    const float* __restrict__ u, const float* __restrict__ cvec,
    const int* __restrict__ mask,
    float* __restrict__ pm, float* __restrict__ ps, float* __restrict__ pw) {
  int bn = blockIdx.x;           // b*NH + n
  int b = bn >> 2;
  int c = blockIdx.y;
  int l0 = c * CHUNK;
  int nloc = min(CHUNK, L1 - l0);
  __shared__ float us[D];
  __shared__ float sc[CHUNK];
  __shared__ float red[4];
  __shared__ float accs[2][D];
  int t = threadIdx.x;
  if (t < D) us[t] = u[(size_t)bn * D + t];
  __syncthreads();
  float cb = cvec[bn];
  int wv = t >> 6, lane = t & 63;
  float2 qv = ((const float2*)us)[lane];
  for (int i = wv; i < nloc; i += 4) {
    int p = l0 + i;
    float2 kk;
    if (p == 0) kk = ((const float2*)(relay + (size_t)b * D))[lane];
    else kk = bf2x2(*(const uint_t*)(nodesb + ((size_t)b * L + p - 1) * D + 2 * lane));
    float s = qv.x * kk.x + qv.y * kk.y;
#pragma unroll
    for (int o = 1; o < 64; o <<= 1) s += __shfl_xor(s, o, 64);
    if (lane == 0) {
      s += cb;
      if (p > 0 && mask[b * L + p - 1] == 0) s = -1e30f;
      sc[i] = s;
    }
  }
  __syncthreads();
  float m = -1e30f;
  for (int i = t; i < nloc; i += 256) m = fmaxf(m, sc[i]);
#pragma unroll
  for (int o = 1; o < 64; o <<= 1) m = fmaxf(m, __shfl_xor(m, o, 64));
  if (lane == 0) red[wv] = m;
  __syncthreads();
  m = fmaxf(fmaxf(red[0], red[1]), fmaxf(red[2], red[3]));
  __syncthreads();
  float sum = 0.f;
  for (int i = t; i < nloc; i += 256) { float e = expf(sc[i] - m); sc[i] = e; sum += e; }
#pragma unroll
  for (int o = 1; o < 64; o <<= 1) sum += __shfl_xor(sum, o, 64);
  if (lane == 0) red[wv] = sum;
  __syncthreads();
  sum = red[0] + red[1] + red[2] + red[3];
  int h = t & 127, par = t >> 7;
  float o = 0.f;
  for (int i = par; i < nloc; i += 2) {
    int p = l0 + i;
    float val = (p == 0) ? relay[(size_t)b * D + h]
                         : bf2f(nodesb[((size_t)b * L + p - 1) * D + h]);
    o += sc[i] * val;
  }
  accs[par][h] = o;
  __syncthreads();
  if (t < D) pw[((size_t)bn * NCH + c) * D + t] = accs[0][t] + accs[1][t];
  if (t == 0) { pm[bn * NCH + c] = m; ps[bn * NCH + c] = sum; }
}

// ---------------- combine chunks -> satt -> relay; then (optional) next-layer projections
__global__ __launch_bounds__(128) void relay_final(
    const float* __restrict__ pm, const float* __restrict__ ps, const float* __restrict__ pw,
    const float* __restrict__ svw, const float* __restrict__ svb,
    const float* __restrict__ sow, const float* __restrict__ sob,
    const float* __restrict__ nrkw, const float* __restrict__ nrkb,
    const float* __restrict__ nrvw, const float* __restrict__ nrvb,
    const float* __restrict__ nsqw, const float* __restrict__ nsqb,
    const float* __restrict__ nskw, const float* __restrict__ nskb,
    float* __restrict__ relay_out,
    float* __restrict__ relay_k, float* __restrict__ relay_v,
    float* __restrict__ u, float* __restrict__ cvec, int do_proj) {
  int b = blockIdx.x, di = blockIdx.y, t = threadIdx.x;
  __shared__ float wsum[NH][D];
  __shared__ float satts[D2];
  __shared__ float rel[D];
  __shared__ float sql[HD];
  __shared__ float cred[2];
  {
    int n = t >> 5, lt = t & 31;
    int bn = b * NH + n;
    float M = -1e30f;
#pragma unroll
    for (int c = 0; c < NCH; c++) M = fmaxf(M, pm[bn * NCH + c]);
    float S = 0.f;
    float ec[NCH];
#pragma unroll
    for (int c = 0; c < NCH; c++) { ec[c] = expf(pm[bn * NCH + c] - M); S += ps[bn * NCH + c] * ec[c]; }
    float invS = 1.0f / S;
#pragma unroll
    for (int hh = 0; hh < 4; hh++) {
      int h = lt * 4 + hh;
      float o = 0.f;
#pragma unroll
      for (int c = 0; c < NCH; c++) o += ec[c] * pw[((size_t)bn * NCH + c) * D + h];
      wsum[n][h] = o * invS;
    }
  }
  __syncthreads();
#pragma unroll
  for (int rep = 0; rep < 4; rep++) {
    int nh = rep * 128 + t;
    int hn = nh >> 7;
    float acc = svb[nh];
    const float4* wp = (const float4*)(svw + (size_t)nh * D);
    const float4* wl = (const float4*)wsum[hn];
#pragma unroll 8
    for (int d = 0; d < D / 4; d++) {
      float4 a = wl[d], wv4 = wp[d];
      acc += a.x * wv4.x + a.y * wv4.y + a.z * wv4.z + a.w * wv4.w;
    }
    satts[nh] = acc;
  }
  __syncthreads();
  {
    float acc = sob[t];
    const float4* wp = (const float4*)(sow + (size_t)t * D2);
    const float4* a4 = (const float4*)satts;
#pragma unroll 8
    for (int j = 0; j < D2 / 4; j++) {
      float4 a = a4[j], wv4 = wp[j];
      acc += a.x * wv4.x + a.y * wv4.y + a.z * wv4.z + a.w * wv4.w;
    }
    acc = (acc > 0.f) ? acc : 0.01f * acc;
    rel[t] = acc;
    relay_out[(size_t)b * D + t] = acc;
  }
  __syncthreads();
  if (do_proj)
    do_relay_proj(b, di, t, rel, nrkw, nrkb, nrvw, nrvb, nsqw, nsqb, nskw, nskb,
                  relay_k, relay_v, u, cvec, sql, cred);
}

extern "C" void kernel_launch(void* const* d_in, const int* in_sizes, int n_in,
                              void* d_out, int out_size, void* d_ws, size_t ws_size,
                              hipStream_t stream) {
  const int* tokens = (const int*)d_in[0];
  const int* mask = (const int*)d_in[1];
  const float* emb = (const float*)d_in[2];
  const float* proj_w = (const float*)d_in[3];
  const float* proj_b = (const float*)d_in[4];
  const float* ng = (const float*)d_in[5];
  const float* nb = (const float*)d_in[6];
  const float* rq_w = (const float*)d_in[7], * rq_b = (const float*)d_in[8];
  const float* rk_w = (const float*)d_in[9], * rk_b = (const float*)d_in[10];
  const float* rv_w = (const float*)d_in[11], * rv_b = (const float*)d_in[12];
  const float* ro_w = (const float*)d_in[13], * ro_b = (const float*)d_in[14];
  const float* sq_w = (const float*)d_in[15], * sq_b = (const float*)d_in[16];
  const float* sk_w = (const float*)d_in[17], * sk_b = (const float*)d_in[18];
  const float* sv_w = (const float*)d_in[19], * sv_b = (const float*)d_in[20];
  const float* so_w = (const float*)d_in[21], * so_b = (const float*)d_in[22];

  const size_t BLD = (size_t)B * L * D;        // 1,048,576
  const size_t BLD4 = (size_t)B * L * D2;      // 4,194,304
  const size_t WTEN = (size_t)NL * D * D2;     // 196,608 per tensor

  float* fp = (float*)d_ws;
  float* nodes = fp;                    fp += BLD;
  float* relay = fp;                    fp += B * D;
  float* relay_k = fp;                  fp += B * D2;
  float* relay_v = fp;                  fp += B * D2;
  float* uvec = fp;                     fp += B * NH * D;
  float* cvec = fp;                     fp += B * NH;
  float* pm = fp;                       fp += B * NH * NCH;
  float* ps = fp;                       fp += B * NH * NCH;
  float* pw = fp;                       fp += (size_t)B * NH * NCH * D;
  u16* up = (u16*)fp;
  u16* xb = up;                         up += BLD;
  u16* nxb = up;                        up += BLD;
  u16* nodesb = up;                     up += BLD;
  u16* qb = up;                         up += BLD4;
  u16* kb = up;                         up += BLD4;
  u16* vb = up;                         up += BLD4;
  u16* akb = up;                        up += BLD4;
  u16* avb = up;                        up += BLD4;
  u16* attb = up;                       up += BLD4;
  u16* wb = up;                         // 4 * WTEN
  u16* wrq = wb, * wrk = wb + WTEN, * wrv = wb + 2 * WTEN, * wro = wb + 3 * WTEN;

  hipMemsetAsync(relay, 0, B * D * sizeof(float), stream);

  // convert ring-side weights to bf16 (one-time per launch)
  {
    WCArgs wa;
    wa.s[0] = rq_w; wa.s[1] = rk_w; wa.s[2] = rv_w; wa.s[3] = ro_w;
    wa.d[0] = wrq; wa.d[1] = wrk; wa.d[2] = wrv; wa.d[3] = wro;
    wconv<<<dim3(WTEN / 1024, 4), 256, 0, stream>>>(wa);
  }
  // embedding projection + layer-0 LN + relay mean (atomics): nodes, xb, nxb, relay
  gemm_embed_ln<<<128, 256, 0, stream>>>(emb, proj_w, proj_b, tokens, ng, nb,
                                         nodes, xb, nxb, relay);
  // layer-0 relay-side projections
  relay_proj<<<dim3(B, 12), 128, 0, stream>>>(relay, rk_w, rk_b, rv_w, rv_b, sq_w, sq_b,
                                              sk_w, sk_b, relay_k, relay_v, uvec, cvec);

  for (int i = 0; i < NL; i++) {
    const size_t wo = (size_t)i * D * D2;
    const float* rqbi = rq_b + (size_t)i * D2;
    const float* rkbi = rk_b + (size_t)i * D2;
    const float* rvbi = rv_b + (size_t)i * D2;
    const float* robi = ro_b + (size_t)i * D;
    const float* svwi = sv_w + wo, * svbi = sv_b + (size_t)i * D2;
    const float* sowi = so_w + wo, * sobi = so_b + (size_t)i * D;

    // q,k,v (from nxb) + ak,av (from xb): one dispatch, 128x128 tiles
    {
      GArgs ga = {};
      ga.d[0] = {nxb, wrq + wo, rqbi, qb};
      ga.d[1] = {nxb, wrk + wo, rkbi, kb};
      ga.d[2] = {nxb, wrv + wo, rvbi, vb};
      ga.d[3] = {xb,  wrk + wo, rkbi, akb};
      ga.d[4] = {xb,  wrv + wo, rvbi, avb};
      gemm_qkv<<<dim3(64, 20), 256, 0, stream>>>(ga, 4, D2);
    }
    ring_attn_kernel<<<B * L, 256, 0, stream>>>(qb, kb, vb, akb, avb, relay_k, relay_v, attb);
    // ro GEMM + residual + mask + fused next-layer LN (writes nodes, nodesb, nxb)
    int last = (i == NL - 1);
    gemm_ro_ln<<<256, 256, 0, stream>>>(
        attb, wro + wo, robi, mask,
        last ? nullptr : ng + (i + 1) * D, last ? nullptr : nb + (i + 1) * D,
        nodes, nodesb, nxb, last ? 0 : 1);
    relay_attn_partial<<<dim3(B * NH, NCH), 256, 0, stream>>>(relay, nodesb, uvec, cvec, mask, pm, ps, pw);
    // combine + project relay; fuse next layer's relay-side projections
    const size_t wn_ = (size_t)(i + 1) * D * D2;
    float* relay_dst = last ? (float*)d_out : relay;
    relay_final<<<dim3(B, last ? 1 : 12), 128, 0, stream>>>(
        pm, ps, pw, svwi, svbi, sowi, sobi,
        last ? nullptr : rk_w + wn_, last ? nullptr : rk_b + (size_t)(i + 1) * D2,
        last ? nullptr : rv_w + wn_, last ? nullptr : rv_b + (size_t)(i + 1) * D2,
        last ? nullptr : sq_w + wn_, last ? nullptr : sq_b + (size_t)(i + 1) * D2,
        last ? nullptr : sk_w + wn_, last ? nullptr : sk_b + (size_t)(i + 1) * D2,
        relay_dst, relay_k, relay_v, uvec, cvec, last ? 0 : 1);
  }
}

// Round 12
// 401.638 us; speedup vs baseline: 1.1966x; 1.0782x over previous
//
#include <hip/hip_runtime.h>
#include <hip/hip_bf16.h>

// Problem constants
constexpr int B = 4, L = 2048, E = 300, D = 128, NH = 4, HD = 128, NL = 3, D2 = 512;
constexpr float EPS = 1e-5f;
constexpr float SCALE = 0.08838834764831843f; // 1/sqrt(128)
constexpr int NCH = 64;              // relay-attention node chunks (32 rows each = ro tile)

typedef unsigned int uint_t;
typedef unsigned short u16;
typedef short bf16x8 __attribute__((ext_vector_type(8)));
typedef float f32x4 __attribute__((ext_vector_type(4)));

__device__ __forceinline__ u16 f2bf(float f) {
  union { float f; uint_t i; } x; x.f = f;
  uint_t r = x.i + 0x7fffu + ((x.i >> 16) & 1u);
  return (u16)(r >> 16);
}
__device__ __forceinline__ uint_t packbf(float a, float b) {
  return (uint_t)f2bf(a) | ((uint_t)f2bf(b) << 16);
}
__device__ __forceinline__ float bf2f(u16 u) {
  union { uint_t i; float f; } x; x.i = ((uint_t)u) << 16; return x.f;
}
__device__ __forceinline__ float2 bf2x2(uint_t u) {
  union { uint_t i; float f; } a, b;
  a.i = (u & 0xffffu) << 16; b.i = u & 0xffff0000u;
  return make_float2(a.f, b.f);
}

// ---------------- weight pre-conversion: 4 tensors (rq,rk,rv,ro), NL*D*D2 fp32 -> bf16
struct WCArgs { const float* s[4]; u16* d[4]; };
__global__ __launch_bounds__(256) void wconv(WCArgs wa) {
  int ti = blockIdx.y;
  const float* s = wa.s[ti]; u16* dd = wa.d[ti];
  int i = (blockIdx.x * 256 + threadIdx.x) * 4;
  float4 f = *(const float4*)(s + i);
  *(uint2*)(dd + i) = make_uint2(packbf(f.x, f.y), packbf(f.z, f.w));
}

// ================= qkv GEMM: 128x128 tile, K=128 (single stage, one barrier)
struct GDesc { const u16* A; const u16* W; const float* bias; u16* outb; };
struct GArgs { GDesc d[5]; };

__global__ __launch_bounds__(256) void gemm_qkv(GArgs ga, int nby, int N) {
  __shared__ u16 As[128][136];
  __shared__ u16 Ws[128][136];
  int t = threadIdx.x;
  int bm = blockIdx.x;
  int di = blockIdx.y / nby, bn = blockIdx.y - di * nby;
  GDesc d = ga.d[di];
  const int rowA = bm * 128, rowW = bn * 128;

  f32x4 acc[4][4];
#pragma unroll
  for (int i = 0; i < 4; i++)
#pragma unroll
    for (int j = 0; j < 4; j++)
      acc[i][j] = (f32x4){0.f, 0.f, 0.f, 0.f};

  const int r = t >> 1, c0 = (t & 1) * 64;
  const int wid = t >> 6;
  const int wm = (wid & 1) * 64, wn = (wid >> 1) * 64;
  const int lr = t & 15, quad = (t >> 4) & 3;

  const u16* Arow = d.A + (size_t)(rowA + r) * 128;
  const u16* Wrow = d.W + (size_t)(rowW + r) * 128;
  uint4 av_[8], wv_[8];
#pragma unroll
  for (int i = 0; i < 8; i++) {
    av_[i] = *(const uint4*)(Arow + c0 + i * 8);
    wv_[i] = *(const uint4*)(Wrow + c0 + i * 8);
  }
#pragma unroll
  for (int i = 0; i < 8; i++) {
    *(uint4*)&As[r][c0 + i * 8] = av_[i];
    *(uint4*)&Ws[r][c0 + i * 8] = wv_[i];
  }
  __syncthreads();
#pragma unroll
  for (int ks = 0; ks < 4; ks++) {
    bf16x8 af[4], bfr[4];
#pragma unroll
    for (int mt = 0; mt < 4; mt++)
      af[mt] = *(const bf16x8*)&As[wm + mt * 16 + lr][ks * 32 + quad * 8];
#pragma unroll
    for (int nt = 0; nt < 4; nt++)
      bfr[nt] = *(const bf16x8*)&Ws[wn + nt * 16 + lr][ks * 32 + quad * 8];
#pragma unroll
    for (int mt = 0; mt < 4; mt++)
#pragma unroll
      for (int nt = 0; nt < 4; nt++)
        acc[mt][nt] = __builtin_amdgcn_mfma_f32_16x16x32_bf16(af[mt], bfr[nt], acc[mt][nt], 0, 0, 0);
  }
#pragma unroll
  for (int nt = 0; nt < 4; nt++) {
    int col = rowW + wn + nt * 16 + lr;
    float bv = d.bias[col];
#pragma unroll
    for (int mt = 0; mt < 4; mt++) {
#pragma unroll
      for (int rr = 0; rr < 4; rr++) {
        int row = rowA + wm + mt * 16 + quad * 4 + rr;
        d.outb[(size_t)row * N + col] = f2bf(acc[mt][nt][rr] + bv);
      }
    }
  }
}

// ================= embedding projection (gathered A, K=300, 64x128 tile) +
// fused layer-0 LN (-> nxb) + relay mean (atomics) + nodes/xb writes
__global__ __launch_bounds__(256) void gemm_embed_ln(
    const float* __restrict__ emb, const float* __restrict__ W,
    const float* __restrict__ bias, const int* __restrict__ gather,
    const float* __restrict__ lng, const float* __restrict__ lnb,
    float* __restrict__ nodes, u16* __restrict__ xb, u16* __restrict__ nxb,
    float* __restrict__ relay) {
  __shared__ u16 As[64][72];
  __shared__ u16 Ws[128][72];
  __shared__ float C[64][132];
  __shared__ float gb[2][D];
  __shared__ float lmu[64], lrs[64];
  int t = threadIdx.x;
  int bm = blockIdx.x;               // 128 blocks
  const int rowA0 = bm * 64;

  f32x4 acc[2][4];
#pragma unroll
  for (int i = 0; i < 2; i++)
#pragma unroll
    for (int j = 0; j < 4; j++)
      acc[i][j] = (f32x4){0.f, 0.f, 0.f, 0.f};

  const int wid = t >> 6;
  const int wm = (wid & 1) * 32, wn = (wid >> 1) * 64;
  const int lr = t & 15, quad = (t >> 4) & 3;
  const int ra = t >> 2, ca = (t & 3) * 16;
  const int rw = t >> 1, cw = (t & 1) * 32;

  if (t < D) { gb[0][t] = lng[t]; gb[1][t] = lnb[t]; }

  const float* Arow = emb + (size_t)gather[rowA0 + ra] * E;
  const float* Wrow = W + (size_t)rw * E;

  for (int kt = 0; kt < E; kt += 64) {
    __syncthreads();
    bool full = (kt + 64 <= E);
#pragma unroll
    for (int ch = 0; ch < 4; ch++) {
      int c = kt + ca + ch * 4;
      float4 fa;
      if (full) fa = *(const float4*)(Arow + c);
      else {
        fa.x = (c + 0 < E) ? Arow[c + 0] : 0.f;
        fa.y = (c + 1 < E) ? Arow[c + 1] : 0.f;
        fa.z = (c + 2 < E) ? Arow[c + 2] : 0.f;
        fa.w = (c + 3 < E) ? Arow[c + 3] : 0.f;
      }
      *(uint2*)&As[ra][ca + ch * 4] = make_uint2(packbf(fa.x, fa.y), packbf(fa.z, fa.w));
    }
#pragma unroll
    for (int ch = 0; ch < 8; ch++) {
      int c = kt + cw + ch * 4;
      float4 fw;
      if (full) fw = *(const float4*)(Wrow + c);
      else {
        fw.x = (c + 0 < E) ? Wrow[c + 0] : 0.f;
        fw.y = (c + 1 < E) ? Wrow[c + 1] : 0.f;
        fw.z = (c + 2 < E) ? Wrow[c + 2] : 0.f;
        fw.w = (c + 3 < E) ? Wrow[c + 3] : 0.f;
      }
      *(uint2*)&Ws[rw][cw + ch * 4] = make_uint2(packbf(fw.x, fw.y), packbf(fw.z, fw.w));
    }
    __syncthreads();
#pragma unroll
    for (int ks = 0; ks < 2; ks++) {
      bf16x8 af[2], bfr[4];
#pragma unroll
      for (int mt = 0; mt < 2; mt++)
        af[mt] = *(const bf16x8*)&As[wm + mt * 16 + lr][ks * 32 + quad * 8];
#pragma unroll
      for (int nt = 0; nt < 4; nt++)
        bfr[nt] = *(const bf16x8*)&Ws[wn + nt * 16 + lr][ks * 32 + quad * 8];
#pragma unroll
      for (int mt = 0; mt < 2; mt++)
#pragma unroll
        for (int nt = 0; nt < 4; nt++)
          acc[mt][nt] = __builtin_amdgcn_mfma_f32_16x16x32_bf16(af[mt], bfr[nt], acc[mt][nt], 0, 0, 0);
    }
  }
#pragma unroll
  for (int nt = 0; nt < 4; nt++) {
    int col = wn + nt * 16 + lr;
    float bv = bias[col];
#pragma unroll
    for (int mt = 0; mt < 2; mt++) {
#pragma unroll
      for (int rr = 0; rr < 4; rr++) {
        int row = wm + mt * 16 + quad * 4 + rr;
        C[row][col] = acc[mt][nt][rr] + bv;
      }
    }
  }
  __syncthreads();
  if (t < 64) {
    float s = 0.f, s2 = 0.f;
#pragma unroll 16
    for (int j = 0; j < D; j++) { float v = C[t][j]; s += v; s2 += v * v; }
    float mu = s * (1.0f / D);
    float var = s2 * (1.0f / D) - mu * mu;
    lmu[t] = mu; lrs[t] = rsqrtf(var + EPS);
  }
  __syncthreads();
#pragma unroll
  for (int rep = 0; rep < 8; rep++) {
    int lin = rep * 1024 + t * 4;
    int row = lin >> 7, col = lin & 127;
    float4 v = *(const float4*)&C[row][col];
    size_t g = (size_t)(rowA0 + row) * D + col;
    *(float4*)&nodes[g] = v;
    *(uint2*)&xb[g] = make_uint2(packbf(v.x, v.y), packbf(v.z, v.w));
    float mu = lmu[row], rs = lrs[row];
    float o0 = (v.x - mu) * rs * gb[0][col] + gb[1][col];
    float o1 = (v.y - mu) * rs * gb[0][col + 1] + gb[1][col + 1];
    float o2 = (v.z - mu) * rs * gb[0][col + 2] + gb[1][col + 2];
    float o3 = (v.w - mu) * rs * gb[0][col + 3] + gb[1][col + 3];
    *(uint2*)&nxb[g] = make_uint2(packbf(o0, o1), packbf(o2, o3));
  }
  if (t < D) {
    int b = rowA0 >> 11;
    float s = 0.f;
#pragma unroll 16
    for (int r2 = 0; r2 < 64; r2++) s += C[r2][t];
    atomicAdd(&relay[b * D + t], s * (1.0f / L));
  }
}

// ================= ro GEMM (32x128 tile, K=512, 256 blocks) + residual + mask +
// fused next-layer LN + fused relay-attention partial (chunk = this tile's 32 rows)
__global__ __launch_bounds__(256) void gemm_ro_ln(
    const u16* __restrict__ A,      // attb [B*L, 512]
    const u16* __restrict__ W,      // ro_w bf16 [128, 512]
    const float* __restrict__ bias, // ro_b [128]
    const int* __restrict__ mask,
    const float* __restrict__ lng, const float* __restrict__ lnb,
    const float* __restrict__ uvec, const float* __restrict__ cvec,
    float* __restrict__ nodes, u16* __restrict__ nxb,
    float* __restrict__ pm, float* __restrict__ ps, float* __restrict__ pw,
    int do_ln) {
  __shared__ u16 As[32][136];
  __shared__ u16 Ws[128][136];
  __shared__ float C[32][132];
  __shared__ float gb[2][D];
  __shared__ float lmu[32], lrs[32];
  __shared__ float usv[NH][D];
  __shared__ float cv2[NH];
  __shared__ float scs[NH][32];
  __shared__ float esr[NH][32];
  int t = threadIdx.x;
  int bm = blockIdx.x;               // 256 blocks
  const int rowA0 = bm * 32;
  const int b4 = rowA0 >> 11;
  const int chunk = (rowA0 >> 5) & 63;

  f32x4 acc[4];
#pragma unroll
  for (int j = 0; j < 4; j++) acc[j] = (f32x4){0.f, 0.f, 0.f, 0.f};

  const int wid = t >> 6;
  const int wm = (wid & 1) * 16, wn = (wid >> 1) * 64;
  const int lr = t & 15, quad = (t >> 4) & 3;
  const int ra = t >> 3, ca = (t & 7) * 16;
  const int rw = t >> 1, cw = (t & 1) * 64;

  if (do_ln && t < D) { gb[0][t] = lng[t]; gb[1][t] = lnb[t]; }
#pragma unroll
  for (int rep = 0; rep < 2; rep++) {
    int idx = rep * 256 + t;
    usv[idx >> 7][idx & 127] = uvec[(size_t)b4 * NH * D + idx];
  }
  if (t < NH) cv2[t] = cvec[b4 * NH + t];

  const u16* Arow = A + (size_t)(rowA0 + ra) * 512;
  const u16* Wrow = W + (size_t)rw * 512;

  for (int kt = 0; kt < 512; kt += 128) {
    uint4 a0 = *(const uint4*)(Arow + kt + ca);
    uint4 a1 = *(const uint4*)(Arow + kt + ca + 8);
    uint4 w0 = *(const uint4*)(Wrow + kt + cw);
    uint4 w1 = *(const uint4*)(Wrow + kt + cw + 8);
    uint4 w2 = *(const uint4*)(Wrow + kt + cw + 16);
    uint4 w3 = *(const uint4*)(Wrow + kt + cw + 24);
    uint4 w4 = *(const uint4*)(Wrow + kt + cw + 32);
    uint4 w5 = *(const uint4*)(Wrow + kt + cw + 40);
    uint4 w6 = *(const uint4*)(Wrow + kt + cw + 48);
    uint4 w7 = *(const uint4*)(Wrow + kt + cw + 56);
    __syncthreads();
    *(uint4*)&As[ra][ca] = a0; *(uint4*)&As[ra][ca + 8] = a1;
    *(uint4*)&Ws[rw][cw] = w0; *(uint4*)&Ws[rw][cw + 8] = w1;
    *(uint4*)&Ws[rw][cw + 16] = w2; *(uint4*)&Ws[rw][cw + 24] = w3;
    *(uint4*)&Ws[rw][cw + 32] = w4; *(uint4*)&Ws[rw][cw + 40] = w5;
    *(uint4*)&Ws[rw][cw + 48] = w6; *(uint4*)&Ws[rw][cw + 56] = w7;
    __syncthreads();
#pragma unroll
    for (int ks = 0; ks < 4; ks++) {
      bf16x8 af = *(const bf16x8*)&As[wm + lr][ks * 32 + quad * 8];
      bf16x8 bfr[4];
#pragma unroll
      for (int nt = 0; nt < 4; nt++)
        bfr[nt] = *(const bf16x8*)&Ws[wn + nt * 16 + lr][ks * 32 + quad * 8];
#pragma unroll
      for (int nt = 0; nt < 4; nt++)
        acc[nt] = __builtin_amdgcn_mfma_f32_16x16x32_bf16(af, bfr[nt], acc[nt], 0, 0, 0);
    }
  }
  __syncthreads();
#pragma unroll
  for (int nt = 0; nt < 4; nt++) {
    int col = wn + nt * 16 + lr;
    float bv = bias[col];
#pragma unroll
    for (int rr = 0; rr < 4; rr++) {
      int row = wm + quad * 4 + rr;
      float v = acc[nt][rr] + bv;
      v = (v > 0.f) ? v : 0.01f * v;
      v += nodes[(size_t)(rowA0 + row) * D + col];
      if (mask[rowA0 + row] == 0) v = 0.f;
      C[row][col] = v;
    }
  }
  __syncthreads();
  if (t < 32) {
    float s = 0.f, s2 = 0.f;
#pragma unroll 16
    for (int j = 0; j < D; j++) { float v = C[t][j]; s += v; s2 += v * v; }
    float mu = s * (1.0f / D);
    float var = s2 * (1.0f / D) - mu * mu;
    lmu[t] = mu; lrs[t] = rsqrtf(var + EPS);
  }
  __syncthreads();
#pragma unroll
  for (int rep = 0; rep < 4; rep++) {
    int lin = rep * 1024 + t * 4;
    int row = lin >> 7, col = lin & 127;
    float4 v = *(const float4*)&C[row][col];
    size_t g = (size_t)(rowA0 + row) * D + col;
    *(float4*)&nodes[g] = v;
    if (do_ln) {
      float mu = lmu[row], rs = lrs[row];
      float o0 = (v.x - mu) * rs * gb[0][col] + gb[1][col];
      float o1 = (v.y - mu) * rs * gb[0][col + 1] + gb[1][col + 1];
      float o2 = (v.z - mu) * rs * gb[0][col + 2] + gb[1][col + 2];
      float o3 = (v.w - mu) * rs * gb[0][col + 3] + gb[1][col + 3];
      *(uint2*)&nxb[g] = make_uint2(packbf(o0, o1), packbf(o2, o3));
    }
  }
  // ---- fused relay-attention partial: wave = head, chunk = this tile's 32 rows
  {
    int n = wid, lane = t & 63;
    int bn = b4 * NH + n;
    const float2* un = (const float2*)usv[n];
    float2 uv2 = un[lane];
    for (int r2 = 0; r2 < 32; r2++) {
      float2 cc = ((const float2*)&C[r2][0])[lane];
      float p = uv2.x * cc.x + uv2.y * cc.y;
#pragma unroll
      for (int o = 1; o < 64; o <<= 1) p += __shfl_xor(p, o, 64);
      if (lane == 0) {
        float s = p + cv2[n];
        if (mask[rowA0 + r2] == 0) s = -1e30f;
        scs[n][r2] = s;
      }
    }
    float m = -1e30f;
    for (int r2 = 0; r2 < 32; r2++) m = fmaxf(m, scs[n][r2]);
    if (lane < 32) esr[n][lane] = expf(scs[n][lane] - m);
    float sum = 0.f;
    for (int r2 = 0; r2 < 32; r2++) sum += esr[n][r2];
    if (lane == 0) { pm[bn * NCH + chunk] = m; ps[bn * NCH + chunk] = sum; }
    float a0 = 0.f, a1 = 0.f;
    for (int r2 = 0; r2 < 32; r2++) {
      float e = esr[n][r2];
      float2 cc = ((const float2*)&C[r2][0])[lane];
      a0 += e * cc.x; a1 += e * cc.y;
    }
    float* pwp = pw + ((size_t)bn * NCH + chunk) * D + 2 * lane;
    pwp[0] = a0; pwp[1] = a1;
  }
}

// ---------------- shared device helper: relay projections from rel[] in LDS
__device__ __forceinline__ void do_relay_proj(
    int b, int di, int t, const float* rel,
    const float* rkw, const float* rkb, const float* rvw, const float* rvb,
    const float* sqw, const float* sqb, const float* skw, const float* skb_,
    float* relay_k, float* relay_v, float* u, float* cvec,
    float* sql, float* cred) {
  const float4* r4 = (const float4*)rel;
  if (di < 8) {
    int which = di >> 2;           // 0 = rk, 1 = rv
    int n = (di & 3) * 128 + t;
    const float* W = which ? rvw : rkw;
    float acc = (which ? rvb : rkb)[n];
    const float4* w4 = (const float4*)(W + (size_t)n * D);
#pragma unroll 8
    for (int i = 0; i < D / 4; i++) {
      float4 w = w4[i], r = r4[i];
      acc += w.x * r.x + w.y * r.y + w.z * r.z + w.w * r.w;
    }
    (which ? relay_v : relay_k)[(size_t)b * D2 + n] = acc;
  } else {
    int n = di - 8;
    {
      int nh = n * HD + t;
      float acc = sqb[nh];
      const float4* w4 = (const float4*)(sqw + (size_t)nh * D);
#pragma unroll 8
      for (int i = 0; i < D / 4; i++) {
        float4 w = w4[i], r = r4[i];
        acc += w.x * r.x + w.y * r.y + w.z * r.z + w.w * r.w;
      }
      sql[t] = acc;
    }
    __syncthreads();
    {
      float cp = sql[t] * skb_[n * HD + t];
#pragma unroll
      for (int o = 1; o < 64; o <<= 1) cp += __shfl_xor(cp, o, 64);
      if ((t & 63) == 0) cred[t >> 6] = cp;
    }
    float a0 = 0.f, a1 = 0.f, a2 = 0.f, a3 = 0.f;
    const float* wp = skw + (size_t)(n * HD) * D + t;
    for (int h = 0; h < HD; h += 4) {
      a0 += sql[h] * wp[(size_t)h * D];
      a1 += sql[h + 1] * wp[(size_t)(h + 1) * D];
      a2 += sql[h + 2] * wp[(size_t)(h + 2) * D];
      a3 += sql[h + 3] * wp[(size_t)(h + 3) * D];
    }
    u[((size_t)b * NH + n) * D + t] = (a0 + a1 + a2 + a3) * SCALE;
    __syncthreads();
    if (t == 0) cvec[b * NH + n] = (cred[0] + cred[1]) * SCALE;
  }
}

// ---------------- standalone relay projections (layer 0), grid (B,12) x 128
__global__ __launch_bounds__(128) void relay_proj(
    const float* __restrict__ relay,
    const float* __restrict__ rkw, const float* __restrict__ rkb,
    const float* __restrict__ rvw, const float* __restrict__ rvb,
    const float* __restrict__ sqw, const float* __restrict__ sqb,
    const float* __restrict__ skw, const float* __restrict__ skb_,
    float* __restrict__ relay_k, float* __restrict__ relay_v,
    float* __restrict__ u, float* __restrict__ cvec) {
  __shared__ float rel[D];
  __shared__ float sql[HD];
  __shared__ float cred[2];
  int b = blockIdx.x, di = blockIdx.y, t = threadIdx.x;
  rel[t] = relay[(size_t)b * D + t];
  __syncthreads();
  do_relay_proj(b, di, t, rel, rkw, rkb, rvw, rvb, sqw, sqb, skw, skb_,
                relay_k, relay_v, u, cvec, sql, cred);
}

// ---------------- ring (windowed) attention; bf16 q/k/v/ak/av + att, fp32 rk/rv
__global__ __launch_bounds__(256) void ring_attn_kernel(
    const u16* __restrict__ q, const u16* __restrict__ k, const u16* __restrict__ v,
    const u16* __restrict__ akr, const u16* __restrict__ avr,
    const float* __restrict__ rk, const float* __restrict__ rv,
    u16* __restrict__ att) {
  int bl = blockIdx.x;
  int b = bl >> 11, l = bl & (L - 1);
  int n = threadIdx.x >> 6, lane = threadIdx.x & 63;
  int h = lane << 1;
  size_t base = (size_t)bl * D2 + n * HD + h;
  float2 qv = bf2x2(*(const uint_t*)(q + base));
  float s[5], v0[5], v1[5];
#pragma unroll
  for (int u = 0; u < 5; u++) {
    float k0 = 0.f, k1 = 0.f, vv0 = 0.f, vv1 = 0.f;
    if (u < 3) {
      int ll = l + u - 1;
      if (ll >= 0 && ll < L) {
        size_t off = ((size_t)b * L + ll) * D2 + n * HD + h;
        float2 kf = bf2x2(*(const uint_t*)(k + off));
        float2 vf = bf2x2(*(const uint_t*)(v + off));
        k0 = kf.x; k1 = kf.y; vv0 = vf.x; vv1 = vf.y;
      }
    } else if (u == 3) {
      float2 kf = bf2x2(*(const uint_t*)(akr + base));
      float2 vf = bf2x2(*(const uint_t*)(avr + base));
      k0 = kf.x; k1 = kf.y; vv0 = vf.x; vv1 = vf.y;
    } else {
      size_t rb = (size_t)b * D2 + n * HD + h;
      k0 = rk[rb]; k1 = rk[rb + 1]; vv0 = rv[rb]; vv1 = rv[rb + 1];
    }
    float p = qv.x * k0 + qv.y * k1;
#pragma unroll
    for (int o = 1; o < 64; o <<= 1) p += __shfl_xor(p, o, 64);
    s[u] = p * SCALE;
    v0[u] = vv0; v1[u] = vv1;
  }
  float m = s[0];
#pragma unroll
  for (int u = 1; u < 5; u++) m = fmaxf(m, s[u]);
  float sum = 0.f, o0 = 0.f, o1 = 0.f;
#pragma unroll
  for (int u = 0; u < 5; u++) {
    float e = expf(s[u] - m);
    sum += e; o0 += e * v0[u]; o1 += e * v1[u];
  }
  *(uint_t*)(att + base) = packbf(o0 / sum, o1 / sum);
}

// ---------------- combine (relay row + 64 node chunks) -> satt -> relay;
// then (optional) next-layer projections. grid (B, 12) when do_proj, else (B,1); 128 thr
__global__ __launch_bounds__(128) void relay_final(
    const float* __restrict__ pm, const float* __restrict__ ps, const float* __restrict__ pw,
    const float* __restrict__ relay_entry,
    const float* __restrict__ uvec_in, const float* __restrict__ cvec_in,
    const float* __restrict__ svw, const float* __restrict__ svb,
    const float* __restrict__ sow, const float* __restrict__ sob,
    const float* __restrict__ nrkw, const float* __restrict__ nrkb,
    const float* __restrict__ nrvw, const float* __restrict__ nrvb,
    const float* __restrict__ nsqw, const float* __restrict__ nsqb,
    const float* __restrict__ nskw, const float* __restrict__ nskb,
    float* __restrict__ relay_out,
    float* __restrict__ relay_k, float* __restrict__ relay_v,
    float* __restrict__ u_out, float* __restrict__ cvec_out, int do_proj) {
  int b = blockIdx.x, di = blockIdx.y, t = threadIdx.x;
  __shared__ float uu[NH][D];
  __shared__ float rel0[D];
  __shared__ float pms[NH][NCH], pss[NH][NCH], ecs[NH][NCH];
  __shared__ float s0s[NH], cvs[NH];
  __shared__ float wsum[NH][D];
  __shared__ float satts[D2];
  __shared__ float rel[D];
  __shared__ float sql[HD];
  __shared__ float cred[2];

  rel0[t] = relay_entry[(size_t)b * D + t];
#pragma unroll
  for (int rep = 0; rep < 4; rep++) {
    int idx = rep * 128 + t;
    uu[idx >> 7][idx & 127] = uvec_in[(size_t)b * NH * D + idx];
  }
  if (t < NH) cvs[t] = cvec_in[b * NH + t];
#pragma unroll
  for (int rep = 0; rep < 2; rep++) {
    int idx = rep * 128 + t;
    int n = idx >> 6, c = idx & 63;
    pms[n][c] = pm[(b * NH + n) * NCH + c];
    pss[n][c] = ps[(b * NH + n) * NCH + c];
  }
  __syncthreads();
  int g = t >> 5, lt = t & 31;
  // s0 = u_g . relay_entry + c_g
  {
    float p = 0.f;
#pragma unroll
    for (int k = 0; k < 4; k++) { int j = lt * 4 + k; p += uu[g][j] * rel0[j]; }
#pragma unroll
    for (int o = 1; o < 32; o <<= 1) p += __shfl_xor(p, o, 64);
    if (lt == 0) s0s[g] = p + cvs[g];
  }
  __syncthreads();
  float s0 = s0s[g];
  float M = s0;
  for (int c = 0; c < NCH; c++) M = fmaxf(M, pms[g][c]);
  for (int c = lt; c < NCH; c += 32) ecs[g][c] = expf(pms[g][c] - M);
  __syncthreads();
  float e0 = expf(s0 - M);
  float S = e0;
  for (int c = 0; c < NCH; c++) S += pss[g][c] * ecs[g][c];
  float invS = 1.0f / S;
#pragma unroll
  for (int k = 0; k < 4; k++) {
    int h = lt * 4 + k;
    float acc = e0 * rel0[h];
    const float* pwp = pw + ((size_t)(b * NH + g) * NCH) * D + h;
    for (int c = 0; c < NCH; c++) acc += ecs[g][c] * pwp[(size_t)c * D];
    wsum[g][h] = acc * invS;
  }
  __syncthreads();
  // satts[nh] = wsum . svw + svb
#pragma unroll
  for (int rep = 0; rep < 4; rep++) {
    int nh = rep * 128 + t;
    int hn = nh >> 7;
    float acc = svb[nh];
    const float4* wp = (const float4*)(svw + (size_t)nh * D);
    const float4* wl = (const float4*)wsum[hn];
#pragma unroll 8
    for (int d = 0; d < D / 4; d++) {
      float4 a = wl[d], wv4 = wp[d];
      acc += a.x * wv4.x + a.y * wv4.y + a.z * wv4.z + a.w * wv4.w;
    }
    satts[nh] = acc;
  }
  __syncthreads();
  {
    float acc = sob[t];
    const float4* wp = (const float4*)(sow + (size_t)t * D2);
    const float4* a4 = (const float4*)satts;
#pragma unroll 8
    for (int j = 0; j < D2 / 4; j++) {
      float4 a = a4[j], wv4 = wp[j];
      acc += a.x * wv4.x + a.y * wv4.y + a.z * wv4.z + a.w * wv4.w;
    }
    acc = (acc > 0.f) ? acc : 0.01f * acc;
    rel[t] = acc;
    relay_out[(size_t)b * D + t] = acc;
  }
  __syncthreads();
  if (do_proj)
    do_relay_proj(b, di, t, rel, nrkw, nrkb, nrvw, nrvb, nsqw, nsqb, nskw, nskb,
                  relay_k, relay_v, u_out, cvec_out, sql, cred);
}

extern "C" void kernel_launch(void* const* d_in, const int* in_sizes, int n_in,
                              void* d_out, int out_size, void* d_ws, size_t ws_size,
                              hipStream_t stream) {
  const int* tokens = (const int*)d_in[0];
  const int* mask = (const int*)d_in[1];
  const float* emb = (const float*)d_in[2];
  const float* proj_w = (const float*)d_in[3];
  const float* proj_b = (const float*)d_in[4];
  const float* ng = (const float*)d_in[5];
  const float* nb = (const float*)d_in[6];
  const float* rq_w = (const float*)d_in[7], * rq_b = (const float*)d_in[8];
  const float* rk_w = (const float*)d_in[9], * rk_b = (const float*)d_in[10];
  const float* rv_w = (const float*)d_in[11], * rv_b = (const float*)d_in[12];
  const float* ro_w = (const float*)d_in[13], * ro_b = (const float*)d_in[14];
  const float* sq_w = (const float*)d_in[15], * sq_b = (const float*)d_in[16];
  const float* sk_w = (const float*)d_in[17], * sk_b = (const float*)d_in[18];
  const float* sv_w = (const float*)d_in[19], * sv_b = (const float*)d_in[20];
  const float* so_w = (const float*)d_in[21], * so_b = (const float*)d_in[22];

  const size_t BLD = (size_t)B * L * D;        // 1,048,576
  const size_t BLD4 = (size_t)B * L * D2;      // 4,194,304
  const size_t WTEN = (size_t)NL * D * D2;     // 196,608 per tensor

  float* fp = (float*)d_ws;
  float* nodes = fp;                    fp += BLD;
  float* rbuf0 = fp;                    fp += B * D;
  float* rbuf1 = fp;                    fp += B * D;
  float* relay_k = fp;                  fp += B * D2;
  float* relay_v = fp;                  fp += B * D2;
  float* uv0 = fp;                      fp += B * NH * D;
  float* uv1 = fp;                      fp += B * NH * D;
  float* cv0 = fp;                      fp += B * NH;
  float* cv1 = fp;                      fp += B * NH;
  float* pm = fp;                       fp += B * NH * NCH;
  float* ps = fp;                       fp += B * NH * NCH;
  float* pw = fp;                       fp += (size_t)B * NH * NCH * D;
  u16* up = (u16*)fp;
  u16* xb = up;                         up += BLD;
  u16* nxb = up;                        up += BLD;
  u16* qb = up;                         up += BLD4;
  u16* kb = up;                         up += BLD4;
  u16* vb = up;                         up += BLD4;
  u16* akb = up;                        up += BLD4;
  u16* avb = up;                        up += BLD4;
  u16* attb = up;                       up += BLD4;
  u16* wb = up;                         // 4 * WTEN
  u16* wrq = wb, * wrk = wb + WTEN, * wrv = wb + 2 * WTEN, * wro = wb + 3 * WTEN;

  float* rbuf[2] = {rbuf0, rbuf1};
  float* uv[2] = {uv0, uv1};
  float* cv[2] = {cv0, cv1};

  hipMemsetAsync(rbuf0, 0, B * D * sizeof(float), stream);

  {
    WCArgs wa;
    wa.s[0] = rq_w; wa.s[1] = rk_w; wa.s[2] = rv_w; wa.s[3] = ro_w;
    wa.d[0] = wrq; wa.d[1] = wrk; wa.d[2] = wrv; wa.d[3] = wro;
    wconv<<<dim3(WTEN / 1024, 4), 256, 0, stream>>>(wa);
  }
  // embedding projection + layer-0 LN + relay mean: nodes, xb, nxb, relay0
  gemm_embed_ln<<<128, 256, 0, stream>>>(emb, proj_w, proj_b, tokens, ng, nb,
                                         nodes, xb, nxb, rbuf0);
  // layer-0 relay-side projections
  relay_proj<<<dim3(B, 12), 128, 0, stream>>>(rbuf0, rk_w, rk_b, rv_w, rv_b, sq_w, sq_b,
                                              sk_w, sk_b, relay_k, relay_v, uv0, cv0);

  for (int i = 0; i < NL; i++) {
    const size_t wo = (size_t)i * D * D2;
    const float* rqbi = rq_b + (size_t)i * D2;
    const float* rkbi = rk_b + (size_t)i * D2;
    const float* rvbi = rv_b + (size_t)i * D2;
    const float* robi = ro_b + (size_t)i * D;
    const float* svwi = sv_w + wo, * svbi = sv_b + (size_t)i * D2;
    const float* sowi = so_w + wo, * sobi = so_b + (size_t)i * D;
    const int e = i & 1, nx2 = e ^ 1;
    const int last = (i == NL - 1);

    // q,k,v (from nxb) + ak,av (from xb): one dispatch, 128x128 tiles
    {
      GArgs ga = {};
      ga.d[0] = {nxb, wrq + wo, rqbi, qb};
      ga.d[1] = {nxb, wrk + wo, rkbi, kb};
      ga.d[2] = {nxb, wrv + wo, rvbi, vb};
      ga.d[3] = {xb,  wrk + wo, rkbi, akb};
      ga.d[4] = {xb,  wrv + wo, rvbi, avb};
      gemm_qkv<<<dim3(64, 20), 256, 0, stream>>>(ga, 4, D2);
    }
    ring_attn_kernel<<<B * L, 256, 0, stream>>>(qb, kb, vb, akb, avb, relay_k, relay_v, attb);
    // ro GEMM + residual + mask + next-layer LN + relay-attn partials
    gemm_ro_ln<<<256, 256, 0, stream>>>(
        attb, wro + wo, robi, mask,
        last ? nullptr : ng + (i + 1) * D, last ? nullptr : nb + (i + 1) * D,
        uv[e], cv[e], nodes, nxb, pm, ps, pw, last ? 0 : 1);
    // combine (incl. relay row) + project relay; fuse next layer's relay-side projections
    const size_t wn_ = (size_t)(i + 1) * D * D2;
    float* relay_dst = last ? (float*)d_out : rbuf[nx2];
    relay_final<<<dim3(B, last ? 1 : 12), 128, 0, stream>>>(
        pm, ps, pw, rbuf[e], uv[e], cv[e], svwi, svbi, sowi, sobi,
        last ? nullptr : rk_w + wn_, last ? nullptr : rk_b + (size_t)(i + 1) * D2,
        last ? nullptr : rv_w + wn_, last ? nullptr : rv_b + (size_t)(i + 1) * D2,
        last ? nullptr : sq_w + wn_, last ? nullptr : sq_b + (size_t)(i + 1) * D2,
        last ? nullptr : sk_w + wn_, last ? nullptr : sk_b + (size_t)(i + 1) * D2,
        relay_dst, relay_k, relay_v, uv[nx2], cv[nx2], last ? 0 : 1);
  }
}

// Round 13
// 383.046 us; speedup vs baseline: 1.2546x; 1.0485x over previous
//
#include <hip/hip_runtime.h>
#include <hip/hip_bf16.h>

// Problem constants
constexpr int B = 4, L = 2048, E = 300, D = 128, NH = 4, HD = 128, NL = 3, D2 = 512;
constexpr float EPS = 1e-5f;
constexpr float SCALE = 0.08838834764831843f; // 1/sqrt(128)
constexpr int NCH = 64;              // relay-attention node chunks (32 rows each = ro tile)

typedef unsigned int uint_t;
typedef unsigned short u16;
typedef short bf16x8 __attribute__((ext_vector_type(8)));
typedef float f32x4 __attribute__((ext_vector_type(4)));

__device__ __forceinline__ u16 f2bf(float f) {
  union { float f; uint_t i; } x; x.f = f;
  uint_t r = x.i + 0x7fffu + ((x.i >> 16) & 1u);
  return (u16)(r >> 16);
}
__device__ __forceinline__ uint_t packbf(float a, float b) {
  return (uint_t)f2bf(a) | ((uint_t)f2bf(b) << 16);
}
__device__ __forceinline__ float bf2f(u16 u) {
  union { uint_t i; float f; } x; x.i = ((uint_t)u) << 16; return x.f;
}
__device__ __forceinline__ float2 bf2x2(uint_t u) {
  union { uint_t i; float f; } a, b;
  a.i = (u & 0xffffu) << 16; b.i = u & 0xffff0000u;
  return make_float2(a.f, b.f);
}
struct f8 { float v[8]; };
__device__ __forceinline__ f8 unpack8(uint4 u) {
  f8 r;
  float2 a = bf2x2(u.x); r.v[0] = a.x; r.v[1] = a.y;
  float2 b = bf2x2(u.y); r.v[2] = b.x; r.v[3] = b.y;
  float2 c = bf2x2(u.z); r.v[4] = c.x; r.v[5] = c.y;
  float2 d = bf2x2(u.w); r.v[6] = d.x; r.v[7] = d.y;
  return r;
}

// ---------------- weight pre-conversion: 4 tensors (rq,rk,rv,ro), NL*D*D2 fp32 -> bf16
struct WCArgs { const float* s[4]; u16* d[4]; };
__global__ __launch_bounds__(256) void wconv(WCArgs wa) {
  int ti = blockIdx.y;
  const float* s = wa.s[ti]; u16* dd = wa.d[ti];
  int i = (blockIdx.x * 256 + threadIdx.x) * 4;
  float4 f = *(const float4*)(s + i);
  *(uint2*)(dd + i) = make_uint2(packbf(f.x, f.y), packbf(f.z, f.w));
}

// ================= qkv GEMM: 128x128 tile, K=128 (single stage, one barrier)
struct GDesc { const u16* A; const u16* W; const float* bias; u16* outb; };
struct GArgs { GDesc d[5]; };

__global__ __launch_bounds__(256) void gemm_qkv(GArgs ga, int nby, int N) {
  __shared__ u16 As[128][136];
  __shared__ u16 Ws[128][136];
  int t = threadIdx.x;
  int bm = blockIdx.x;
  int di = blockIdx.y / nby, bn = blockIdx.y - di * nby;
  GDesc d = ga.d[di];
  const int rowA = bm * 128, rowW = bn * 128;

  f32x4 acc[4][4];
#pragma unroll
  for (int i = 0; i < 4; i++)
#pragma unroll
    for (int j = 0; j < 4; j++)
      acc[i][j] = (f32x4){0.f, 0.f, 0.f, 0.f};

  const int r = t >> 1, c0 = (t & 1) * 64;
  const int wid = t >> 6;
  const int wm = (wid & 1) * 64, wn = (wid >> 1) * 64;
  const int lr = t & 15, quad = (t >> 4) & 3;

  const u16* Arow = d.A + (size_t)(rowA + r) * 128;
  const u16* Wrow = d.W + (size_t)(rowW + r) * 128;
  uint4 av_[8], wv_[8];
#pragma unroll
  for (int i = 0; i < 8; i++) {
    av_[i] = *(const uint4*)(Arow + c0 + i * 8);
    wv_[i] = *(const uint4*)(Wrow + c0 + i * 8);
  }
#pragma unroll
  for (int i = 0; i < 8; i++) {
    *(uint4*)&As[r][c0 + i * 8] = av_[i];
    *(uint4*)&Ws[r][c0 + i * 8] = wv_[i];
  }
  __syncthreads();
#pragma unroll
  for (int ks = 0; ks < 4; ks++) {
    bf16x8 af[4], bfr[4];
#pragma unroll
    for (int mt = 0; mt < 4; mt++)
      af[mt] = *(const bf16x8*)&As[wm + mt * 16 + lr][ks * 32 + quad * 8];
#pragma unroll
    for (int nt = 0; nt < 4; nt++)
      bfr[nt] = *(const bf16x8*)&Ws[wn + nt * 16 + lr][ks * 32 + quad * 8];
#pragma unroll
    for (int mt = 0; mt < 4; mt++)
#pragma unroll
      for (int nt = 0; nt < 4; nt++)
        acc[mt][nt] = __builtin_amdgcn_mfma_f32_16x16x32_bf16(af[mt], bfr[nt], acc[mt][nt], 0, 0, 0);
  }
#pragma unroll
  for (int nt = 0; nt < 4; nt++) {
    int col = rowW + wn + nt * 16 + lr;
    float bv = d.bias[col];
#pragma unroll
    for (int mt = 0; mt < 4; mt++) {
#pragma unroll
      for (int rr = 0; rr < 4; rr++) {
        int row = rowA + wm + mt * 16 + quad * 4 + rr;
        d.outb[(size_t)row * N + col] = f2bf(acc[mt][nt][rr] + bv);
      }
    }
  }
}

// ================= embedding projection (gathered A, K=300, 64x128 tile) +
// fused layer-0 LN (-> nxb) + relay mean (atomics) + nodes/xb writes
__global__ __launch_bounds__(256) void gemm_embed_ln(
    const float* __restrict__ emb, const float* __restrict__ W,
    const float* __restrict__ bias, const int* __restrict__ gather,
    const float* __restrict__ lng, const float* __restrict__ lnb,
    float* __restrict__ nodes, u16* __restrict__ xb, u16* __restrict__ nxb,
    float* __restrict__ relay) {
  __shared__ u16 As[64][72];
  __shared__ u16 Ws[128][72];
  __shared__ float C[64][132];
  __shared__ float gb[2][D];
  __shared__ float lmu[64], lrs[64];
  int t = threadIdx.x;
  int bm = blockIdx.x;               // 128 blocks
  const int rowA0 = bm * 64;

  f32x4 acc[2][4];
#pragma unroll
  for (int i = 0; i < 2; i++)
#pragma unroll
    for (int j = 0; j < 4; j++)
      acc[i][j] = (f32x4){0.f, 0.f, 0.f, 0.f};

  const int wid = t >> 6;
  const int wm = (wid & 1) * 32, wn = (wid >> 1) * 64;
  const int lr = t & 15, quad = (t >> 4) & 3;
  const int ra = t >> 2, ca = (t & 3) * 16;
  const int rw = t >> 1, cw = (t & 1) * 32;

  if (t < D) { gb[0][t] = lng[t]; gb[1][t] = lnb[t]; }

  const float* Arow = emb + (size_t)gather[rowA0 + ra] * E;
  const float* Wrow = W + (size_t)rw * E;

  for (int kt = 0; kt < E; kt += 64) {
    __syncthreads();
    bool full = (kt + 64 <= E);
#pragma unroll
    for (int ch = 0; ch < 4; ch++) {
      int c = kt + ca + ch * 4;
      float4 fa;
      if (full) fa = *(const float4*)(Arow + c);
      else {
        fa.x = (c + 0 < E) ? Arow[c + 0] : 0.f;
        fa.y = (c + 1 < E) ? Arow[c + 1] : 0.f;
        fa.z = (c + 2 < E) ? Arow[c + 2] : 0.f;
        fa.w = (c + 3 < E) ? Arow[c + 3] : 0.f;
      }
      *(uint2*)&As[ra][ca + ch * 4] = make_uint2(packbf(fa.x, fa.y), packbf(fa.z, fa.w));
    }
#pragma unroll
    for (int ch = 0; ch < 8; ch++) {
      int c = kt + cw + ch * 4;
      float4 fw;
      if (full) fw = *(const float4*)(Wrow + c);
      else {
        fw.x = (c + 0 < E) ? Wrow[c + 0] : 0.f;
        fw.y = (c + 1 < E) ? Wrow[c + 1] : 0.f;
        fw.z = (c + 2 < E) ? Wrow[c + 2] : 0.f;
        fw.w = (c + 3 < E) ? Wrow[c + 3] : 0.f;
      }
      *(uint2*)&Ws[rw][cw + ch * 4] = make_uint2(packbf(fw.x, fw.y), packbf(fw.z, fw.w));
    }
    __syncthreads();
#pragma unroll
    for (int ks = 0; ks < 2; ks++) {
      bf16x8 af[2], bfr[4];
#pragma unroll
      for (int mt = 0; mt < 2; mt++)
        af[mt] = *(const bf16x8*)&As[wm + mt * 16 + lr][ks * 32 + quad * 8];
#pragma unroll
      for (int nt = 0; nt < 4; nt++)
        bfr[nt] = *(const bf16x8*)&Ws[wn + nt * 16 + lr][ks * 32 + quad * 8];
#pragma unroll
      for (int mt = 0; mt < 2; mt++)
#pragma unroll
        for (int nt = 0; nt < 4; nt++)
          acc[mt][nt] = __builtin_amdgcn_mfma_f32_16x16x32_bf16(af[mt], bfr[nt], acc[mt][nt], 0, 0, 0);
    }
  }
#pragma unroll
  for (int nt = 0; nt < 4; nt++) {
    int col = wn + nt * 16 + lr;
    float bv = bias[col];
#pragma unroll
    for (int mt = 0; mt < 2; mt++) {
#pragma unroll
      for (int rr = 0; rr < 4; rr++) {
        int row = wm + mt * 16 + quad * 4 + rr;
        C[row][col] = acc[mt][nt][rr] + bv;
      }
    }
  }
  __syncthreads();
  if (t < 64) {
    float s = 0.f, s2 = 0.f;
#pragma unroll 16
    for (int j = 0; j < D; j++) { float v = C[t][j]; s += v; s2 += v * v; }
    float mu = s * (1.0f / D);
    float var = s2 * (1.0f / D) - mu * mu;
    lmu[t] = mu; lrs[t] = rsqrtf(var + EPS);
  }
  __syncthreads();
#pragma unroll
  for (int rep = 0; rep < 8; rep++) {
    int lin = rep * 1024 + t * 4;
    int row = lin >> 7, col = lin & 127;
    float4 v = *(const float4*)&C[row][col];
    size_t g = (size_t)(rowA0 + row) * D + col;
    *(float4*)&nodes[g] = v;
    *(uint2*)&xb[g] = make_uint2(packbf(v.x, v.y), packbf(v.z, v.w));
    float mu = lmu[row], rs = lrs[row];
    float o0 = (v.x - mu) * rs * gb[0][col] + gb[1][col];
    float o1 = (v.y - mu) * rs * gb[0][col + 1] + gb[1][col + 1];
    float o2 = (v.z - mu) * rs * gb[0][col + 2] + gb[1][col + 2];
    float o3 = (v.w - mu) * rs * gb[0][col + 3] + gb[1][col + 3];
    *(uint2*)&nxb[g] = make_uint2(packbf(o0, o1), packbf(o2, o3));
  }
  if (t < D) {
    int b = rowA0 >> 11;
    float s = 0.f;
#pragma unroll 16
    for (int r2 = 0; r2 < 64; r2++) s += C[r2][t];
    atomicAdd(&relay[b * D + t], s * (1.0f / L));
  }
}

// ================= ro GEMM (32x128 tile, K=512, 256 blocks) + residual + mask +
// fused next-layer LN + fused relay-attention partial (chunk = this tile's 32 rows)
__global__ __launch_bounds__(256) void gemm_ro_ln(
    const u16* __restrict__ A,      // attb [B*L, 512]
    const u16* __restrict__ W,      // ro_w bf16 [128, 512]
    const float* __restrict__ bias, // ro_b [128]
    const int* __restrict__ mask,
    const float* __restrict__ lng, const float* __restrict__ lnb,
    const float* __restrict__ uvec, const float* __restrict__ cvec,
    float* __restrict__ nodes, u16* __restrict__ nxb,
    float* __restrict__ pm, float* __restrict__ ps, float* __restrict__ pw,
    int do_ln) {
  __shared__ u16 As[32][136];
  __shared__ u16 Ws[128][136];
  __shared__ float C[32][132];
  __shared__ float gb[2][D];
  __shared__ float lmu[32], lrs[32];
  __shared__ float usv[NH][D];
  __shared__ float cv2[NH];
  __shared__ float scs[NH][32];
  __shared__ float esr[NH][32];
  int t = threadIdx.x;
  int bm = blockIdx.x;               // 256 blocks
  const int rowA0 = bm * 32;
  const int b4 = rowA0 >> 11;
  const int chunk = (rowA0 >> 5) & 63;

  f32x4 acc[4];
#pragma unroll
  for (int j = 0; j < 4; j++) acc[j] = (f32x4){0.f, 0.f, 0.f, 0.f};

  const int wid = t >> 6;
  const int wm = (wid & 1) * 16, wn = (wid >> 1) * 64;
  const int lr = t & 15, quad = (t >> 4) & 3;
  const int ra = t >> 3, ca = (t & 7) * 16;
  const int rw = t >> 1, cw = (t & 1) * 64;

  if (do_ln && t < D) { gb[0][t] = lng[t]; gb[1][t] = lnb[t]; }
#pragma unroll
  for (int rep = 0; rep < 2; rep++) {
    int idx = rep * 256 + t;
    usv[idx >> 7][idx & 127] = uvec[(size_t)b4 * NH * D + idx];
  }
  if (t < NH) cv2[t] = cvec[b4 * NH + t];

  const u16* Arow = A + (size_t)(rowA0 + ra) * 512;
  const u16* Wrow = W + (size_t)rw * 512;

  for (int kt = 0; kt < 512; kt += 128) {
    uint4 a0 = *(const uint4*)(Arow + kt + ca);
    uint4 a1 = *(const uint4*)(Arow + kt + ca + 8);
    uint4 w0 = *(const uint4*)(Wrow + kt + cw);
    uint4 w1 = *(const uint4*)(Wrow + kt + cw + 8);
    uint4 w2 = *(const uint4*)(Wrow + kt + cw + 16);
    uint4 w3 = *(const uint4*)(Wrow + kt + cw + 24);
    uint4 w4 = *(const uint4*)(Wrow + kt + cw + 32);
    uint4 w5 = *(const uint4*)(Wrow + kt + cw + 40);
    uint4 w6 = *(const uint4*)(Wrow + kt + cw + 48);
    uint4 w7 = *(const uint4*)(Wrow + kt + cw + 56);
    __syncthreads();
    *(uint4*)&As[ra][ca] = a0; *(uint4*)&As[ra][ca + 8] = a1;
    *(uint4*)&Ws[rw][cw] = w0; *(uint4*)&Ws[rw][cw + 8] = w1;
    *(uint4*)&Ws[rw][cw + 16] = w2; *(uint4*)&Ws[rw][cw + 24] = w3;
    *(uint4*)&Ws[rw][cw + 32] = w4; *(uint4*)&Ws[rw][cw + 40] = w5;
    *(uint4*)&Ws[rw][cw + 48] = w6; *(uint4*)&Ws[rw][cw + 56] = w7;
    __syncthreads();
#pragma unroll
    for (int ks = 0; ks < 4; ks++) {
      bf16x8 af = *(const bf16x8*)&As[wm + lr][ks * 32 + quad * 8];
      bf16x8 bfr[4];
#pragma unroll
      for (int nt = 0; nt < 4; nt++)
        bfr[nt] = *(const bf16x8*)&Ws[wn + nt * 16 + lr][ks * 32 + quad * 8];
#pragma unroll
      for (int nt = 0; nt < 4; nt++)
        acc[nt] = __builtin_amdgcn_mfma_f32_16x16x32_bf16(af, bfr[nt], acc[nt], 0, 0, 0);
    }
  }
  __syncthreads();
#pragma unroll
  for (int nt = 0; nt < 4; nt++) {
    int col = wn + nt * 16 + lr;
    float bv = bias[col];
#pragma unroll
    for (int rr = 0; rr < 4; rr++) {
      int row = wm + quad * 4 + rr;
      float v = acc[nt][rr] + bv;
      v = (v > 0.f) ? v : 0.01f * v;
      v += nodes[(size_t)(rowA0 + row) * D + col];
      if (mask[rowA0 + row] == 0) v = 0.f;
      C[row][col] = v;
    }
  }
  __syncthreads();
  if (t < 32) {
    float s = 0.f, s2 = 0.f;
#pragma unroll 16
    for (int j = 0; j < D; j++) { float v = C[t][j]; s += v; s2 += v * v; }
    float mu = s * (1.0f / D);
    float var = s2 * (1.0f / D) - mu * mu;
    lmu[t] = mu; lrs[t] = rsqrtf(var + EPS);
  }
  __syncthreads();
#pragma unroll
  for (int rep = 0; rep < 4; rep++) {
    int lin = rep * 1024 + t * 4;
    int row = lin >> 7, col = lin & 127;
    float4 v = *(const float4*)&C[row][col];
    size_t g = (size_t)(rowA0 + row) * D + col;
    *(float4*)&nodes[g] = v;
    if (do_ln) {
      float mu = lmu[row], rs = lrs[row];
      float o0 = (v.x - mu) * rs * gb[0][col] + gb[1][col];
      float o1 = (v.y - mu) * rs * gb[0][col + 1] + gb[1][col + 1];
      float o2 = (v.z - mu) * rs * gb[0][col + 2] + gb[1][col + 2];
      float o3 = (v.w - mu) * rs * gb[0][col + 3] + gb[1][col + 3];
      *(uint2*)&nxb[g] = make_uint2(packbf(o0, o1), packbf(o2, o3));
    }
  }
  // ---- fused relay-attention partial: wave = head, chunk = this tile's 32 rows
  {
    int n = wid, lane = t & 63;
    int bn = b4 * NH + n;
    const float2* un = (const float2*)usv[n];
    float2 uv2 = un[lane];
    for (int r2 = 0; r2 < 32; r2++) {
      float2 cc = ((const float2*)&C[r2][0])[lane];
      float p = uv2.x * cc.x + uv2.y * cc.y;
#pragma unroll
      for (int o = 1; o < 64; o <<= 1) p += __shfl_xor(p, o, 64);
      if (lane == 0) {
        float s = p + cv2[n];
        if (mask[rowA0 + r2] == 0) s = -1e30f;
        scs[n][r2] = s;
      }
    }
    float m = -1e30f;
    for (int r2 = 0; r2 < 32; r2++) m = fmaxf(m, scs[n][r2]);
    if (lane < 32) esr[n][lane] = expf(scs[n][lane] - m);
    float sum = 0.f;
    for (int r2 = 0; r2 < 32; r2++) sum += esr[n][r2];
    if (lane == 0) { pm[bn * NCH + chunk] = m; ps[bn * NCH + chunk] = sum; }
    float a0 = 0.f, a1 = 0.f;
    for (int r2 = 0; r2 < 32; r2++) {
      float e = esr[n][r2];
      float2 cc = ((const float2*)&C[r2][0])[lane];
      a0 += e * cc.x; a1 += e * cc.y;
    }
    float* pwp = pw + ((size_t)bn * NCH + chunk) * D + 2 * lane;
    pwp[0] = a0; pwp[1] = a1;
  }
}

// ---------------- shared device helper: relay projections from rel[] in LDS
__device__ __forceinline__ void do_relay_proj(
    int b, int di, int t, const float* rel,
    const float* rkw, const float* rkb, const float* rvw, const float* rvb,
    const float* sqw, const float* sqb, const float* skw, const float* skb_,
    float* relay_k, float* relay_v, float* u, float* cvec,
    float* sql, float* cred) {
  const float4* r4 = (const float4*)rel;
  if (di < 8) {
    int which = di >> 2;           // 0 = rk, 1 = rv
    int n = (di & 3) * 128 + t;
    const float* W = which ? rvw : rkw;
    float acc = (which ? rvb : rkb)[n];
    const float4* w4 = (const float4*)(W + (size_t)n * D);
#pragma unroll 8
    for (int i = 0; i < D / 4; i++) {
      float4 w = w4[i], r = r4[i];
      acc += w.x * r.x + w.y * r.y + w.z * r.z + w.w * r.w;
    }
    (which ? relay_v : relay_k)[(size_t)b * D2 + n] = acc;
  } else {
    int n = di - 8;
    {
      int nh = n * HD + t;
      float acc = sqb[nh];
      const float4* w4 = (const float4*)(sqw + (size_t)nh * D);
#pragma unroll 8
      for (int i = 0; i < D / 4; i++) {
        float4 w = w4[i], r = r4[i];
        acc += w.x * r.x + w.y * r.y + w.z * r.z + w.w * r.w;
      }
      sql[t] = acc;
    }
    __syncthreads();
    {
      float cp = sql[t] * skb_[n * HD + t];
#pragma unroll
      for (int o = 1; o < 64; o <<= 1) cp += __shfl_xor(cp, o, 64);
      if ((t & 63) == 0) cred[t >> 6] = cp;
    }
    float a0 = 0.f, a1 = 0.f, a2 = 0.f, a3 = 0.f;
    const float* wp = skw + (size_t)(n * HD) * D + t;
    for (int h = 0; h < HD; h += 4) {
      a0 += sql[h] * wp[(size_t)h * D];
      a1 += sql[h + 1] * wp[(size_t)(h + 1) * D];
      a2 += sql[h + 2] * wp[(size_t)(h + 2) * D];
      a3 += sql[h + 3] * wp[(size_t)(h + 3) * D];
    }
    u[((size_t)b * NH + n) * D + t] = (a0 + a1 + a2 + a3) * SCALE;
    __syncthreads();
    if (t == 0) cvec[b * NH + n] = (cred[0] + cred[1]) * SCALE;
  }
}

// ---------------- standalone relay projections (layer 0), grid (B,12) x 128
__global__ __launch_bounds__(128) void relay_proj(
    const float* __restrict__ relay,
    const float* __restrict__ rkw, const float* __restrict__ rkb,
    const float* __restrict__ rvw, const float* __restrict__ rvb,
    const float* __restrict__ sqw, const float* __restrict__ sqb,
    const float* __restrict__ skw, const float* __restrict__ skb_,
    float* __restrict__ relay_k, float* __restrict__ relay_v,
    float* __restrict__ u, float* __restrict__ cvec) {
  __shared__ float rel[D];
  __shared__ float sql[HD];
  __shared__ float cred[2];
  int b = blockIdx.x, di = blockIdx.y, t = threadIdx.x;
  rel[t] = relay[(size_t)b * D + t];
  __syncthreads();
  do_relay_proj(b, di, t, rel, rkw, rkb, rvw, rvb, sqw, sqb, skw, skb_,
                relay_k, relay_v, u, cvec, sql, cred);
}

// ---------------- ring (windowed) attention, full-row vectorized:
// one wave per (b,l); lane covers 8 contiguous bf16 of the D2=512 row
// (head = lane>>4); dots reduce over 16-lane groups (4 shfl steps).
__global__ __launch_bounds__(256) void ring_attn_kernel(
    const u16* __restrict__ q, const u16* __restrict__ k, const u16* __restrict__ v,
    const u16* __restrict__ akr, const u16* __restrict__ avr,
    const float* __restrict__ rk, const float* __restrict__ rv,
    u16* __restrict__ att) {
  int wv = threadIdx.x >> 6, lane = threadIdx.x & 63;
  int bl = blockIdx.x * 4 + wv;
  int b = bl >> 11, l = bl & (L - 1);
  size_t rowoff = (size_t)bl * D2 + lane * 8;

  uint4 qd = *(const uint4*)(q + rowoff);
  uint4 kd[5], vd[5];
  bool valid[3];
#pragma unroll
  for (int u = 0; u < 3; u++) {
    int ll = l + u - 1;
    valid[u] = (ll >= 0 && ll < L);
    size_t off = ((size_t)b * L + ll) * D2 + lane * 8;
    if (valid[u]) { kd[u] = *(const uint4*)(k + off); vd[u] = *(const uint4*)(v + off); }
    else { kd[u] = make_uint4(0, 0, 0, 0); vd[u] = make_uint4(0, 0, 0, 0); }
  }
  kd[3] = *(const uint4*)(akr + rowoff);
  vd[3] = *(const uint4*)(avr + rowoff);
  size_t rb = (size_t)b * D2 + lane * 8;
  float4 rk0 = *(const float4*)(rk + rb), rk1 = *(const float4*)(rk + rb + 4);
  float4 rv0 = *(const float4*)(rv + rb), rv1 = *(const float4*)(rv + rb + 4);

  f8 qf = unpack8(qd);
  f8 kf[5], vf[5];
#pragma unroll
  for (int u = 0; u < 4; u++) { kf[u] = unpack8(kd[u]); vf[u] = unpack8(vd[u]); }
  kf[4].v[0] = rk0.x; kf[4].v[1] = rk0.y; kf[4].v[2] = rk0.z; kf[4].v[3] = rk0.w;
  kf[4].v[4] = rk1.x; kf[4].v[5] = rk1.y; kf[4].v[6] = rk1.z; kf[4].v[7] = rk1.w;
  vf[4].v[0] = rv0.x; vf[4].v[1] = rv0.y; vf[4].v[2] = rv0.z; vf[4].v[3] = rv0.w;
  vf[4].v[4] = rv1.x; vf[4].v[5] = rv1.y; vf[4].v[6] = rv1.z; vf[4].v[7] = rv1.w;

  float s[5];
#pragma unroll
  for (int u = 0; u < 5; u++) {
    float p = 0.f;
#pragma unroll
    for (int j = 0; j < 8; j++) p += qf.v[j] * kf[u].v[j];
#pragma unroll
    for (int o = 1; o < 16; o <<= 1) p += __shfl_xor(p, o, 64);
    s[u] = p * SCALE;
  }
  float m = s[0];
#pragma unroll
  for (int u = 1; u < 5; u++) m = fmaxf(m, s[u]);
  float e[5], sum = 0.f;
#pragma unroll
  for (int u = 0; u < 5; u++) { e[u] = expf(s[u] - m); sum += e[u]; }
  float inv = 1.0f / sum;
  float o[8];
#pragma unroll
  for (int j = 0; j < 8; j++) {
    float a = 0.f;
#pragma unroll
    for (int u = 0; u < 5; u++) a += e[u] * vf[u].v[j];
    o[j] = a * inv;
  }
  uint4 od;
  od.x = packbf(o[0], o[1]); od.y = packbf(o[2], o[3]);
  od.z = packbf(o[4], o[5]); od.w = packbf(o[6], o[7]);
  *(uint4*)(att + rowoff) = od;
}

// ---------------- combine (relay row + 64 node chunks) -> satt -> relay;
// then (optional) next-layer projections. grid (B, 12) when do_proj, else (B,1); 128 thr
__global__ __launch_bounds__(128) void relay_final(
    const float* __restrict__ pm, const float* __restrict__ ps, const float* __restrict__ pw,
    const float* __restrict__ relay_entry,
    const float* __restrict__ uvec_in, const float* __restrict__ cvec_in,
    const float* __restrict__ svw, const float* __restrict__ svb,
    const float* __restrict__ sow, const float* __restrict__ sob,
    const float* __restrict__ nrkw, const float* __restrict__ nrkb,
    const float* __restrict__ nrvw, const float* __restrict__ nrvb,
    const float* __restrict__ nsqw, const float* __restrict__ nsqb,
    const float* __restrict__ nskw, const float* __restrict__ nskb,
    float* __restrict__ relay_out,
    float* __restrict__ relay_k, float* __restrict__ relay_v,
    float* __restrict__ u_out, float* __restrict__ cvec_out, int do_proj) {
  int b = blockIdx.x, di = blockIdx.y, t = threadIdx.x;
  __shared__ float uu[NH][D];
  __shared__ float rel0[D];
  __shared__ float pms[NH][NCH], pss[NH][NCH], ecs[NH][NCH];
  __shared__ float s0s[NH], cvs[NH];
  __shared__ float wsum[NH][D];
  __shared__ float satts[D2];
  __shared__ float rel[D];
  __shared__ float sql[HD];
  __shared__ float cred[2];

  rel0[t] = relay_entry[(size_t)b * D + t];
#pragma unroll
  for (int rep = 0; rep < 4; rep++) {
    int idx = rep * 128 + t;
    uu[idx >> 7][idx & 127] = uvec_in[(size_t)b * NH * D + idx];
  }
  if (t < NH) cvs[t] = cvec_in[b * NH + t];
#pragma unroll
  for (int rep = 0; rep < 2; rep++) {
    int idx = rep * 128 + t;
    int n = idx >> 6, c = idx & 63;
    pms[n][c] = pm[(b * NH + n) * NCH + c];
    pss[n][c] = ps[(b * NH + n) * NCH + c];
  }
  __syncthreads();
  int g = t >> 5, lt = t & 31;
  {
    float p = 0.f;
#pragma unroll
    for (int kk = 0; kk < 4; kk++) { int j = lt * 4 + kk; p += uu[g][j] * rel0[j]; }
#pragma unroll
    for (int o = 1; o < 32; o <<= 1) p += __shfl_xor(p, o, 64);
    if (lt == 0) s0s[g] = p + cvs[g];
  }
  __syncthreads();
  float s0 = s0s[g];
  float M = s0;
  for (int c = 0; c < NCH; c++) M = fmaxf(M, pms[g][c]);
  for (int c = lt; c < NCH; c += 32) ecs[g][c] = expf(pms[g][c] - M);
  __syncthreads();
  float e0 = expf(s0 - M);
  float S = e0;
  for (int c = 0; c < NCH; c++) S += pss[g][c] * ecs[g][c];
  float invS = 1.0f / S;
#pragma unroll
  for (int kk = 0; kk < 4; kk++) {
    int h = lt * 4 + kk;
    float acc = e0 * rel0[h];
    const float* pwp = pw + ((size_t)(b * NH + g) * NCH) * D + h;
    for (int c = 0; c < NCH; c++) acc += ecs[g][c] * pwp[(size_t)c * D];
    wsum[g][h] = acc * invS;
  }
  __syncthreads();
#pragma unroll
  for (int rep = 0; rep < 4; rep++) {
    int nh = rep * 128 + t;
    int hn = nh >> 7;
    float acc = svb[nh];
    const float4* wp = (const float4*)(svw + (size_t)nh * D);
    const float4* wl = (const float4*)wsum[hn];
#pragma unroll 8
    for (int d = 0; d < D / 4; d++) {
      float4 a = wl[d], wv4 = wp[d];
      acc += a.x * wv4.x + a.y * wv4.y + a.z * wv4.z + a.w * wv4.w;
    }
    satts[nh] = acc;
  }
  __syncthreads();
  {
    float acc = sob[t];
    const float4* wp = (const float4*)(sow + (size_t)t * D2);
    const float4* a4 = (const float4*)satts;
#pragma unroll 8
    for (int j = 0; j < D2 / 4; j++) {
      float4 a = a4[j], wv4 = wp[j];
      acc += a.x * wv4.x + a.y * wv4.y + a.z * wv4.z + a.w * wv4.w;
    }
    acc = (acc > 0.f) ? acc : 0.01f * acc;
    rel[t] = acc;
    relay_out[(size_t)b * D + t] = acc;
  }
  __syncthreads();
  if (do_proj)
    do_relay_proj(b, di, t, rel, nrkw, nrkb, nrvw, nrvb, nsqw, nsqb, nskw, nskb,
                  relay_k, relay_v, u_out, cvec_out, sql, cred);
}

extern "C" void kernel_launch(void* const* d_in, const int* in_sizes, int n_in,
                              void* d_out, int out_size, void* d_ws, size_t ws_size,
                              hipStream_t stream) {
  const int* tokens = (const int*)d_in[0];
  const int* mask = (const int*)d_in[1];
  const float* emb = (const float*)d_in[2];
  const float* proj_w = (const float*)d_in[3];
  const float* proj_b = (const float*)d_in[4];
  const float* ng = (const float*)d_in[5];
  const float* nb = (const float*)d_in[6];
  const float* rq_w = (const float*)d_in[7], * rq_b = (const float*)d_in[8];
  const float* rk_w = (const float*)d_in[9], * rk_b = (const float*)d_in[10];
  const float* rv_w = (const float*)d_in[11], * rv_b = (const float*)d_in[12];
  const float* ro_w = (const float*)d_in[13], * ro_b = (const float*)d_in[14];
  const float* sq_w = (const float*)d_in[15], * sq_b = (const float*)d_in[16];
  const float* sk_w = (const float*)d_in[17], * sk_b = (const float*)d_in[18];
  const float* sv_w = (const float*)d_in[19], * sv_b = (const float*)d_in[20];
  const float* so_w = (const float*)d_in[21], * so_b = (const float*)d_in[22];

  const size_t BLD = (size_t)B * L * D;        // 1,048,576
  const size_t BLD4 = (size_t)B * L * D2;      // 4,194,304
  const size_t WTEN = (size_t)NL * D * D2;     // 196,608 per tensor

  float* fp = (float*)d_ws;
  float* nodes = fp;                    fp += BLD;
  float* rbuf0 = fp;                    fp += B * D;
  float* rbuf1 = fp;                    fp += B * D;
  float* relay_k = fp;                  fp += B * D2;
  float* relay_v = fp;                  fp += B * D2;
  float* uv0 = fp;                      fp += B * NH * D;
  float* uv1 = fp;                      fp += B * NH * D;
  float* cv0 = fp;                      fp += B * NH;
  float* cv1 = fp;                      fp += B * NH;
  float* pm = fp;                       fp += B * NH * NCH;
  float* ps = fp;                       fp += B * NH * NCH;
  float* pw = fp;                       fp += (size_t)B * NH * NCH * D;
  u16* up = (u16*)fp;
  u16* xb = up;                         up += BLD;
  u16* nxb = up;                        up += BLD;
  u16* qb = up;                         up += BLD4;
  u16* kb = up;                         up += BLD4;
  u16* vb = up;                         up += BLD4;
  u16* akb = up;                        up += BLD4;
  u16* avb = up;                        up += BLD4;
  u16* attb = up;                       up += BLD4;
  u16* wb = up;                         // 4 * WTEN
  u16* wrq = wb, * wrk = wb + WTEN, * wrv = wb + 2 * WTEN, * wro = wb + 3 * WTEN;

  float* rbuf[2] = {rbuf0, rbuf1};
  float* uv[2] = {uv0, uv1};
  float* cv[2] = {cv0, cv1};

  hipMemsetAsync(rbuf0, 0, B * D * sizeof(float), stream);

  {
    WCArgs wa;
    wa.s[0] = rq_w; wa.s[1] = rk_w; wa.s[2] = rv_w; wa.s[3] = ro_w;
    wa.d[0] = wrq; wa.d[1] = wrk; wa.d[2] = wrv; wa.d[3] = wro;
    wconv<<<dim3(WTEN / 1024, 4), 256, 0, stream>>>(wa);
  }
  // embedding projection + layer-0 LN + relay mean: nodes, xb, nxb, relay0
  gemm_embed_ln<<<128, 256, 0, stream>>>(emb, proj_w, proj_b, tokens, ng, nb,
                                         nodes, xb, nxb, rbuf0);
  // layer-0 relay-side projections
  relay_proj<<<dim3(B, 12), 128, 0, stream>>>(rbuf0, rk_w, rk_b, rv_w, rv_b, sq_w, sq_b,
                                              sk_w, sk_b, relay_k, relay_v, uv0, cv0);

  for (int i = 0; i < NL; i++) {
    const size_t wo = (size_t)i * D * D2;
    const float* rqbi = rq_b + (size_t)i * D2;
    const float* rkbi = rk_b + (size_t)i * D2;
    const float* rvbi = rv_b + (size_t)i * D2;
    const float* robi = ro_b + (size_t)i * D;
    const float* svwi = sv_w + wo, * svbi = sv_b + (size_t)i * D2;
    const float* sowi = so_w + wo, * sobi = so_b + (size_t)i * D;
    const int e = i & 1, nx2 = e ^ 1;
    const int last = (i == NL - 1);

    // q,k,v (from nxb) + ak,av (from xb): one dispatch, 128x128 tiles
    {
      GArgs ga = {};
      ga.d[0] = {nxb, wrq + wo, rqbi, qb};
      ga.d[1] = {nxb, wrk + wo, rkbi, kb};
      ga.d[2] = {nxb, wrv + wo, rvbi, vb};
      ga.d[3] = {xb,  wrk + wo, rkbi, akb};
      ga.d[4] = {xb,  wrv + wo, rvbi, avb};
      gemm_qkv<<<dim3(64, 20), 256, 0, stream>>>(ga, 4, D2);
    }
    ring_attn_kernel<<<B * L / 4, 256, 0, stream>>>(qb, kb, vb, akb, avb, relay_k, relay_v, attb);
    // ro GEMM + residual + mask + next-layer LN + relay-attn partials
    gemm_ro_ln<<<256, 256, 0, stream>>>(
        attb, wro + wo, robi, mask,
        last ? nullptr : ng + (i + 1) * D, last ? nullptr : nb + (i + 1) * D,
        uv[e], cv[e], nodes, nxb, pm, ps, pw, last ? 0 : 1);
    // combine (incl. relay row) + project relay; fuse next layer's relay-side projections
    const size_t wn_ = (size_t)(i + 1) * D * D2;
    float* relay_dst = last ? (float*)d_out : rbuf[nx2];
    relay_final<<<dim3(B, last ? 1 : 12), 128, 0, stream>>>(
        pm, ps, pw, rbuf[e], uv[e], cv[e], svwi, svbi, sowi, sobi,
        last ? nullptr : rk_w + wn_, last ? nullptr : rk_b + (size_t)(i + 1) * D2,
        last ? nullptr : rv_w + wn_, last ? nullptr : rv_b + (size_t)(i + 1) * D2,
        last ? nullptr : sq_w + wn_, last ? nullptr : sq_b + (size_t)(i + 1) * D2,
        last ? nullptr : sk_w + wn_, last ? nullptr : sk_b + (size_t)(i + 1) * D2,
        relay_dst, relay_k, relay_v, uv[nx2], cv[nx2], last ? 0 : 1);
  }
}

// Round 14
// 379.184 us; speedup vs baseline: 1.2674x; 1.0102x over previous
//
#include <hip/hip_runtime.h>
#include <hip/hip_bf16.h>

// Problem constants
constexpr int B = 4, L = 2048, E = 300, D = 128, NH = 4, HD = 128, NL = 3, D2 = 512;
constexpr float EPS = 1e-5f;
constexpr float SCALE = 0.08838834764831843f; // 1/sqrt(128)
constexpr int NCH = 64;              // relay-attention node chunks (32 rows each = ro tile)

typedef unsigned int uint_t;
typedef unsigned short u16;
typedef short bf16x8 __attribute__((ext_vector_type(8)));
typedef float f32x4 __attribute__((ext_vector_type(4)));

__device__ __forceinline__ u16 f2bf(float f) {
  union { float f; uint_t i; } x; x.f = f;
  uint_t r = x.i + 0x7fffu + ((x.i >> 16) & 1u);
  return (u16)(r >> 16);
}
__device__ __forceinline__ uint_t packbf(float a, float b) {
  return (uint_t)f2bf(a) | ((uint_t)f2bf(b) << 16);
}
__device__ __forceinline__ float bf2f(u16 u) {
  union { uint_t i; float f; } x; x.i = ((uint_t)u) << 16; return x.f;
}
__device__ __forceinline__ float2 bf2x2(uint_t u) {
  union { uint_t i; float f; } a, b;
  a.i = (u & 0xffffu) << 16; b.i = u & 0xffff0000u;
  return make_float2(a.f, b.f);
}
struct f8 { float v[8]; };
__device__ __forceinline__ f8 unpack8(uint4 u) {
  f8 r;
  float2 a = bf2x2(u.x); r.v[0] = a.x; r.v[1] = a.y;
  float2 b = bf2x2(u.y); r.v[2] = b.x; r.v[3] = b.y;
  float2 c = bf2x2(u.z); r.v[4] = c.x; r.v[5] = c.y;
  float2 d = bf2x2(u.w); r.v[6] = d.x; r.v[7] = d.y;
  return r;
}

// ---------------- weight pre-conversion: 4 tensors (rq,rk,rv,ro), NL*D*D2 fp32 -> bf16
struct WCArgs { const float* s[4]; u16* d[4]; };
__global__ __launch_bounds__(256) void wconv(WCArgs wa) {
  int ti = blockIdx.y;
  const float* s = wa.s[ti]; u16* dd = wa.d[ti];
  int i = (blockIdx.x * 256 + threadIdx.x) * 4;
  float4 f = *(const float4*)(s + i);
  *(uint2*)(dd + i) = make_uint2(packbf(f.x, f.y), packbf(f.z, f.w));
}

// ================= qkv GEMM: 128x128 tile, K=128 (single stage, one barrier),
// LDS-staged coalesced bf16 output (uint4 stores)
struct GDesc { const u16* A; const u16* W; const float* bias; u16* outb; };
struct GArgs { GDesc d[5]; };

__global__ __launch_bounds__(256) void gemm_qkv(GArgs ga, int nby, int N) {
  __shared__ u16 As[128][136];
  __shared__ u16 Ws[128][136];
  int t = threadIdx.x;
  int bm = blockIdx.x;
  int di = blockIdx.y / nby, bn = blockIdx.y - di * nby;
  GDesc d = ga.d[di];
  const int rowA = bm * 128, rowW = bn * 128;

  f32x4 acc[4][4];
#pragma unroll
  for (int i = 0; i < 4; i++)
#pragma unroll
    for (int j = 0; j < 4; j++)
      acc[i][j] = (f32x4){0.f, 0.f, 0.f, 0.f};

  const int r = t >> 1, c0 = (t & 1) * 64;
  const int wid = t >> 6;
  const int wm = (wid & 1) * 64, wn = (wid >> 1) * 64;
  const int lr = t & 15, quad = (t >> 4) & 3;

  const u16* Arow = d.A + (size_t)(rowA + r) * 128;
  const u16* Wrow = d.W + (size_t)(rowW + r) * 128;
  uint4 av_[8], wv_[8];
#pragma unroll
  for (int i = 0; i < 8; i++) {
    av_[i] = *(const uint4*)(Arow + c0 + i * 8);
    wv_[i] = *(const uint4*)(Wrow + c0 + i * 8);
  }
#pragma unroll
  for (int i = 0; i < 8; i++) {
    *(uint4*)&As[r][c0 + i * 8] = av_[i];
    *(uint4*)&Ws[r][c0 + i * 8] = wv_[i];
  }
  __syncthreads();
#pragma unroll
  for (int ks = 0; ks < 4; ks++) {
    bf16x8 af[4], bfr[4];
#pragma unroll
    for (int mt = 0; mt < 4; mt++)
      af[mt] = *(const bf16x8*)&As[wm + mt * 16 + lr][ks * 32 + quad * 8];
#pragma unroll
    for (int nt = 0; nt < 4; nt++)
      bfr[nt] = *(const bf16x8*)&Ws[wn + nt * 16 + lr][ks * 32 + quad * 8];
#pragma unroll
    for (int mt = 0; mt < 4; mt++)
#pragma unroll
      for (int nt = 0; nt < 4; nt++)
        acc[mt][nt] = __builtin_amdgcn_mfma_f32_16x16x32_bf16(af[mt], bfr[nt], acc[mt][nt], 0, 0, 0);
  }
  // epilogue: round to bf16 into LDS (reuse As), then coalesced uint4 stores
  __syncthreads();
#pragma unroll
  for (int nt = 0; nt < 4; nt++) {
    int colL = wn + nt * 16 + lr;
    float bv = d.bias[rowW + colL];
#pragma unroll
    for (int mt = 0; mt < 4; mt++) {
#pragma unroll
      for (int rr = 0; rr < 4; rr++) {
        int rowL = wm + mt * 16 + quad * 4 + rr;
        As[rowL][colL] = f2bf(acc[mt][nt][rr] + bv);
      }
    }
  }
  __syncthreads();
#pragma unroll
  for (int rep = 0; rep < 8; rep++) {
    int lin = rep * 256 + t;
    int rowL = lin >> 4, colL = (lin & 15) * 8;
    uint4 v = *(const uint4*)&As[rowL][colL];
    *(uint4*)&d.outb[(size_t)(rowA + rowL) * N + rowW + colL] = v;
  }
}

// ================= embedding projection (gathered A, K=300, 64x128 tile) +
// fused layer-0 LN (-> nxb) + relay mean (atomics) + nodes/xb writes
__global__ __launch_bounds__(256) void gemm_embed_ln(
    const float* __restrict__ emb, const float* __restrict__ W,
    const float* __restrict__ bias, const int* __restrict__ gather,
    const float* __restrict__ lng, const float* __restrict__ lnb,
    float* __restrict__ nodes, u16* __restrict__ xb, u16* __restrict__ nxb,
    float* __restrict__ relay) {
  __shared__ u16 As[64][72];
  __shared__ u16 Ws[128][72];
  __shared__ float C[64][132];
  __shared__ float gb[2][D];
  __shared__ float lmu[64], lrs[64];
  int t = threadIdx.x;
  int bm = blockIdx.x;               // 128 blocks
  const int rowA0 = bm * 64;

  f32x4 acc[2][4];
#pragma unroll
  for (int i = 0; i < 2; i++)
#pragma unroll
    for (int j = 0; j < 4; j++)
      acc[i][j] = (f32x4){0.f, 0.f, 0.f, 0.f};

  const int wid = t >> 6;
  const int wm = (wid & 1) * 32, wn = (wid >> 1) * 64;
  const int lr = t & 15, quad = (t >> 4) & 3;
  const int ra = t >> 2, ca = (t & 3) * 16;
  const int rw = t >> 1, cw = (t & 1) * 32;

  if (t < D) { gb[0][t] = lng[t]; gb[1][t] = lnb[t]; }

  const float* Arow = emb + (size_t)gather[rowA0 + ra] * E;
  const float* Wrow = W + (size_t)rw * E;

  for (int kt = 0; kt < E; kt += 64) {
    __syncthreads();
    bool full = (kt + 64 <= E);
#pragma unroll
    for (int ch = 0; ch < 4; ch++) {
      int c = kt + ca + ch * 4;
      float4 fa;
      if (full) fa = *(const float4*)(Arow + c);
      else {
        fa.x = (c + 0 < E) ? Arow[c + 0] : 0.f;
        fa.y = (c + 1 < E) ? Arow[c + 1] : 0.f;
        fa.z = (c + 2 < E) ? Arow[c + 2] : 0.f;
        fa.w = (c + 3 < E) ? Arow[c + 3] : 0.f;
      }
      *(uint2*)&As[ra][ca + ch * 4] = make_uint2(packbf(fa.x, fa.y), packbf(fa.z, fa.w));
    }
#pragma unroll
    for (int ch = 0; ch < 8; ch++) {
      int c = kt + cw + ch * 4;
      float4 fw;
      if (full) fw = *(const float4*)(Wrow + c);
      else {
        fw.x = (c + 0 < E) ? Wrow[c + 0] : 0.f;
        fw.y = (c + 1 < E) ? Wrow[c + 1] : 0.f;
        fw.z = (c + 2 < E) ? Wrow[c + 2] : 0.f;
        fw.w = (c + 3 < E) ? Wrow[c + 3] : 0.f;
      }
      *(uint2*)&Ws[rw][cw + ch * 4] = make_uint2(packbf(fw.x, fw.y), packbf(fw.z, fw.w));
    }
    __syncthreads();
#pragma unroll
    for (int ks = 0; ks < 2; ks++) {
      bf16x8 af[2], bfr[4];
#pragma unroll
      for (int mt = 0; mt < 2; mt++)
        af[mt] = *(const bf16x8*)&As[wm + mt * 16 + lr][ks * 32 + quad * 8];
#pragma unroll
      for (int nt = 0; nt < 4; nt++)
        bfr[nt] = *(const bf16x8*)&Ws[wn + nt * 16 + lr][ks * 32 + quad * 8];
#pragma unroll
      for (int mt = 0; mt < 2; mt++)
#pragma unroll
        for (int nt = 0; nt < 4; nt++)
          acc[mt][nt] = __builtin_amdgcn_mfma_f32_16x16x32_bf16(af[mt], bfr[nt], acc[mt][nt], 0, 0, 0);
    }
  }
#pragma unroll
  for (int nt = 0; nt < 4; nt++) {
    int col = wn + nt * 16 + lr;
    float bv = bias[col];
#pragma unroll
    for (int mt = 0; mt < 2; mt++) {
#pragma unroll
      for (int rr = 0; rr < 4; rr++) {
        int row = wm + mt * 16 + quad * 4 + rr;
        C[row][col] = acc[mt][nt][rr] + bv;
      }
    }
  }
  __syncthreads();
  if (t < 64) {
    float s = 0.f, s2 = 0.f;
#pragma unroll 16
    for (int j = 0; j < D; j++) { float v = C[t][j]; s += v; s2 += v * v; }
    float mu = s * (1.0f / D);
    float var = s2 * (1.0f / D) - mu * mu;
    lmu[t] = mu; lrs[t] = rsqrtf(var + EPS);
  }
  __syncthreads();
#pragma unroll
  for (int rep = 0; rep < 8; rep++) {
    int lin = rep * 1024 + t * 4;
    int row = lin >> 7, col = lin & 127;
    float4 v = *(const float4*)&C[row][col];
    size_t g = (size_t)(rowA0 + row) * D + col;
    *(float4*)&nodes[g] = v;
    *(uint2*)&xb[g] = make_uint2(packbf(v.x, v.y), packbf(v.z, v.w));
    float mu = lmu[row], rs = lrs[row];
    float o0 = (v.x - mu) * rs * gb[0][col] + gb[1][col];
    float o1 = (v.y - mu) * rs * gb[0][col + 1] + gb[1][col + 1];
    float o2 = (v.z - mu) * rs * gb[0][col + 2] + gb[1][col + 2];
    float o3 = (v.w - mu) * rs * gb[0][col + 3] + gb[1][col + 3];
    *(uint2*)&nxb[g] = make_uint2(packbf(o0, o1), packbf(o2, o3));
  }
  if (t < D) {
    int b = rowA0 >> 11;
    float s = 0.f;
#pragma unroll 16
    for (int r2 = 0; r2 < 64; r2++) s += C[r2][t];
    atomicAdd(&relay[b * D + t], s * (1.0f / L));
  }
}

// ================= ro GEMM (32x128 tile, K=512, 256 blocks) + residual + mask +
// fused next-layer LN + fused relay-attention partial (chunk = this tile's 32 rows)
__global__ __launch_bounds__(256) void gemm_ro_ln(
    const u16* __restrict__ A,      // attb [B*L, 512]
    const u16* __restrict__ W,      // ro_w bf16 [128, 512]
    const float* __restrict__ bias, // ro_b [128]
    const int* __restrict__ mask,
    const float* __restrict__ lng, const float* __restrict__ lnb,
    const float* __restrict__ uvec, const float* __restrict__ cvec,
    float* __restrict__ nodes, u16* __restrict__ nxb,
    float* __restrict__ pm, float* __restrict__ ps, float* __restrict__ pw,
    int do_ln) {
  __shared__ u16 As[32][136];
  __shared__ u16 Ws[128][136];
  __shared__ float C[32][132];
  __shared__ float gb[2][D];
  __shared__ float lmu[32], lrs[32];
  __shared__ float usv[NH][D];
  __shared__ float cv2[NH];
  __shared__ float scs[NH][32];
  __shared__ float esr[NH][32];
  int t = threadIdx.x;
  int bm = blockIdx.x;               // 256 blocks
  const int rowA0 = bm * 32;
  const int b4 = rowA0 >> 11;
  const int chunk = (rowA0 >> 5) & 63;

  f32x4 acc[4];
#pragma unroll
  for (int j = 0; j < 4; j++) acc[j] = (f32x4){0.f, 0.f, 0.f, 0.f};

  const int wid = t >> 6;
  const int wm = (wid & 1) * 16, wn = (wid >> 1) * 64;
  const int lr = t & 15, quad = (t >> 4) & 3;
  const int ra = t >> 3, ca = (t & 7) * 16;
  const int rw = t >> 1, cw = (t & 1) * 64;

  if (do_ln && t < D) { gb[0][t] = lng[t]; gb[1][t] = lnb[t]; }
#pragma unroll
  for (int rep = 0; rep < 2; rep++) {
    int idx = rep * 256 + t;
    usv[idx >> 7][idx & 127] = uvec[(size_t)b4 * NH * D + idx];
  }
  if (t < NH) cv2[t] = cvec[b4 * NH + t];

  const u16* Arow = A + (size_t)(rowA0 + ra) * 512;
  const u16* Wrow = W + (size_t)rw * 512;

  for (int kt = 0; kt < 512; kt += 128) {
    uint4 a0 = *(const uint4*)(Arow + kt + ca);
    uint4 a1 = *(const uint4*)(Arow + kt + ca + 8);
    uint4 w0 = *(const uint4*)(Wrow + kt + cw);
    uint4 w1 = *(const uint4*)(Wrow + kt + cw + 8);
    uint4 w2 = *(const uint4*)(Wrow + kt + cw + 16);
    uint4 w3 = *(const uint4*)(Wrow + kt + cw + 24);
    uint4 w4 = *(const uint4*)(Wrow + kt + cw + 32);
    uint4 w5 = *(const uint4*)(Wrow + kt + cw + 40);
    uint4 w6 = *(const uint4*)(Wrow + kt + cw + 48);
    uint4 w7 = *(const uint4*)(Wrow + kt + cw + 56);
    __syncthreads();
    *(uint4*)&As[ra][ca] = a0; *(uint4*)&As[ra][ca + 8] = a1;
    *(uint4*)&Ws[rw][cw] = w0; *(uint4*)&Ws[rw][cw + 8] = w1;
    *(uint4*)&Ws[rw][cw + 16] = w2; *(uint4*)&Ws[rw][cw + 24] = w3;
    *(uint4*)&Ws[rw][cw + 32] = w4; *(uint4*)&Ws[rw][cw + 40] = w5;
    *(uint4*)&Ws[rw][cw + 48] = w6; *(uint4*)&Ws[rw][cw + 56] = w7;
    __syncthreads();
#pragma unroll
    for (int ks = 0; ks < 4; ks++) {
      bf16x8 af = *(const bf16x8*)&As[wm + lr][ks * 32 + quad * 8];
      bf16x8 bfr[4];
#pragma unroll
      for (int nt = 0; nt < 4; nt++)
        bfr[nt] = *(const bf16x8*)&Ws[wn + nt * 16 + lr][ks * 32 + quad * 8];
#pragma unroll
      for (int nt = 0; nt < 4; nt++)
        acc[nt] = __builtin_amdgcn_mfma_f32_16x16x32_bf16(af, bfr[nt], acc[nt], 0, 0, 0);
    }
  }
  __syncthreads();
#pragma unroll
  for (int nt = 0; nt < 4; nt++) {
    int col = wn + nt * 16 + lr;
    float bv = bias[col];
#pragma unroll
    for (int rr = 0; rr < 4; rr++) {
      int row = wm + quad * 4 + rr;
      float v = acc[nt][rr] + bv;
      v = (v > 0.f) ? v : 0.01f * v;
      v += nodes[(size_t)(rowA0 + row) * D + col];
      if (mask[rowA0 + row] == 0) v = 0.f;
      C[row][col] = v;
    }
  }
  __syncthreads();
  if (t < 32) {
    float s = 0.f, s2 = 0.f;
#pragma unroll 16
    for (int j = 0; j < D; j++) { float v = C[t][j]; s += v; s2 += v * v; }
    float mu = s * (1.0f / D);
    float var = s2 * (1.0f / D) - mu * mu;
    lmu[t] = mu; lrs[t] = rsqrtf(var + EPS);
  }
  __syncthreads();
#pragma unroll
  for (int rep = 0; rep < 4; rep++) {
    int lin = rep * 1024 + t * 4;
    int row = lin >> 7, col = lin & 127;
    float4 v = *(const float4*)&C[row][col];
    size_t g = (size_t)(rowA0 + row) * D + col;
    *(float4*)&nodes[g] = v;
    if (do_ln) {
      float mu = lmu[row], rs = lrs[row];
      float o0 = (v.x - mu) * rs * gb[0][col] + gb[1][col];
      float o1 = (v.y - mu) * rs * gb[0][col + 1] + gb[1][col + 1];
      float o2 = (v.z - mu) * rs * gb[0][col + 2] + gb[1][col + 2];
      float o3 = (v.w - mu) * rs * gb[0][col + 3] + gb[1][col + 3];
      *(uint2*)&nxb[g] = make_uint2(packbf(o0, o1), packbf(o2, o3));
    }
  }
  // ---- fused relay-attention partial: wave = head, chunk = this tile's 32 rows
  {
    int n = wid, lane = t & 63;
    int bn = b4 * NH + n;
    const float2* un = (const float2*)usv[n];
    float2 uv2 = un[lane];
    for (int r2 = 0; r2 < 32; r2++) {
      float2 cc = ((const float2*)&C[r2][0])[lane];
      float p = uv2.x * cc.x + uv2.y * cc.y;
#pragma unroll
      for (int o = 1; o < 64; o <<= 1) p += __shfl_xor(p, o, 64);
      if (lane == 0) {
        float s = p + cv2[n];
        if (mask[rowA0 + r2] == 0) s = -1e30f;
        scs[n][r2] = s;
      }
    }
    float m = -1e30f;
    for (int r2 = 0; r2 < 32; r2++) m = fmaxf(m, scs[n][r2]);
    if (lane < 32) esr[n][lane] = expf(scs[n][lane] - m);
    float sum = 0.f;
    for (int r2 = 0; r2 < 32; r2++) sum += esr[n][r2];
    if (lane == 0) { pm[bn * NCH + chunk] = m; ps[bn * NCH + chunk] = sum; }
    float a0 = 0.f, a1 = 0.f;
    for (int r2 = 0; r2 < 32; r2++) {
      float e = esr[n][r2];
      float2 cc = ((const float2*)&C[r2][0])[lane];
      a0 += e * cc.x; a1 += e * cc.y;
    }
    float* pwp = pw + ((size_t)bn * NCH + chunk) * D + 2 * lane;
    pwp[0] = a0; pwp[1] = a1;
  }
}

// ---------------- shared device helper: relay projections from rel[] in LDS
__device__ __forceinline__ void do_relay_proj(
    int b, int di, int t, const float* rel,
    const float* rkw, const float* rkb, const float* rvw, const float* rvb,
    const float* sqw, const float* sqb, const float* skw, const float* skb_,
    float* relay_k, float* relay_v, float* u, float* cvec,
    float* sql, float* cred) {
  const float4* r4 = (const float4*)rel;
  if (di < 8) {
    int which = di >> 2;           // 0 = rk, 1 = rv
    int n = (di & 3) * 128 + t;
    const float* W = which ? rvw : rkw;
    float acc = (which ? rvb : rkb)[n];
    const float4* w4 = (const float4*)(W + (size_t)n * D);
#pragma unroll 8
    for (int i = 0; i < D / 4; i++) {
      float4 w = w4[i], r = r4[i];
      acc += w.x * r.x + w.y * r.y + w.z * r.z + w.w * r.w;
    }
    (which ? relay_v : relay_k)[(size_t)b * D2 + n] = acc;
  } else {
    int n = di - 8;
    {
      int nh = n * HD + t;
      float acc = sqb[nh];
      const float4* w4 = (const float4*)(sqw + (size_t)nh * D);
#pragma unroll 8
      for (int i = 0; i < D / 4; i++) {
        float4 w = w4[i], r = r4[i];
        acc += w.x * r.x + w.y * r.y + w.z * r.z + w.w * r.w;
      }
      sql[t] = acc;
    }
    __syncthreads();
    {
      float cp = sql[t] * skb_[n * HD + t];
#pragma unroll
      for (int o = 1; o < 64; o <<= 1) cp += __shfl_xor(cp, o, 64);
      if ((t & 63) == 0) cred[t >> 6] = cp;
    }
    float a0 = 0.f, a1 = 0.f, a2 = 0.f, a3 = 0.f;
    const float* wp = skw + (size_t)(n * HD) * D + t;
    for (int h = 0; h < HD; h += 4) {
      a0 += sql[h] * wp[(size_t)h * D];
      a1 += sql[h + 1] * wp[(size_t)(h + 1) * D];
      a2 += sql[h + 2] * wp[(size_t)(h + 2) * D];
      a3 += sql[h + 3] * wp[(size_t)(h + 3) * D];
    }
    u[((size_t)b * NH + n) * D + t] = (a0 + a1 + a2 + a3) * SCALE;
    __syncthreads();
    if (t == 0) cvec[b * NH + n] = (cred[0] + cred[1]) * SCALE;
  }
}

// ---------------- standalone relay projections (layer 0), grid (B,12) x 128
__global__ __launch_bounds__(128) void relay_proj(
    const float* __restrict__ relay,
    const float* __restrict__ rkw, const float* __restrict__ rkb,
    const float* __restrict__ rvw, const float* __restrict__ rvb,
    const float* __restrict__ sqw, const float* __restrict__ sqb,
    const float* __restrict__ skw, const float* __restrict__ skb_,
    float* __restrict__ relay_k, float* __restrict__ relay_v,
    float* __restrict__ u, float* __restrict__ cvec) {
  __shared__ float rel[D];
  __shared__ float sql[HD];
  __shared__ float cred[2];
  int b = blockIdx.x, di = blockIdx.y, t = threadIdx.x;
  rel[t] = relay[(size_t)b * D + t];
  __syncthreads();
  do_relay_proj(b, di, t, rel, rkw, rkb, rvw, rvb, sqw, sqb, skw, skb_,
                relay_k, relay_v, u, cvec, sql, cred);
}

// ---------------- ring (windowed) attention, full-row vectorized:
// one wave per (b,l); lane covers 8 contiguous bf16 of the D2=512 row
// (head = lane>>4); dots reduce over 16-lane groups (4 shfl steps).
__global__ __launch_bounds__(256) void ring_attn_kernel(
    const u16* __restrict__ q, const u16* __restrict__ k, const u16* __restrict__ v,
    const u16* __restrict__ akr, const u16* __restrict__ avr,
    const float* __restrict__ rk, const float* __restrict__ rv,
    u16* __restrict__ att) {
  int wv = threadIdx.x >> 6, lane = threadIdx.x & 63;
  int bl = blockIdx.x * 4 + wv;
  int b = bl >> 11, l = bl & (L - 1);
  size_t rowoff = (size_t)bl * D2 + lane * 8;

  uint4 qd = *(const uint4*)(q + rowoff);
  uint4 kd[5], vd[5];
  bool valid[3];
#pragma unroll
  for (int u = 0; u < 3; u++) {
    int ll = l + u - 1;
    valid[u] = (ll >= 0 && ll < L);
    size_t off = ((size_t)b * L + ll) * D2 + lane * 8;
    if (valid[u]) { kd[u] = *(const uint4*)(k + off); vd[u] = *(const uint4*)(v + off); }
    else { kd[u] = make_uint4(0, 0, 0, 0); vd[u] = make_uint4(0, 0, 0, 0); }
  }
  kd[3] = *(const uint4*)(akr + rowoff);
  vd[3] = *(const uint4*)(avr + rowoff);
  size_t rb = (size_t)b * D2 + lane * 8;
  float4 rk0 = *(const float4*)(rk + rb), rk1 = *(const float4*)(rk + rb + 4);
  float4 rv0 = *(const float4*)(rv + rb), rv1 = *(const float4*)(rv + rb + 4);

  f8 qf = unpack8(qd);
  f8 kf[5], vf[5];
#pragma unroll
  for (int u = 0; u < 4; u++) { kf[u] = unpack8(kd[u]); vf[u] = unpack8(vd[u]); }
  kf[4].v[0] = rk0.x; kf[4].v[1] = rk0.y; kf[4].v[2] = rk0.z; kf[4].v[3] = rk0.w;
  kf[4].v[4] = rk1.x; kf[4].v[5] = rk1.y; kf[4].v[6] = rk1.z; kf[4].v[7] = rk1.w;
  vf[4].v[0] = rv0.x; vf[4].v[1] = rv0.y; vf[4].v[2] = rv0.z; vf[4].v[3] = rv0.w;
  vf[4].v[4] = rv1.x; vf[4].v[5] = rv1.y; vf[4].v[6] = rv1.z; vf[4].v[7] = rv1.w;

  float s[5];
#pragma unroll
  for (int u = 0; u < 5; u++) {
    float p = 0.f;
#pragma unroll
    for (int j = 0; j < 8; j++) p += qf.v[j] * kf[u].v[j];
#pragma unroll
    for (int o = 1; o < 16; o <<= 1) p += __shfl_xor(p, o, 64);
    s[u] = p * SCALE;
  }
  float m = s[0];
#pragma unroll
  for (int u = 1; u < 5; u++) m = fmaxf(m, s[u]);
  float e[5], sum = 0.f;
#pragma unroll
  for (int u = 0; u < 5; u++) { e[u] = expf(s[u] - m); sum += e[u]; }
  float inv = 1.0f / sum;
  float o[8];
#pragma unroll
  for (int j = 0; j < 8; j++) {
    float a = 0.f;
#pragma unroll
    for (int u = 0; u < 5; u++) a += e[u] * vf[u].v[j];
    o[j] = a * inv;
  }
  uint4 od;
  od.x = packbf(o[0], o[1]); od.y = packbf(o[2], o[3]);
  od.z = packbf(o[4], o[5]); od.w = packbf(o[6], o[7]);
  *(uint4*)(att + rowoff) = od;
}

// ---------------- combine (relay row + 64 node chunks) -> satt -> relay;
// then (optional) next-layer projections. grid (B, 12) when do_proj, else (B,1); 128 thr
__global__ __launch_bounds__(128) void relay_final(
    const float* __restrict__ pm, const float* __restrict__ ps, const float* __restrict__ pw,
    const float* __restrict__ relay_entry,
    const float* __restrict__ uvec_in, const float* __restrict__ cvec_in,
    const float* __restrict__ svw, const float* __restrict__ svb,
    const float* __restrict__ sow, const float* __restrict__ sob,
    const float* __restrict__ nrkw, const float* __restrict__ nrkb,
    const float* __restrict__ nrvw, const float* __restrict__ nrvb,
    const float* __restrict__ nsqw, const float* __restrict__ nsqb,
    const float* __restrict__ nskw, const float* __restrict__ nskb,
    float* __restrict__ relay_out,
    float* __restrict__ relay_k, float* __restrict__ relay_v,
    float* __restrict__ u_out, float* __restrict__ cvec_out, int do_proj) {
  int b = blockIdx.x, di = blockIdx.y, t = threadIdx.x;
  __shared__ float uu[NH][D];
  __shared__ float rel0[D];
  __shared__ float pms[NH][NCH], pss[NH][NCH], ecs[NH][NCH];
  __shared__ float s0s[NH], cvs[NH];
  __shared__ float wsum[NH][D];
  __shared__ float satts[D2];
  __shared__ float rel[D];
  __shared__ float sql[HD];
  __shared__ float cred[2];

  rel0[t] = relay_entry[(size_t)b * D + t];
#pragma unroll
  for (int rep = 0; rep < 4; rep++) {
    int idx = rep * 128 + t;
    uu[idx >> 7][idx & 127] = uvec_in[(size_t)b * NH * D + idx];
  }
  if (t < NH) cvs[t] = cvec_in[b * NH + t];
#pragma unroll
  for (int rep = 0; rep < 2; rep++) {
    int idx = rep * 128 + t;
    int n = idx >> 6, c = idx & 63;
    pms[n][c] = pm[(b * NH + n) * NCH + c];
    pss[n][c] = ps[(b * NH + n) * NCH + c];
  }
  __syncthreads();
  int g = t >> 5, lt = t & 31;
  {
    float p = 0.f;
#pragma unroll
    for (int kk = 0; kk < 4; kk++) { int j = lt * 4 + kk; p += uu[g][j] * rel0[j]; }
#pragma unroll
    for (int o = 1; o < 32; o <<= 1) p += __shfl_xor(p, o, 64);
    if (lt == 0) s0s[g] = p + cvs[g];
  }
  __syncthreads();
  float s0 = s0s[g];
  float M = s0;
  for (int c = 0; c < NCH; c++) M = fmaxf(M, pms[g][c]);
  for (int c = lt; c < NCH; c += 32) ecs[g][c] = expf(pms[g][c] - M);
  __syncthreads();
  float e0 = expf(s0 - M);
  float S = e0;
  for (int c = 0; c < NCH; c++) S += pss[g][c] * ecs[g][c];
  float invS = 1.0f / S;
#pragma unroll
  for (int kk = 0; kk < 4; kk++) {
    int h = lt * 4 + kk;
    float acc = e0 * rel0[h];
    const float* pwp = pw + ((size_t)(b * NH + g) * NCH) * D + h;
    for (int c = 0; c < NCH; c++) acc += ecs[g][c] * pwp[(size_t)c * D];
    wsum[g][h] = acc * invS;
  }
  __syncthreads();
#pragma unroll
  for (int rep = 0; rep < 4; rep++) {
    int nh = rep * 128 + t;
    int hn = nh >> 7;
    float acc = svb[nh];
    const float4* wp = (const float4*)(svw + (size_t)nh * D);
    const float4* wl = (const float4*)wsum[hn];
#pragma unroll 8
    for (int d = 0; d < D / 4; d++) {
      float4 a = wl[d], wv4 = wp[d];
      acc += a.x * wv4.x + a.y * wv4.y + a.z * wv4.z + a.w * wv4.w;
    }
    satts[nh] = acc;
  }
  __syncthreads();
  {
    float acc = sob[t];
    const float4* wp = (const float4*)(sow + (size_t)t * D2);
    const float4* a4 = (const float4*)satts;
#pragma unroll 8
    for (int j = 0; j < D2 / 4; j++) {
      float4 a = a4[j], wv4 = wp[j];
      acc += a.x * wv4.x + a.y * wv4.y + a.z * wv4.z + a.w * wv4.w;
    }
    acc = (acc > 0.f) ? acc : 0.01f * acc;
    rel[t] = acc;
    relay_out[(size_t)b * D + t] = acc;
  }
  __syncthreads();
  if (do_proj)
    do_relay_proj(b, di, t, rel, nrkw, nrkb, nrvw, nrvb, nsqw, nsqb, nskw, nskb,
                  relay_k, relay_v, u_out, cvec_out, sql, cred);
}

extern "C" void kernel_launch(void* const* d_in, const int* in_sizes, int n_in,
                              void* d_out, int out_size, void* d_ws, size_t ws_size,
                              hipStream_t stream) {
  const int* tokens = (const int*)d_in[0];
  const int* mask = (const int*)d_in[1];
  const float* emb = (const float*)d_in[2];
  const float* proj_w = (const float*)d_in[3];
  const float* proj_b = (const float*)d_in[4];
  const float* ng = (const float*)d_in[5];
  const float* nb = (const float*)d_in[6];
  const float* rq_w = (const float*)d_in[7], * rq_b = (const float*)d_in[8];
  const float* rk_w = (const float*)d_in[9], * rk_b = (const float*)d_in[10];
  const float* rv_w = (const float*)d_in[11], * rv_b = (const float*)d_in[12];
  const float* ro_w = (const float*)d_in[13], * ro_b = (const float*)d_in[14];
  const float* sq_w = (const float*)d_in[15], * sq_b = (const float*)d_in[16];
  const float* sk_w = (const float*)d_in[17], * sk_b = (const float*)d_in[18];
  const float* sv_w = (const float*)d_in[19], * sv_b = (const float*)d_in[20];
  const float* so_w = (const float*)d_in[21], * so_b = (const float*)d_in[22];

  const size_t BLD = (size_t)B * L * D;        // 1,048,576
  const size_t BLD4 = (size_t)B * L * D2;      // 4,194,304
  const size_t WTEN = (size_t)NL * D * D2;     // 196,608 per tensor

  float* fp = (float*)d_ws;
  float* nodes = fp;                    fp += BLD;
  float* rbuf0 = fp;                    fp += B * D;
  float* rbuf1 = fp;                    fp += B * D;
  float* relay_k = fp;                  fp += B * D2;
  float* relay_v = fp;                  fp += B * D2;
  float* uv0 = fp;                      fp += B * NH * D;
  float* uv1 = fp;                      fp += B * NH * D;
  float* cv0 = fp;                      fp += B * NH;
  float* cv1 = fp;                      fp += B * NH;
  float* pm = fp;                       fp += B * NH * NCH;
  float* ps = fp;                       fp += B * NH * NCH;
  float* pw = fp;                       fp += (size_t)B * NH * NCH * D;
  u16* up = (u16*)fp;
  u16* xb = up;                         up += BLD;
  u16* nxb = up;                        up += BLD;
  u16* qb = up;                         up += BLD4;
  u16* kb = up;                         up += BLD4;
  u16* vb = up;                         up += BLD4;
  u16* akb = up;                        up += BLD4;
  u16* avb = up;                        up += BLD4;
  u16* attb = up;                       up += BLD4;
  u16* wb = up;                         // 4 * WTEN
  u16* wrq = wb, * wrk = wb + WTEN, * wrv = wb + 2 * WTEN, * wro = wb + 3 * WTEN;

  float* rbuf[2] = {rbuf0, rbuf1};
  float* uv[2] = {uv0, uv1};
  float* cv[2] = {cv0, cv1};

  hipMemsetAsync(rbuf0, 0, B * D * sizeof(float), stream);

  {
    WCArgs wa;
    wa.s[0] = rq_w; wa.s[1] = rk_w; wa.s[2] = rv_w; wa.s[3] = ro_w;
    wa.d[0] = wrq; wa.d[1] = wrk; wa.d[2] = wrv; wa.d[3] = wro;
    wconv<<<dim3(WTEN / 1024, 4), 256, 0, stream>>>(wa);
  }
  // embedding projection + layer-0 LN + relay mean: nodes, xb, nxb, relay0
  gemm_embed_ln<<<128, 256, 0, stream>>>(emb, proj_w, proj_b, tokens, ng, nb,
                                         nodes, xb, nxb, rbuf0);
  // layer-0 relay-side projections
  relay_proj<<<dim3(B, 12), 128, 0, stream>>>(rbuf0, rk_w, rk_b, rv_w, rv_b, sq_w, sq_b,
                                              sk_w, sk_b, relay_k, relay_v, uv0, cv0);

  for (int i = 0; i < NL; i++) {
    const size_t wo = (size_t)i * D * D2;
    const float* rqbi = rq_b + (size_t)i * D2;
    const float* rkbi = rk_b + (size_t)i * D2;
    const float* rvbi = rv_b + (size_t)i * D2;
    const float* robi = ro_b + (size_t)i * D;
    const float* svwi = sv_w + wo, * svbi = sv_b + (size_t)i * D2;
    const float* sowi = so_w + wo, * sobi = so_b + (size_t)i * D;
    const int e = i & 1, nx2 = e ^ 1;
    const int last = (i == NL - 1);

    // q,k,v (from nxb) + ak,av (from xb): one dispatch, 128x128 tiles
    {
      GArgs ga = {};
      ga.d[0] = {nxb, wrq + wo, rqbi, qb};
      ga.d[1] = {nxb, wrk + wo, rkbi, kb};
      ga.d[2] = {nxb, wrv + wo, rvbi, vb};
      ga.d[3] = {xb,  wrk + wo, rkbi, akb};
      ga.d[4] = {xb,  wrv + wo, rvbi, avb};
      gemm_qkv<<<dim3(64, 20), 256, 0, stream>>>(ga, 4, D2);
    }
    ring_attn_kernel<<<B * L / 4, 256, 0, stream>>>(qb, kb, vb, akb, avb, relay_k, relay_v, attb);
    // ro GEMM + residual + mask + next-layer LN + relay-attn partials
    gemm_ro_ln<<<256, 256, 0, stream>>>(
        attb, wro + wo, robi, mask,
        last ? nullptr : ng + (i + 1) * D, last ? nullptr : nb + (i + 1) * D,
        uv[e], cv[e], nodes, nxb, pm, ps, pw, last ? 0 : 1);
    // combine (incl. relay row) + project relay; fuse next layer's relay-side projections
    const size_t wn_ = (size_t)(i + 1) * D * D2;
    float* relay_dst = last ? (float*)d_out : rbuf[nx2];
    relay_final<<<dim3(B, last ? 1 : 12), 128, 0, stream>>>(
        pm, ps, pw, rbuf[e], uv[e], cv[e], svwi, svbi, sowi, sobi,
        last ? nullptr : rk_w + wn_, last ? nullptr : rk_b + (size_t)(i + 1) * D2,
        last ? nullptr : rv_w + wn_, last ? nullptr : rv_b + (size_t)(i + 1) * D2,
        last ? nullptr : sq_w + wn_, last ? nullptr : sq_b + (size_t)(i + 1) * D2,
        last ? nullptr : sk_w + wn_, last ? nullptr : sk_b + (size_t)(i + 1) * D2,
        relay_dst, relay_k, relay_v, uv[nx2], cv[nx2], last ? 0 : 1);
  }
}